// Round 5
// baseline (714.496 us; speedup 1.0000x reference)
//
#include <hip/hip_runtime.h>

#define NPIX   1024   // 32*32
#define NEH    992    // horizontal edges 32*31
#define NEDGE  1984   // + vertical 31*32
#define SORTN  2048
#define CHUNK  8      // labels per phase-2 pass
#define NMERGE 1023
#define NIL    0xFFFFu

// per-(tile,sgn) merge-record block in ws (20480 B stride)
#define MRG_STRIDE 20480
#define MRG_M      0
#define MRG_RA     256
#define MRG_RB     4608
#define MRG_SS     8960
#define MRG_ED     13312
#define MRG_NXT    15616

__device__ __forceinline__ void edge_ab(int e, int& a, int& b) {
    if (e < NEH) { int y = e / 31; int x = e - y * 31; a = y * 32 + x; b = a + 1; }
    else         { int ev = e - NEH; a = ev; b = ev + 32; }
}

__device__ __forceinline__ uint4 add4(uint4 x, uint4 y) {
    return make_uint4(x.x + y.x, x.y + y.y, x.z + y.z, x.w + y.w);
}
__device__ __forceinline__ uint4 sub4(uint4 x, uint4 y) {
    return make_uint4(x.x - y.x, x.y - y.y, x.z - y.z, x.w - y.w);
}

// ============================ K1: CCL + label compact (per tile) ============================
__global__ __launch_bounds__(256, 2)
void k1_ccl(const float* __restrict__ t_glob,
            unsigned short* __restrict__ pixLab_g,
            int* __restrict__ Kg) {
    const int tid = threadIdx.x;
    const int tileId = blockIdx.x;
    const int bat = tileId >> 6;
    const int tile = tileId & 63;
    const int tr = tile >> 3, tc = tile & 7;

    __shared__ unsigned char  bgS[NPIX];
    __shared__ unsigned short labS[NPIX];
    __shared__ unsigned int   cntS[NPIX];
    __shared__ int kprimeSh;

    for (int i = tid; i < NPIX; i += 256) {
        int y = i >> 5, x = i & 31;
        int gidx = bat * 65536 + (tr * 32 + y) * 256 + (tc * 32 + x);
        bgS[i] = (t_glob[gidx] == 0.0f) ? 1 : 0;
    }
    __syncthreads();

    if (tid < 64) {
        const int lane = tid;
        if (lane < 32) {
            #pragma unroll
            for (int x = 0; x < 32; x++) {
                int i = lane * 32 + x;
                labS[i] = bgS[i] ? (unsigned short)i : (unsigned short)NIL;
            }
        }
        while (true) {
            bool changed = false;
            if (lane < 32) {
                const int base = lane * 32;
                unsigned short v[32];
                #pragma unroll
                for (int x = 0; x < 32; x++) v[x] = labS[base + x];
                unsigned run = NIL;
                #pragma unroll
                for (int x = 0; x < 32; x++) {
                    unsigned val = v[x];
                    if (val == NIL) { run = NIL; }
                    else { unsigned nv = min(run, val); changed |= (nv != val); v[x] = (unsigned short)nv; run = nv; }
                }
                run = NIL;
                #pragma unroll
                for (int x = 31; x >= 0; x--) {
                    unsigned val = v[x];
                    if (val == NIL) { run = NIL; }
                    else { unsigned nv = min(run, val); changed |= (nv != val); v[x] = (unsigned short)nv; run = nv; }
                }
                #pragma unroll
                for (int x = 0; x < 32; x++) labS[base + x] = v[x];
            }
            if (lane < 32) {
                unsigned short c[32];
                #pragma unroll
                for (int k = 0; k < 32; k++) c[k] = labS[k * 32 + lane];
                unsigned run = NIL;
                #pragma unroll
                for (int k = 0; k < 32; k++) {
                    unsigned val = c[k];
                    if (val == NIL) { run = NIL; }
                    else { unsigned nv = min(run, val); changed |= (nv != val); c[k] = (unsigned short)nv; run = nv; }
                }
                run = NIL;
                #pragma unroll
                for (int k = 31; k >= 0; k--) {
                    unsigned val = c[k];
                    if (val == NIL) { run = NIL; }
                    else { unsigned nv = min(run, val); changed |= (nv != val); c[k] = (unsigned short)nv; run = nv; }
                }
                #pragma unroll
                for (int k = 0; k < 32; k++) labS[k * 32 + lane] = c[k];
            }
            if (!__any(changed)) break;
        }
    }
    __syncthreads();

    for (int i = tid; i < NPIX; i += 256) cntS[i] = 0;
    if (tid == 0) kprimeSh = 0;
    __syncthreads();
    for (int i = tid; i < NPIX; i += 256)
        if (bgS[i]) atomicAdd(&cntS[labS[i]], 1u);
    __syncthreads();
    for (int i = tid; i < NPIX; i += 256) {
        if (bgS[i] && (int)labS[i] == i) {
            unsigned id = (cntS[i] >= 2) ? (unsigned)atomicAdd(&kprimeSh, 1) : NIL;
            cntS[i] = id;
        }
    }
    __syncthreads();
    for (int i = tid; i < NPIX; i += 256)
        pixLab_g[tileId * NPIX + i] = bgS[i] ? (unsigned short)cntS[labS[i]] : (unsigned short)NIL;
    if (tid == 0) Kg[tileId] = kprimeSh;
}

// ============================ K2: edge-key bitonic sort (per tile,sgn) ============================
__global__ __launch_bounds__(256, 2)
void k2_sort(const float* __restrict__ t_glob,
             const float* __restrict__ p_glob,
             unsigned short* __restrict__ ord_g) {
    const int tid = threadIdx.x;
    const int wg  = blockIdx.x;
    const int sgn = wg & 1;
    const int tileId = wg >> 1;
    const int bat = tileId >> 6;
    const int tile = tileId & 63;
    const int tr = tile >> 3, tc = tile & 7;

    __shared__ float pT[NPIX];
    __shared__ unsigned char bgS[NPIX];
    __shared__ unsigned long long keys[SORTN];

    for (int i = tid; i < NPIX; i += 256) {
        int y = i >> 5, x = i & 31;
        int gidx = bat * 65536 + (tr * 32 + y) * 256 + (tc * 32 + x);
        pT[i] = p_glob[gidx];
        bgS[i] = (t_glob[gidx] == 0.0f) ? 1 : 0;
    }
    __syncthreads();

    for (int k = tid; k < SORTN; k += 256) {
        unsigned long long key = 0ULL;
        if (k < NEDGE) {
            int a, b; edge_ab(k, a, b);
            float cost = pT[a] + pT[b];
            int nfg = (int)(!bgS[a]) + (int)(!bgS[b]);
            if (sgn == 0) { if (nfg == 2) cost = 20.0f; }
            else          { if (nfg == 0) cost = 0.0f;  }
            key = ((unsigned long long)__float_as_uint(cost) << 16)
                | (unsigned long long)(0xFFFFu - (unsigned)k);
        }
        keys[k] = key;
    }
    __syncthreads();
    for (int kk = 2; kk <= SORTN; kk <<= 1) {
        for (int jj = kk >> 1; jj > 0; jj >>= 1) {
            for (int i = tid; i < SORTN; i += 256) {
                int ixj = i ^ jj;
                if (ixj > i) {
                    unsigned long long A = keys[i], Bv = keys[ixj];
                    bool descBlk = ((i & kk) == 0);
                    if ((A < Bv) == descBlk) { keys[i] = Bv; keys[ixj] = A; }
                }
            }
            __syncthreads();
        }
    }
    for (int k = tid; k < NEDGE; k += 256)
        ord_g[(size_t)wg * SORTN + k] = (unsigned short)(0xFFFFu - (unsigned)(keys[k] & 0xFFFFULL));
}

// ============================ K3: Kruskal merge sequence (per tile,sgn) ============================
__global__ __launch_bounds__(64)
void k3_kruskal(const float* __restrict__ t_glob,
                const unsigned short* __restrict__ ord_g,
                char* __restrict__ mrg_base) {
    const int lane = threadIdx.x;
    const int wg  = blockIdx.x;
    const int tileId = wg >> 1;
    const int bat = tileId >> 6;
    const int tile = tileId & 63;
    const int tr = tile >> 3, tc = tile & 7;

    __shared__ unsigned short parentS[NPIX];
    __shared__ unsigned long long nodeS[NPIX];
    __shared__ unsigned short nextS[NPIX];

    char* mg = mrg_base + (size_t)wg * MRG_STRIDE;
    unsigned int*   mrA = (unsigned int*)(mg + MRG_RA);
    unsigned int*   mrB = (unsigned int*)(mg + MRG_RB);
    unsigned int*   mSS = (unsigned int*)(mg + MRG_SS);
    unsigned short* mED = (unsigned short*)(mg + MRG_ED);
    unsigned short* mNX = (unsigned short*)(mg + MRG_NXT);
    const unsigned short* ord = ord_g + (size_t)wg * SORTN;

    for (int i = lane; i < NPIX; i += 64) {
        int y = i >> 5, x = i & 31;
        int gidx = bat * 65536 + (tr * 32 + y) * 256 + (tc * 32 + x);
        unsigned bg = (t_glob[gidx] == 0.0f) ? 1u : 0u;
        parentS[i] = (unsigned short)i;
        nodeS[i] = ((unsigned long long)i << 48) | ((unsigned long long)i << 32)
                 | (1ULL << 16) | (unsigned long long)bg;
        nextS[i] = (unsigned short)NIL;
    }
    __syncthreads();   // single wave; cheap, guarantees LDS init visible

    int m = 0;
    for (int kb = 0; kb < NEDGE; kb += 64) {
        int e = ord[kb + lane];
        int a, b; edge_ab(e, a, b);
        unsigned ra = (unsigned)a, rb = (unsigned)b;
        while (true) {
            unsigned pa = parentS[ra];
            unsigned pb = parentS[rb];
            if (pa == ra && pb == rb) break;
            if (pa != ra) { unsigned ga = parentS[pa]; parentS[ra] = (unsigned short)ga; ra = ga; }
            if (pb != rb) { unsigned gb = parentS[pb]; parentS[rb] = (unsigned short)gb; rb = gb; }
        }
        unsigned long long spec = ((unsigned long long)(unsigned)e << 32)
                                | ((unsigned long long)ra << 16) | (unsigned long long)rb;
        unsigned long long candm = __ballot(ra != rb);

        __builtin_amdgcn_sched_barrier(0);
        asm volatile("s_waitcnt lgkmcnt(0)" ::: "memory");

        bool haveCur = false;
        unsigned cra = 0, crb = 0, ce = 0, cpa = 0, cpb = 0;
        unsigned long long cna = 0, cnb = 0;
        while (candm != 0ULL || haveCur) {
            bool haveNext = (candm != 0ULL);
            unsigned nra = 0, nrb = 0, ne = 0, npa = 0, npb = 0;
            unsigned long long nna = 0, nnb = 0;
            if (haveNext) {
                int j = __ffsll((long long)candm) - 1;
                candm &= candm - 1ULL;
                unsigned long long sj = __shfl(spec, j);
                ne  = (unsigned)(sj >> 32);
                nra = (unsigned)(sj >> 16) & 0xFFFFu;
                nrb = (unsigned)sj & 0xFFFFu;
                npa = parentS[nra];
                npb = parentS[nrb];
                nna = nodeS[nra];
                nnb = nodeS[nrb];
            }
            if (haveCur) {
                unsigned ra2 = cra, rb2 = crb;
                unsigned long long na = cna, nb = cnb;
                bool ok = true;
                if (cpa != ra2 || cpb != rb2) {
                    unsigned r = cpa;
                    while (true) { unsigned p = parentS[r]; if (p == r) break; r = p; }
                    ra2 = r;
                    r = cpb;
                    while (true) { unsigned p = parentS[r]; if (p == r) break; r = p; }
                    rb2 = r;
                    if (ra2 == rb2) ok = false;
                    else { na = nodeS[ra2]; nb = nodeS[rb2]; }
                }
                if (ok) {
                    unsigned headA = (unsigned)(na >> 48);
                    unsigned tailA = (unsigned)(na >> 32) & 0xFFFFu;
                    unsigned szA   = (unsigned)(na >> 16) & 0xFFFFu;
                    unsigned slA   = (unsigned)na & 0xFFFFu;
                    unsigned headB = (unsigned)(nb >> 48);
                    unsigned tailB = (unsigned)(nb >> 32) & 0xFFFFu;
                    unsigned szB   = (unsigned)(nb >> 16) & 0xFFFFu;
                    unsigned slB   = (unsigned)nb & 0xFFFFu;
                    unsigned long long merged =
                          ((unsigned long long)headA << 48)
                        | ((unsigned long long)tailB << 32)
                        | ((unsigned long long)(szA + szB) << 16)
                        | (unsigned long long)(slA + slB);
                    if (lane == 0) {
                        mrA[m] = (headA << 16) | headB;     // global fire-and-forget
                        mrB[m] = (szA << 16) | szB;
                        mSS[m] = slA * slB;
                        mED[m] = (unsigned short)ce;
                        nextS[tailA] = (unsigned short)headB;
                        nodeS[rb2]   = merged;
                        parentS[ra2] = (unsigned short)rb2;
                    }
                    m++;
                    if (haveNext) {
                        if (nra == ra2) npa = rb2;
                        if (nrb == ra2) npb = rb2;
                        if (nra == rb2) nna = merged;
                        if (nrb == rb2) nnb = merged;
                    }
                }
            }
            cra = nra; crb = nrb; ce = ne; cpa = npa; cpb = npb; cna = nna; cnb = nnb;
            haveCur = haveNext;
        }
        __builtin_amdgcn_sched_barrier(0);
        asm volatile("s_waitcnt lgkmcnt(0)" ::: "memory");
    }
    if (lane == 0) *(int*)(mg + MRG_M) = m;
    for (int i = lane; i < NPIX; i += 64) mNX[i] = nextS[i];
}

// ============================ K4: list-rank + chunked prefix dots + loss ============================
__global__ __launch_bounds__(256, 2)
void k4_weights(const float* __restrict__ t_glob,
                const float* __restrict__ p_glob,
                const unsigned short* __restrict__ pixLab_g,
                const int* __restrict__ Kg,
                const char* __restrict__ mrg_base,
                float* __restrict__ out) {
    const int tid = threadIdx.x;
    const int wg  = blockIdx.x;
    const int sgn = wg & 1;
    const int tileId = wg >> 1;
    const int bat = tileId >> 6;
    const int tile = tileId & 63;
    const int tr = tile >> 3, tc = tile & 7;

    __shared__ float          pT[NPIX];
    __shared__ unsigned char  bgS[NPIX];
    __shared__ unsigned short pixLab[NPIX];
    __shared__ unsigned short posS[NPIX];
    __shared__ unsigned int   mRecA[NMERGE];
    __shared__ unsigned int   mRecB[NMERGE];
    __shared__ unsigned int   mSaSb[NMERGE];
    __shared__ unsigned int   commonW[NMERGE];
    __shared__ unsigned short mEd[NMERGE];
    __shared__ __align__(16) unsigned long long big[2564];
    __shared__ unsigned wsumSh;
    __shared__ float lossSh;

    const char* mg = mrg_base + (size_t)wg * MRG_STRIDE;
    const int M = *(const int*)(mg + MRG_M);
    const int K = Kg[tileId];
    const unsigned int*   mrA = (const unsigned int*)(mg + MRG_RA);
    const unsigned int*   mrB = (const unsigned int*)(mg + MRG_RB);
    const unsigned int*   mSS = (const unsigned int*)(mg + MRG_SS);
    const unsigned short* mED = (const unsigned short*)(mg + MRG_ED);
    const unsigned short* mNX = (const unsigned short*)(mg + MRG_NXT);

    for (int i = tid; i < NPIX; i += 256) {
        int y = i >> 5, x = i & 31;
        int gidx = bat * 65536 + (tr * 32 + y) * 256 + (tc * 32 + x);
        pT[i] = p_glob[gidx];
        bgS[i] = (t_glob[gidx] == 0.0f) ? 1 : 0;
        pixLab[i] = pixLab_g[tileId * NPIX + i];
    }
    for (int j = tid; j < M; j += 256) {
        mRecA[j] = mrA[j];
        mRecB[j] = mrB[j];
        mSaSb[j] = mSS[j];
        mEd[j]   = mED[j];
        commonW[j] = 0;
    }

    // ---- Wyllie list ranking -> posS ----
    unsigned short* n0 = (unsigned short*)big;
    unsigned short* n1 = n0 + 1024;
    unsigned short* d0 = n0 + 2048;
    unsigned short* d1 = n0 + 3072;
    for (int i = tid; i < NPIX; i += 256) { n0[i] = mNX[i]; d0[i] = 1; }
    __syncthreads();
    for (int s = 0; s < 10; s++) {
        unsigned short* sn = (s & 1) ? n1 : n0;
        unsigned short* sd = (s & 1) ? d1 : d0;
        unsigned short* dn = (s & 1) ? n0 : n1;
        unsigned short* dd = (s & 1) ? d0 : d1;
        for (int i = tid; i < NPIX; i += 256) {
            unsigned nx = sn[i];
            unsigned dv = sd[i];
            if (nx != NIL) { dv += sd[nx]; nx = sn[nx]; }
            dn[i] = (unsigned short)nx;
            dd[i] = (unsigned short)dv;
        }
        __syncthreads();
    }
    for (int i = tid; i < NPIX; i += 256)
        posS[i] = (unsigned short)(NPIX - (int)d0[i]);
    __syncthreads();

    // ---- chunked label prefix sums + per-merge dots ----
    unsigned*       P32 = (unsigned*)big;
    uint4*          P4  = (uint4*)big;
    unsigned*       scr = P32 + 4100;
    uint4*          S4  = (uint4*)scr;
    unsigned short* P16 = (unsigned short*)big;
    for (int base = 0; base < K; base += CHUNK) {
        for (int idx = tid; idx < 4100; idx += 256) P32[idx] = 0;
        __syncthreads();
        for (int i = tid; i < NPIX; i += 256) {
            unsigned l = pixLab[i];
            if (l != NIL && l >= (unsigned)base && l < (unsigned)(base + CHUNK))
                P16[(posS[i] + 1) * 8 + (l - base)] = 1;
        }
        __syncthreads();
        {
            int r0 = tid * 4 + 1;
            uint4 acc = P4[r0];
            for (int rr = r0 + 1; rr <= r0 + 3; rr++) { acc = add4(acc, P4[rr]); P4[rr] = acc; }
            S4[tid] = acc;
            __syncthreads();
            if (tid < 64) {
                uint4 s0 = S4[tid * 4], s1 = S4[tid * 4 + 1], s2 = S4[tid * 4 + 2], s3 = S4[tid * 4 + 3];
                uint4 t1 = add4(s0, s1), t2 = add4(t1, s2), t3 = add4(t2, s3);
                uint4 run = t3;
                #pragma unroll
                for (int d = 1; d < 64; d <<= 1) {
                    uint4 o;
                    o.x = __shfl_up(run.x, d, 64);
                    o.y = __shfl_up(run.y, d, 64);
                    o.z = __shfl_up(run.z, d, 64);
                    o.w = __shfl_up(run.w, d, 64);
                    if (tid >= d) run = add4(run, o);
                }
                uint4 off = sub4(run, t3);
                S4[tid * 4]     = add4(s0, off);
                S4[tid * 4 + 1] = add4(t1, off);
                S4[tid * 4 + 2] = add4(t2, off);
                S4[tid * 4 + 3] = add4(t3, off);
            }
            __syncthreads();
            if (tid > 0) {
                uint4 off = S4[tid - 1];
                for (int rr = r0; rr <= r0 + 3; rr++) P4[rr] = add4(P4[rr], off);
            }
        }
        __syncthreads();
        for (int j = tid; j < M; j += 256) {
            unsigned recA = mRecA[j], recB = mRecB[j];
            unsigned aS = posS[recA >> 16];
            unsigned bS = posS[recA & 0xFFFFu];
            uint4 da = sub4(P4[aS + (recB >> 16)], P4[aS]);
            uint4 db = sub4(P4[bS + (recB & 0xFFFFu)], P4[bS]);
            unsigned acc;
            acc  = (da.x & 0xFFFFu) * (db.x & 0xFFFFu) + (da.x >> 16) * (db.x >> 16);
            acc += (da.y & 0xFFFFu) * (db.y & 0xFFFFu) + (da.y >> 16) * (db.y >> 16);
            acc += (da.z & 0xFFFFu) * (db.z & 0xFFFFu) + (da.z >> 16) * (db.z >> 16);
            acc += (da.w & 0xFFFFu) * (db.w & 0xFFFFu) + (da.w >> 16) * (db.w >> 16);
            commonW[j] += acc;
        }
        __syncthreads();
    }

    // ---- normalize + mask + loss ----
    if (tid == 0) { wsumSh = 0; lossSh = 0.0f; }
    __syncthreads();
    unsigned wloc = 0;
    for (int j = tid; j < M; j += 256)
        wloc += (sgn == 0) ? (mSaSb[j] - commonW[j]) : commonW[j];
    if (wloc) atomicAdd(&wsumSh, wloc);
    __syncthreads();
    const unsigned wsum = wsumSh;
    if (wsum > 0) {
        const double inv = 1.0 / (double)wsum;
        float lloc = 0.0f;
        for (int j = tid; j < M; j += 256) {
            unsigned w = (sgn == 0) ? (mSaSb[j] - commonW[j]) : commonW[j];
            if (!w) continue;
            int e = mEd[j];
            int a, b; edge_ab(e, a, b);
            int nfg = (int)(!bgS[a]) + (int)(!bgS[b]);
            bool keep = (sgn == 0) ? (nfg == 0) : (nfg >= 1);
            if (!keep) continue;
            float wn = (float)((double)w * inv);
            float fa, fb;
            if (sgn == 0) { fa = pT[a] * pT[a];            fb = pT[b] * pT[b]; }
            else { float da = 20.0f - pT[a], db = 20.0f - pT[b]; fa = da * da; fb = db * db; }
            lloc += wn * (fa + fb);
        }
        if (lloc != 0.0f) atomicAdd(&lossSh, lloc);
        __syncthreads();
        if (tid == 0 && lossSh != 0.0f) atomicAdd(out, lossSh);
    }
}

// ============================ fallback: R4 monolith (used if ws too small) ============================
__global__ __launch_bounds__(256, 2)
void malis_mono(const float* __restrict__ t_glob,
                const float* __restrict__ p_glob,
                float* __restrict__ out) {
    const int tid  = threadIdx.x;
    const int wg   = blockIdx.x;
    const int sgn  = wg & 1;
    const int tileId = wg >> 1;
    const int bat  = tileId >> 6;
    const int tile = tileId & 63;
    const int tr = tile >> 3, tc = tile & 7;

    __shared__ float          pT[NPIX];
    __shared__ unsigned char  bgS[NPIX];
    __shared__ unsigned short pixLab[NPIX];
    __shared__ unsigned short parentS[NPIX];
    __shared__ unsigned short nextS[NPIX];
    __shared__ unsigned long long nodeS[NPIX];
    __shared__ unsigned short posS[NPIX];
    __shared__ unsigned short orderS[NEDGE];
    __shared__ unsigned int   mRecA[NMERGE];
    __shared__ unsigned int   mRecB[NMERGE];
    __shared__ unsigned short mEd[NMERGE];
    __shared__ unsigned int   mSaSb[NMERGE];
    __shared__ unsigned int   commonW[NMERGE];
    __shared__ __align__(16) unsigned long long big[2564];
    __shared__ int   kprimeSh, mCountSh;
    __shared__ unsigned wsumSh;
    __shared__ float lossSh;

    for (int i = tid; i < NPIX; i += 256) {
        int y = i >> 5, x = i & 31;
        int gidx = bat * 65536 + (tr * 32 + y) * 256 + (tc * 32 + x);
        pT[i] = p_glob[gidx];
        bgS[i] = (t_glob[gidx] == 0.0f) ? 1 : 0;
    }
    __syncthreads();

    unsigned short* labS = (unsigned short*)big;
    unsigned int*   cntS = (unsigned int*)(((char*)big) + 2048);
    if (tid < 64) {
        const int lane = tid;
        if (lane < 32) {
            #pragma unroll
            for (int x = 0; x < 32; x++) {
                int i = lane * 32 + x;
                labS[i] = bgS[i] ? (unsigned short)i : (unsigned short)NIL;
            }
        }
        while (true) {
            bool changed = false;
            if (lane < 32) {
                const int base = lane * 32;
                unsigned short v[32];
                #pragma unroll
                for (int x = 0; x < 32; x++) v[x] = labS[base + x];
                unsigned run = NIL;
                #pragma unroll
                for (int x = 0; x < 32; x++) {
                    unsigned val = v[x];
                    if (val == NIL) { run = NIL; }
                    else { unsigned nv = min(run, val); changed |= (nv != val); v[x] = (unsigned short)nv; run = nv; }
                }
                run = NIL;
                #pragma unroll
                for (int x = 31; x >= 0; x--) {
                    unsigned val = v[x];
                    if (val == NIL) { run = NIL; }
                    else { unsigned nv = min(run, val); changed |= (nv != val); v[x] = (unsigned short)nv; run = nv; }
                }
                #pragma unroll
                for (int x = 0; x < 32; x++) labS[base + x] = v[x];
            }
            if (lane < 32) {
                unsigned short c[32];
                #pragma unroll
                for (int k = 0; k < 32; k++) c[k] = labS[k * 32 + lane];
                unsigned run = NIL;
                #pragma unroll
                for (int k = 0; k < 32; k++) {
                    unsigned val = c[k];
                    if (val == NIL) { run = NIL; }
                    else { unsigned nv = min(run, val); changed |= (nv != val); c[k] = (unsigned short)nv; run = nv; }
                }
                run = NIL;
                #pragma unroll
                for (int k = 31; k >= 0; k--) {
                    unsigned val = c[k];
                    if (val == NIL) { run = NIL; }
                    else { unsigned nv = min(run, val); changed |= (nv != val); c[k] = (unsigned short)nv; run = nv; }
                }
                #pragma unroll
                for (int k = 0; k < 32; k++) labS[k * 32 + lane] = c[k];
            }
            if (!__any(changed)) break;
        }
    }
    __syncthreads();

    for (int i = tid; i < NPIX; i += 256) cntS[i] = 0;
    if (tid == 0) kprimeSh = 0;
    __syncthreads();
    for (int i = tid; i < NPIX; i += 256)
        if (bgS[i]) atomicAdd(&cntS[labS[i]], 1u);
    __syncthreads();
    for (int i = tid; i < NPIX; i += 256) {
        if (bgS[i] && (int)labS[i] == i) {
            unsigned id = (cntS[i] >= 2) ? (unsigned)atomicAdd(&kprimeSh, 1) : NIL;
            cntS[i] = id;
        }
    }
    __syncthreads();
    for (int i = tid; i < NPIX; i += 256)
        pixLab[i] = bgS[i] ? (unsigned short)cntS[labS[i]] : (unsigned short)NIL;
    __syncthreads();
    const int K = kprimeSh;

    unsigned long long* keys = big;
    for (int k = tid; k < SORTN; k += 256) {
        unsigned long long key = 0ULL;
        if (k < NEDGE) {
            int a, b; edge_ab(k, a, b);
            float cost = pT[a] + pT[b];
            int nfg = (int)(!bgS[a]) + (int)(!bgS[b]);
            if (sgn == 0) { if (nfg == 2) cost = 20.0f; }
            else          { if (nfg == 0) cost = 0.0f;  }
            key = ((unsigned long long)__float_as_uint(cost) << 16)
                | (unsigned long long)(0xFFFFu - (unsigned)k);
        }
        keys[k] = key;
    }
    __syncthreads();
    for (int kk = 2; kk <= SORTN; kk <<= 1) {
        for (int jj = kk >> 1; jj > 0; jj >>= 1) {
            for (int i = tid; i < SORTN; i += 256) {
                int ixj = i ^ jj;
                if (ixj > i) {
                    unsigned long long A = keys[i], Bv = keys[ixj];
                    bool descBlk = ((i & kk) == 0);
                    if ((A < Bv) == descBlk) { keys[i] = Bv; keys[ixj] = A; }
                }
            }
            __syncthreads();
        }
    }
    for (int k = tid; k < NEDGE; k += 256)
        orderS[k] = (unsigned short)(0xFFFFu - (unsigned)(keys[k] & 0xFFFFULL));
    for (int i = tid; i < NPIX; i += 256) {
        parentS[i] = (unsigned short)i;
        nodeS[i] = ((unsigned long long)i << 48) | ((unsigned long long)i << 32)
                 | (1ULL << 16) | (unsigned long long)bgS[i];
        nextS[i] = (unsigned short)NIL;
    }
    __syncthreads();

    if (tid < 64) {
        const int lane = tid;
        int m = 0;
        for (int kb = 0; kb < NEDGE; kb += 64) {
            int e = orderS[kb + lane];
            int a, b; edge_ab(e, a, b);
            unsigned ra = (unsigned)a, rb = (unsigned)b;
            while (true) {
                unsigned pa = parentS[ra];
                unsigned pb = parentS[rb];
                if (pa == ra && pb == rb) break;
                if (pa != ra) { unsigned ga = parentS[pa]; parentS[ra] = (unsigned short)ga; ra = ga; }
                if (pb != rb) { unsigned gb = parentS[pb]; parentS[rb] = (unsigned short)gb; rb = gb; }
            }
            unsigned long long spec = ((unsigned long long)(unsigned)e << 32)
                                    | ((unsigned long long)ra << 16) | (unsigned long long)rb;
            unsigned long long candm = __ballot(ra != rb);

            bool haveCur = false;
            unsigned cra = 0, crb = 0, ce = 0, cpa = 0, cpb = 0;
            unsigned long long cna = 0, cnb = 0;
            while (candm != 0ULL || haveCur) {
                bool haveNext = (candm != 0ULL);
                unsigned nra = 0, nrb = 0, ne = 0, npa = 0, npb = 0;
                unsigned long long nna = 0, nnb = 0;
                if (haveNext) {
                    int j = __ffsll((long long)candm) - 1;
                    candm &= candm - 1ULL;
                    unsigned long long sj = __shfl(spec, j);
                    ne  = (unsigned)(sj >> 32);
                    nra = (unsigned)(sj >> 16) & 0xFFFFu;
                    nrb = (unsigned)sj & 0xFFFFu;
                    npa = parentS[nra];
                    npb = parentS[nrb];
                    nna = nodeS[nra];
                    nnb = nodeS[nrb];
                }
                if (haveCur) {
                    unsigned ra2 = cra, rb2 = crb;
                    unsigned long long na = cna, nb = cnb;
                    bool ok = true;
                    if (cpa != ra2 || cpb != rb2) {
                        unsigned r = cpa;
                        while (true) { unsigned p = parentS[r]; if (p == r) break; r = p; }
                        ra2 = r;
                        r = cpb;
                        while (true) { unsigned p = parentS[r]; if (p == r) break; r = p; }
                        rb2 = r;
                        if (ra2 == rb2) ok = false;
                        else { na = nodeS[ra2]; nb = nodeS[rb2]; }
                    }
                    if (ok) {
                        unsigned headA = (unsigned)(na >> 48);
                        unsigned tailA = (unsigned)(na >> 32) & 0xFFFFu;
                        unsigned szA   = (unsigned)(na >> 16) & 0xFFFFu;
                        unsigned slA   = (unsigned)na & 0xFFFFu;
                        unsigned headB = (unsigned)(nb >> 48);
                        unsigned tailB = (unsigned)(nb >> 32) & 0xFFFFu;
                        unsigned szB   = (unsigned)(nb >> 16) & 0xFFFFu;
                        unsigned slB   = (unsigned)nb & 0xFFFFu;
                        unsigned long long merged =
                              ((unsigned long long)headA << 48)
                            | ((unsigned long long)tailB << 32)
                            | ((unsigned long long)(szA + szB) << 16)
                            | (unsigned long long)(slA + slB);
                        if (lane == 0) {
                            mRecA[m] = (headA << 16) | headB;
                            mRecB[m] = (szA << 16) | szB;
                            mSaSb[m] = slA * slB;
                            mEd[m]   = (unsigned short)ce;
                            nextS[tailA] = (unsigned short)headB;
                            nodeS[rb2]   = merged;
                            parentS[ra2] = (unsigned short)rb2;
                        }
                        m++;
                        if (haveNext) {
                            if (nra == ra2) npa = rb2;
                            if (nrb == ra2) npb = rb2;
                            if (nra == rb2) nna = merged;
                            if (nrb == rb2) nnb = merged;
                        }
                    }
                }
                cra = nra; crb = nrb; ce = ne; cpa = npa; cpb = npb; cna = nna; cnb = nnb;
                haveCur = haveNext;
            }
        }
        if (lane == 0) mCountSh = m;
    }
    __syncthreads();
    const int M = mCountSh;
    for (int j = tid; j < M; j += 256) commonW[j] = 0;

    unsigned short* n0 = (unsigned short*)big;
    unsigned short* n1 = n0 + 1024;
    unsigned short* d0 = n0 + 2048;
    unsigned short* d1 = n0 + 3072;
    for (int i = tid; i < NPIX; i += 256) { n0[i] = nextS[i]; d0[i] = 1; }
    __syncthreads();
    for (int s = 0; s < 10; s++) {
        unsigned short* sn = (s & 1) ? n1 : n0;
        unsigned short* sd = (s & 1) ? d1 : d0;
        unsigned short* dn = (s & 1) ? n0 : n1;
        unsigned short* dd = (s & 1) ? d0 : d1;
        for (int i = tid; i < NPIX; i += 256) {
            unsigned nx = sn[i];
            unsigned dv = sd[i];
            if (nx != NIL) { dv += sd[nx]; nx = sn[nx]; }
            dn[i] = (unsigned short)nx;
            dd[i] = (unsigned short)dv;
        }
        __syncthreads();
    }
    for (int i = tid; i < NPIX; i += 256)
        posS[i] = (unsigned short)(NPIX - (int)d0[i]);
    __syncthreads();

    unsigned*       P32 = (unsigned*)big;
    uint4*          P4  = (uint4*)big;
    unsigned*       scr = P32 + 4100;
    uint4*          S4  = (uint4*)scr;
    unsigned short* P16 = (unsigned short*)big;
    for (int base = 0; base < K; base += CHUNK) {
        for (int idx = tid; idx < 4100; idx += 256) P32[idx] = 0;
        __syncthreads();
        for (int i = tid; i < NPIX; i += 256) {
            unsigned l = pixLab[i];
            if (l != NIL && l >= (unsigned)base && l < (unsigned)(base + CHUNK))
                P16[(posS[i] + 1) * 8 + (l - base)] = 1;
        }
        __syncthreads();
        {
            int r0 = tid * 4 + 1;
            uint4 acc = P4[r0];
            for (int rr = r0 + 1; rr <= r0 + 3; rr++) { acc = add4(acc, P4[rr]); P4[rr] = acc; }
            S4[tid] = acc;
            __syncthreads();
            if (tid < 64) {
                uint4 s0 = S4[tid * 4], s1 = S4[tid * 4 + 1], s2 = S4[tid * 4 + 2], s3 = S4[tid * 4 + 3];
                uint4 t1 = add4(s0, s1), t2 = add4(t1, s2), t3 = add4(t2, s3);
                uint4 run = t3;
                #pragma unroll
                for (int d = 1; d < 64; d <<= 1) {
                    uint4 o;
                    o.x = __shfl_up(run.x, d, 64);
                    o.y = __shfl_up(run.y, d, 64);
                    o.z = __shfl_up(run.z, d, 64);
                    o.w = __shfl_up(run.w, d, 64);
                    if (tid >= d) run = add4(run, o);
                }
                uint4 off = sub4(run, t3);
                S4[tid * 4]     = add4(s0, off);
                S4[tid * 4 + 1] = add4(t1, off);
                S4[tid * 4 + 2] = add4(t2, off);
                S4[tid * 4 + 3] = add4(t3, off);
            }
            __syncthreads();
            if (tid > 0) {
                uint4 off = S4[tid - 1];
                for (int rr = r0; rr <= r0 + 3; rr++) P4[rr] = add4(P4[rr], off);
            }
        }
        __syncthreads();
        for (int j = tid; j < M; j += 256) {
            unsigned recA = mRecA[j], recB = mRecB[j];
            unsigned aS = posS[recA >> 16];
            unsigned bS = posS[recA & 0xFFFFu];
            uint4 da = sub4(P4[aS + (recB >> 16)], P4[aS]);
            uint4 db = sub4(P4[bS + (recB & 0xFFFFu)], P4[bS]);
            unsigned acc;
            acc  = (da.x & 0xFFFFu) * (db.x & 0xFFFFu) + (da.x >> 16) * (db.x >> 16);
            acc += (da.y & 0xFFFFu) * (db.y & 0xFFFFu) + (da.y >> 16) * (db.y >> 16);
            acc += (da.z & 0xFFFFu) * (db.z & 0xFFFFu) + (da.z >> 16) * (db.z >> 16);
            acc += (da.w & 0xFFFFu) * (db.w & 0xFFFFu) + (da.w >> 16) * (db.w >> 16);
            commonW[j] += acc;
        }
        __syncthreads();
    }

    if (tid == 0) { wsumSh = 0; lossSh = 0.0f; }
    __syncthreads();
    unsigned wloc = 0;
    for (int j = tid; j < M; j += 256)
        wloc += (sgn == 0) ? (mSaSb[j] - commonW[j]) : commonW[j];
    if (wloc) atomicAdd(&wsumSh, wloc);
    __syncthreads();
    const unsigned wsum = wsumSh;
    if (wsum > 0) {
        const double inv = 1.0 / (double)wsum;
        float lloc = 0.0f;
        for (int j = tid; j < M; j += 256) {
            unsigned w = (sgn == 0) ? (mSaSb[j] - commonW[j]) : commonW[j];
            if (!w) continue;
            int e = mEd[j];
            int a, b; edge_ab(e, a, b);
            int nfg = (int)(!bgS[a]) + (int)(!bgS[b]);
            bool keep = (sgn == 0) ? (nfg == 0) : (nfg >= 1);
            if (!keep) continue;
            float wn = (float)((double)w * inv);
            float fa, fb;
            if (sgn == 0) { fa = pT[a] * pT[a];            fb = pT[b] * pT[b]; }
            else { float da = 20.0f - pT[a], db = 20.0f - pT[b]; fa = da * da; fb = db * db; }
            lloc += wn * (fa + fb);
        }
        if (lloc != 0.0f) atomicAdd(&lossSh, lloc);
        __syncthreads();
        if (tid == 0 && lossSh != 0.0f) atomicAdd(out, lossSh);
    }
}

extern "C" void kernel_launch(void* const* d_in, const int* in_sizes, int n_in,
                              void* d_out, int out_size, void* d_ws, size_t ws_size,
                              hipStream_t stream) {
    const float* y_true = (const float*)d_in[0];
    const float* y_pred = (const float*)d_in[1];
    float* out = (float*)d_out;
    const int B  = in_sizes[0] / (256 * 256);
    const int nT = B * 64;
    const int nW = nT * 2;

    const size_t offK   = (size_t)nT * 2048;
    const size_t offOrd = offK + (((size_t)nT * 4 + 255) & ~(size_t)255);
    const size_t offMrg = offOrd + (size_t)nW * 4096;
    const size_t need   = offMrg + (size_t)nW * MRG_STRIDE;

    hipMemsetAsync(d_out, 0, (size_t)out_size * sizeof(float), stream);

    if (ws_size >= need) {
        char* ws = (char*)d_ws;
        unsigned short* pixLab_g = (unsigned short*)ws;
        int*            Kg       = (int*)(ws + offK);
        unsigned short* ord_g    = (unsigned short*)(ws + offOrd);
        char*           mrg      = ws + offMrg;
        hipLaunchKernelGGL(k1_ccl,     dim3(nT), dim3(256), 0, stream, y_true, pixLab_g, Kg);
        hipLaunchKernelGGL(k2_sort,    dim3(nW), dim3(256), 0, stream, y_true, y_pred, ord_g);
        hipLaunchKernelGGL(k3_kruskal, dim3(nW), dim3(64),  0, stream, y_true, ord_g, mrg);
        hipLaunchKernelGGL(k4_weights, dim3(nW), dim3(256), 0, stream, y_true, y_pred,
                           pixLab_g, Kg, mrg, out);
    } else {
        hipLaunchKernelGGL(malis_mono, dim3(nW), dim3(256), 0, stream, y_true, y_pred, out);
    }
}

// Round 6
// 701.220 us; speedup vs baseline: 1.0189x; 1.0189x over previous
//
#include <hip/hip_runtime.h>

#define NPIX   1024   // 32*32
#define NEH    992    // horizontal edges 32*31
#define NEDGE  1984   // + vertical 31*32
#define SORTN  2048
#define CHUNK  8      // labels per phase-2 pass
#define NMERGE 1023
#define NIL    0xFFFFu

// per-(tile,sgn) merge-record block in ws (20480 B stride)
#define MRG_STRIDE 20480
#define MRG_M      0
#define MRG_RA     256
#define MRG_RB     4608
#define MRG_SS     8960
#define MRG_ED     13312
#define MRG_NXT    15616

__device__ __forceinline__ void edge_ab(int e, int& a, int& b) {
    if (e < NEH) { int y = e / 31; int x = e - y * 31; a = y * 32 + x; b = a + 1; }
    else         { int ev = e - NEH; a = ev; b = ev + 32; }
}

__device__ __forceinline__ uint4 add4(uint4 x, uint4 y) {
    return make_uint4(x.x + y.x, x.y + y.y, x.z + y.z, x.w + y.w);
}
__device__ __forceinline__ uint4 sub4(uint4 x, uint4 y) {
    return make_uint4(x.x - y.x, x.y - y.y, x.z - y.z, x.w - y.w);
}

// ============================ K1: CCL + label compact (per tile) ============================
__global__ __launch_bounds__(256, 2)
void k1_ccl(const float* __restrict__ t_glob,
            unsigned short* __restrict__ pixLab_g,
            int* __restrict__ Kg) {
    const int tid = threadIdx.x;
    const int tileId = blockIdx.x;
    const int bat = tileId >> 6;
    const int tile = tileId & 63;
    const int tr = tile >> 3, tc = tile & 7;

    __shared__ unsigned char  bgS[NPIX];
    __shared__ unsigned short labS[NPIX];
    __shared__ unsigned int   cntS[NPIX];
    __shared__ int kprimeSh;

    for (int i = tid; i < NPIX; i += 256) {
        int y = i >> 5, x = i & 31;
        int gidx = bat * 65536 + (tr * 32 + y) * 256 + (tc * 32 + x);
        bgS[i] = (t_glob[gidx] == 0.0f) ? 1 : 0;
    }
    __syncthreads();

    if (tid < 64) {
        const int lane = tid;
        if (lane < 32) {
            #pragma unroll
            for (int x = 0; x < 32; x++) {
                int i = lane * 32 + x;
                labS[i] = bgS[i] ? (unsigned short)i : (unsigned short)NIL;
            }
        }
        while (true) {
            bool changed = false;
            if (lane < 32) {
                const int base = lane * 32;
                unsigned short v[32];
                #pragma unroll
                for (int x = 0; x < 32; x++) v[x] = labS[base + x];
                unsigned run = NIL;
                #pragma unroll
                for (int x = 0; x < 32; x++) {
                    unsigned val = v[x];
                    if (val == NIL) { run = NIL; }
                    else { unsigned nv = min(run, val); changed |= (nv != val); v[x] = (unsigned short)nv; run = nv; }
                }
                run = NIL;
                #pragma unroll
                for (int x = 31; x >= 0; x--) {
                    unsigned val = v[x];
                    if (val == NIL) { run = NIL; }
                    else { unsigned nv = min(run, val); changed |= (nv != val); v[x] = (unsigned short)nv; run = nv; }
                }
                #pragma unroll
                for (int x = 0; x < 32; x++) labS[base + x] = v[x];
            }
            if (lane < 32) {
                unsigned short c[32];
                #pragma unroll
                for (int k = 0; k < 32; k++) c[k] = labS[k * 32 + lane];
                unsigned run = NIL;
                #pragma unroll
                for (int k = 0; k < 32; k++) {
                    unsigned val = c[k];
                    if (val == NIL) { run = NIL; }
                    else { unsigned nv = min(run, val); changed |= (nv != val); c[k] = (unsigned short)nv; run = nv; }
                }
                run = NIL;
                #pragma unroll
                for (int k = 31; k >= 0; k--) {
                    unsigned val = c[k];
                    if (val == NIL) { run = NIL; }
                    else { unsigned nv = min(run, val); changed |= (nv != val); c[k] = (unsigned short)nv; run = nv; }
                }
                #pragma unroll
                for (int k = 0; k < 32; k++) labS[k * 32 + lane] = c[k];
            }
            if (!__any(changed)) break;
        }
    }
    __syncthreads();

    for (int i = tid; i < NPIX; i += 256) cntS[i] = 0;
    if (tid == 0) kprimeSh = 0;
    __syncthreads();
    for (int i = tid; i < NPIX; i += 256)
        if (bgS[i]) atomicAdd(&cntS[labS[i]], 1u);
    __syncthreads();
    for (int i = tid; i < NPIX; i += 256) {
        if (bgS[i] && (int)labS[i] == i) {
            unsigned id = (cntS[i] >= 2) ? (unsigned)atomicAdd(&kprimeSh, 1) : NIL;
            cntS[i] = id;
        }
    }
    __syncthreads();
    for (int i = tid; i < NPIX; i += 256)
        pixLab_g[tileId * NPIX + i] = bgS[i] ? (unsigned short)cntS[labS[i]] : (unsigned short)NIL;
    if (tid == 0) Kg[tileId] = kprimeSh;
}

// ============================ K2: edge-key bitonic sort (per tile,sgn) ============================
__global__ __launch_bounds__(256, 2)
void k2_sort(const float* __restrict__ t_glob,
             const float* __restrict__ p_glob,
             unsigned short* __restrict__ ord_g) {
    const int tid = threadIdx.x;
    const int wg  = blockIdx.x;
    const int sgn = wg & 1;
    const int tileId = wg >> 1;
    const int bat = tileId >> 6;
    const int tile = tileId & 63;
    const int tr = tile >> 3, tc = tile & 7;

    __shared__ float pT[NPIX];
    __shared__ unsigned char bgS[NPIX];
    __shared__ unsigned long long keys[SORTN];

    for (int i = tid; i < NPIX; i += 256) {
        int y = i >> 5, x = i & 31;
        int gidx = bat * 65536 + (tr * 32 + y) * 256 + (tc * 32 + x);
        pT[i] = p_glob[gidx];
        bgS[i] = (t_glob[gidx] == 0.0f) ? 1 : 0;
    }
    __syncthreads();

    for (int k = tid; k < SORTN; k += 256) {
        unsigned long long key = 0ULL;
        if (k < NEDGE) {
            int a, b; edge_ab(k, a, b);
            float cost = pT[a] + pT[b];
            int nfg = (int)(!bgS[a]) + (int)(!bgS[b]);
            if (sgn == 0) { if (nfg == 2) cost = 20.0f; }
            else          { if (nfg == 0) cost = 0.0f;  }
            key = ((unsigned long long)__float_as_uint(cost) << 16)
                | (unsigned long long)(0xFFFFu - (unsigned)k);
        }
        keys[k] = key;
    }
    __syncthreads();
    for (int kk = 2; kk <= SORTN; kk <<= 1) {
        for (int jj = kk >> 1; jj > 0; jj >>= 1) {
            for (int i = tid; i < SORTN; i += 256) {
                int ixj = i ^ jj;
                if (ixj > i) {
                    unsigned long long A = keys[i], Bv = keys[ixj];
                    bool descBlk = ((i & kk) == 0);
                    if ((A < Bv) == descBlk) { keys[i] = Bv; keys[ixj] = A; }
                }
            }
            __syncthreads();
        }
    }
    for (int k = tid; k < NEDGE; k += 256)
        ord_g[(size_t)wg * SORTN + k] = (unsigned short)(0xFFFFu - (unsigned)(keys[k] & 0xFFFFULL));
}

// ============================ K3: Kruskal via register-resident merge log ============================
__global__ __launch_bounds__(64)
void k3_kruskal(const float* __restrict__ t_glob,
                const unsigned short* __restrict__ ord_g,
                char* __restrict__ mrg_base) {
    const int lane = threadIdx.x;
    const int wg  = blockIdx.x;
    const int tileId = wg >> 1;
    const int bat = tileId >> 6;
    const int tile = tileId & 63;
    const int tr = tile >> 3, tc = tile & 7;

    __shared__ unsigned short parentS[NPIX];
    __shared__ unsigned long long nodeS[NPIX];
    __shared__ unsigned short nextS[NPIX];

    char* mg = mrg_base + (size_t)wg * MRG_STRIDE;
    unsigned int*   mrA = (unsigned int*)(mg + MRG_RA);
    unsigned int*   mrB = (unsigned int*)(mg + MRG_RB);
    unsigned int*   mSS = (unsigned int*)(mg + MRG_SS);
    unsigned short* mED = (unsigned short*)(mg + MRG_ED);
    unsigned short* mNX = (unsigned short*)(mg + MRG_NXT);
    const unsigned short* ord = ord_g + (size_t)wg * SORTN;

    for (int i = lane; i < NPIX; i += 64) {
        int y = i >> 5, x = i & 31;
        int gidx = bat * 65536 + (tr * 32 + y) * 256 + (tc * 32 + x);
        unsigned bg = (t_glob[gidx] == 0.0f) ? 1u : 0u;
        parentS[i] = (unsigned short)i;
        nodeS[i] = ((unsigned long long)i << 48) | ((unsigned long long)i << 32)
                 | (1ULL << 16) | (unsigned long long)bg;
        nextS[i] = (unsigned short)NIL;
    }
    __syncthreads();

    int m = 0;
    for (int kb = 0; kb < NEDGE; kb += 64) {      // 31 exact batches
        // ---- spec phase: all 64 lanes find roots (concurrent path-halving) ----
        int e = ord[kb + lane];
        int a, b; edge_ab(e, a, b);
        unsigned ra = (unsigned)a, rb = (unsigned)b;
        while (true) {
            unsigned pa = parentS[ra];
            unsigned pb = parentS[rb];
            if (pa == ra && pb == rb) break;
            if (pa != ra) { unsigned ga = parentS[pa]; parentS[ra] = (unsigned short)ga; ra = ga; }
            if (pb != rb) { unsigned gb = parentS[pb]; parentS[rb] = (unsigned short)gb; rb = gb; }
        }
        unsigned specAB = (ra << 16) | rb;                 // roots as of batch start
        unsigned long long na = nodeS[ra];                 // node values as of batch start
        unsigned long long nb = nodeS[rb];
        unsigned long long candm = __ballot(ra != rb);     // spec-equal => definitely connected

        // ---- serial log phase: wave-uniform; per-lane registers hold the log ----
        unsigned logRa = 0xFFFFFFFFu;                      // root consumed at entry 'lane'
        unsigned logRb = 0xFFFFFFFFu;                      // root it merged into
        unsigned long long logNode = 0;                    // merged node value at that entry
        int logCount = 0;
        while (candm != 0ULL) {
            int j = __ffsll((long long)candm) - 1;
            candm &= candm - 1ULL;
            unsigned sAB = __shfl(specAB, j);
            unsigned cra = sAB >> 16;
            unsigned crb = sAB & 0xFFFFu;
            // resolve roots through the in-register log (logRa values are distinct)
            while (true) {
                unsigned long long hit = __ballot(logRa == cra);
                if (hit == 0ULL) break;
                cra = __shfl(logRb, __ffsll((long long)hit) - 1);
            }
            while (true) {
                unsigned long long hit = __ballot(logRa == crb);
                if (hit == 0ULL) break;
                crb = __shfl(logRb, __ffsll((long long)hit) - 1);
            }
            if (cra == crb) continue;                      // became connected within batch
            // node values: latest log entry that merged INTO this root, else batch-start value
            unsigned ce = (unsigned)__shfl(e, j);
            unsigned long long cna, cnb;
            {
                unsigned long long hb = __ballot(logRb == cra);
                cna = hb ? __shfl(logNode, 63 - __clzll((long long)hb)) : __shfl(na, j);
                unsigned long long hb2 = __ballot(logRb == crb);
                cnb = hb2 ? __shfl(logNode, 63 - __clzll((long long)hb2)) : __shfl(nb, j);
            }
            unsigned headA = (unsigned)(cna >> 48);
            unsigned tailA = (unsigned)(cna >> 32) & 0xFFFFu;
            unsigned szA   = (unsigned)(cna >> 16) & 0xFFFFu;
            unsigned slA   = (unsigned)cna & 0xFFFFu;
            unsigned headB = (unsigned)(cnb >> 48);
            unsigned tailB = (unsigned)(cnb >> 32) & 0xFFFFu;
            unsigned szB   = (unsigned)(cnb >> 16) & 0xFFFFu;
            unsigned slB   = (unsigned)cnb & 0xFFFFu;
            unsigned long long merged =
                  ((unsigned long long)headA << 48)
                | ((unsigned long long)tailB << 32)
                | ((unsigned long long)(szA + szB) << 16)
                | (unsigned long long)(slA + slB);
            if (lane == logCount) {
                logRa = cra; logRb = crb; logNode = merged;   // register log append
                parentS[cra] = (unsigned short)crb;           // fire-and-forget commits:
                nodeS[crb]   = merged;                        //  nothing in this batch reads them
                nextS[tailA] = (unsigned short)headB;         //  (log registers serve all queries)
                mrA[m] = (headA << 16) | headB;
                mrB[m] = (szA << 16) | szB;
                mSS[m] = slA * slB;
                mED[m] = (unsigned short)ce;
            }
            logCount++;
            m++;
        }
    }
    if (lane == 0) *(int*)(mg + MRG_M) = m;
    for (int i = lane; i < NPIX; i += 64) mNX[i] = nextS[i];
}

// ============================ K4: list-rank + chunked prefix dots + loss ============================
__global__ __launch_bounds__(256, 2)
void k4_weights(const float* __restrict__ t_glob,
                const float* __restrict__ p_glob,
                const unsigned short* __restrict__ pixLab_g,
                const int* __restrict__ Kg,
                const char* __restrict__ mrg_base,
                float* __restrict__ out) {
    const int tid = threadIdx.x;
    const int wg  = blockIdx.x;
    const int sgn = wg & 1;
    const int tileId = wg >> 1;
    const int bat = tileId >> 6;
    const int tile = tileId & 63;
    const int tr = tile >> 3, tc = tile & 7;

    __shared__ float          pT[NPIX];
    __shared__ unsigned char  bgS[NPIX];
    __shared__ unsigned short pixLab[NPIX];
    __shared__ unsigned short posS[NPIX];
    __shared__ unsigned int   mRecA[NMERGE];
    __shared__ unsigned int   mRecB[NMERGE];
    __shared__ unsigned int   mSaSb[NMERGE];
    __shared__ unsigned int   commonW[NMERGE];
    __shared__ unsigned short mEd[NMERGE];
    __shared__ __align__(16) unsigned long long big[2564];
    __shared__ unsigned wsumSh;
    __shared__ float lossSh;

    const char* mg = mrg_base + (size_t)wg * MRG_STRIDE;
    const int M = *(const int*)(mg + MRG_M);
    const int K = Kg[tileId];
    const unsigned int*   mrA = (const unsigned int*)(mg + MRG_RA);
    const unsigned int*   mrB = (const unsigned int*)(mg + MRG_RB);
    const unsigned int*   mSS = (const unsigned int*)(mg + MRG_SS);
    const unsigned short* mED = (const unsigned short*)(mg + MRG_ED);
    const unsigned short* mNX = (const unsigned short*)(mg + MRG_NXT);

    for (int i = tid; i < NPIX; i += 256) {
        int y = i >> 5, x = i & 31;
        int gidx = bat * 65536 + (tr * 32 + y) * 256 + (tc * 32 + x);
        pT[i] = p_glob[gidx];
        bgS[i] = (t_glob[gidx] == 0.0f) ? 1 : 0;
        pixLab[i] = pixLab_g[tileId * NPIX + i];
    }
    for (int j = tid; j < M; j += 256) {
        mRecA[j] = mrA[j];
        mRecB[j] = mrB[j];
        mSaSb[j] = mSS[j];
        mEd[j]   = mED[j];
        commonW[j] = 0;
    }

    // ---- Wyllie list ranking -> posS ----
    unsigned short* n0 = (unsigned short*)big;
    unsigned short* n1 = n0 + 1024;
    unsigned short* d0 = n0 + 2048;
    unsigned short* d1 = n0 + 3072;
    for (int i = tid; i < NPIX; i += 256) { n0[i] = mNX[i]; d0[i] = 1; }
    __syncthreads();
    for (int s = 0; s < 10; s++) {
        unsigned short* sn = (s & 1) ? n1 : n0;
        unsigned short* sd = (s & 1) ? d1 : d0;
        unsigned short* dn = (s & 1) ? n0 : n1;
        unsigned short* dd = (s & 1) ? d0 : d1;
        for (int i = tid; i < NPIX; i += 256) {
            unsigned nx = sn[i];
            unsigned dv = sd[i];
            if (nx != NIL) { dv += sd[nx]; nx = sn[nx]; }
            dn[i] = (unsigned short)nx;
            dd[i] = (unsigned short)dv;
        }
        __syncthreads();
    }
    for (int i = tid; i < NPIX; i += 256)
        posS[i] = (unsigned short)(NPIX - (int)d0[i]);
    __syncthreads();

    // ---- chunked label prefix sums + per-merge dots ----
    unsigned*       P32 = (unsigned*)big;
    uint4*          P4  = (uint4*)big;
    unsigned*       scr = P32 + 4100;
    uint4*          S4  = (uint4*)scr;
    unsigned short* P16 = (unsigned short*)big;
    for (int base = 0; base < K; base += CHUNK) {
        for (int idx = tid; idx < 4100; idx += 256) P32[idx] = 0;
        __syncthreads();
        for (int i = tid; i < NPIX; i += 256) {
            unsigned l = pixLab[i];
            if (l != NIL && l >= (unsigned)base && l < (unsigned)(base + CHUNK))
                P16[(posS[i] + 1) * 8 + (l - base)] = 1;
        }
        __syncthreads();
        {
            int r0 = tid * 4 + 1;
            uint4 acc = P4[r0];
            for (int rr = r0 + 1; rr <= r0 + 3; rr++) { acc = add4(acc, P4[rr]); P4[rr] = acc; }
            S4[tid] = acc;
            __syncthreads();
            if (tid < 64) {
                uint4 s0 = S4[tid * 4], s1 = S4[tid * 4 + 1], s2 = S4[tid * 4 + 2], s3 = S4[tid * 4 + 3];
                uint4 t1 = add4(s0, s1), t2 = add4(t1, s2), t3 = add4(t2, s3);
                uint4 run = t3;
                #pragma unroll
                for (int d = 1; d < 64; d <<= 1) {
                    uint4 o;
                    o.x = __shfl_up(run.x, d, 64);
                    o.y = __shfl_up(run.y, d, 64);
                    o.z = __shfl_up(run.z, d, 64);
                    o.w = __shfl_up(run.w, d, 64);
                    if (tid >= d) run = add4(run, o);
                }
                uint4 off = sub4(run, t3);
                S4[tid * 4]     = add4(s0, off);
                S4[tid * 4 + 1] = add4(t1, off);
                S4[tid * 4 + 2] = add4(t2, off);
                S4[tid * 4 + 3] = add4(t3, off);
            }
            __syncthreads();
            if (tid > 0) {
                uint4 off = S4[tid - 1];
                for (int rr = r0; rr <= r0 + 3; rr++) P4[rr] = add4(P4[rr], off);
            }
        }
        __syncthreads();
        for (int j = tid; j < M; j += 256) {
            unsigned recA = mRecA[j], recB = mRecB[j];
            unsigned aS = posS[recA >> 16];
            unsigned bS = posS[recA & 0xFFFFu];
            uint4 da = sub4(P4[aS + (recB >> 16)], P4[aS]);
            uint4 db = sub4(P4[bS + (recB & 0xFFFFu)], P4[bS]);
            unsigned acc;
            acc  = (da.x & 0xFFFFu) * (db.x & 0xFFFFu) + (da.x >> 16) * (db.x >> 16);
            acc += (da.y & 0xFFFFu) * (db.y & 0xFFFFu) + (da.y >> 16) * (db.y >> 16);
            acc += (da.z & 0xFFFFu) * (db.z & 0xFFFFu) + (da.z >> 16) * (db.z >> 16);
            acc += (da.w & 0xFFFFu) * (db.w & 0xFFFFu) + (da.w >> 16) * (db.w >> 16);
            commonW[j] += acc;
        }
        __syncthreads();
    }

    // ---- normalize + mask + loss ----
    if (tid == 0) { wsumSh = 0; lossSh = 0.0f; }
    __syncthreads();
    unsigned wloc = 0;
    for (int j = tid; j < M; j += 256)
        wloc += (sgn == 0) ? (mSaSb[j] - commonW[j]) : commonW[j];
    if (wloc) atomicAdd(&wsumSh, wloc);
    __syncthreads();
    const unsigned wsum = wsumSh;
    if (wsum > 0) {
        const double inv = 1.0 / (double)wsum;
        float lloc = 0.0f;
        for (int j = tid; j < M; j += 256) {
            unsigned w = (sgn == 0) ? (mSaSb[j] - commonW[j]) : commonW[j];
            if (!w) continue;
            int e = mEd[j];
            int a, b; edge_ab(e, a, b);
            int nfg = (int)(!bgS[a]) + (int)(!bgS[b]);
            bool keep = (sgn == 0) ? (nfg == 0) : (nfg >= 1);
            if (!keep) continue;
            float wn = (float)((double)w * inv);
            float fa, fb;
            if (sgn == 0) { fa = pT[a] * pT[a];            fb = pT[b] * pT[b]; }
            else { float da = 20.0f - pT[a], db = 20.0f - pT[b]; fa = da * da; fb = db * db; }
            lloc += wn * (fa + fb);
        }
        if (lloc != 0.0f) atomicAdd(&lossSh, lloc);
        __syncthreads();
        if (tid == 0 && lossSh != 0.0f) atomicAdd(out, lossSh);
    }
}

// ============================ fallback: monolith (used if ws too small) ============================
__global__ __launch_bounds__(256, 2)
void malis_mono(const float* __restrict__ t_glob,
                const float* __restrict__ p_glob,
                float* __restrict__ out) {
    const int tid  = threadIdx.x;
    const int wg   = blockIdx.x;
    const int sgn  = wg & 1;
    const int tileId = wg >> 1;
    const int bat  = tileId >> 6;
    const int tile = tileId & 63;
    const int tr = tile >> 3, tc = tile & 7;

    __shared__ float          pT[NPIX];
    __shared__ unsigned char  bgS[NPIX];
    __shared__ unsigned short pixLab[NPIX];
    __shared__ unsigned short parentS[NPIX];
    __shared__ unsigned short nextS[NPIX];
    __shared__ unsigned long long nodeS[NPIX];
    __shared__ unsigned short posS[NPIX];
    __shared__ unsigned short orderS[NEDGE];
    __shared__ unsigned int   mRecA[NMERGE];
    __shared__ unsigned int   mRecB[NMERGE];
    __shared__ unsigned short mEd[NMERGE];
    __shared__ unsigned int   mSaSb[NMERGE];
    __shared__ unsigned int   commonW[NMERGE];
    __shared__ __align__(16) unsigned long long big[2564];
    __shared__ int   kprimeSh, mCountSh;
    __shared__ unsigned wsumSh;
    __shared__ float lossSh;

    for (int i = tid; i < NPIX; i += 256) {
        int y = i >> 5, x = i & 31;
        int gidx = bat * 65536 + (tr * 32 + y) * 256 + (tc * 32 + x);
        pT[i] = p_glob[gidx];
        bgS[i] = (t_glob[gidx] == 0.0f) ? 1 : 0;
    }
    __syncthreads();

    unsigned short* labS = (unsigned short*)big;
    unsigned int*   cntS = (unsigned int*)(((char*)big) + 2048);
    if (tid < 64) {
        const int lane = tid;
        if (lane < 32) {
            #pragma unroll
            for (int x = 0; x < 32; x++) {
                int i = lane * 32 + x;
                labS[i] = bgS[i] ? (unsigned short)i : (unsigned short)NIL;
            }
        }
        while (true) {
            bool changed = false;
            if (lane < 32) {
                const int base = lane * 32;
                unsigned short v[32];
                #pragma unroll
                for (int x = 0; x < 32; x++) v[x] = labS[base + x];
                unsigned run = NIL;
                #pragma unroll
                for (int x = 0; x < 32; x++) {
                    unsigned val = v[x];
                    if (val == NIL) { run = NIL; }
                    else { unsigned nv = min(run, val); changed |= (nv != val); v[x] = (unsigned short)nv; run = nv; }
                }
                run = NIL;
                #pragma unroll
                for (int x = 31; x >= 0; x--) {
                    unsigned val = v[x];
                    if (val == NIL) { run = NIL; }
                    else { unsigned nv = min(run, val); changed |= (nv != val); v[x] = (unsigned short)nv; run = nv; }
                }
                #pragma unroll
                for (int x = 0; x < 32; x++) labS[base + x] = v[x];
            }
            if (lane < 32) {
                unsigned short c[32];
                #pragma unroll
                for (int k = 0; k < 32; k++) c[k] = labS[k * 32 + lane];
                unsigned run = NIL;
                #pragma unroll
                for (int k = 0; k < 32; k++) {
                    unsigned val = c[k];
                    if (val == NIL) { run = NIL; }
                    else { unsigned nv = min(run, val); changed |= (nv != val); c[k] = (unsigned short)nv; run = nv; }
                }
                run = NIL;
                #pragma unroll
                for (int k = 31; k >= 0; k--) {
                    unsigned val = c[k];
                    if (val == NIL) { run = NIL; }
                    else { unsigned nv = min(run, val); changed |= (nv != val); c[k] = (unsigned short)nv; run = nv; }
                }
                #pragma unroll
                for (int k = 0; k < 32; k++) labS[k * 32 + lane] = c[k];
            }
            if (!__any(changed)) break;
        }
    }
    __syncthreads();

    for (int i = tid; i < NPIX; i += 256) cntS[i] = 0;
    if (tid == 0) kprimeSh = 0;
    __syncthreads();
    for (int i = tid; i < NPIX; i += 256)
        if (bgS[i]) atomicAdd(&cntS[labS[i]], 1u);
    __syncthreads();
    for (int i = tid; i < NPIX; i += 256) {
        if (bgS[i] && (int)labS[i] == i) {
            unsigned id = (cntS[i] >= 2) ? (unsigned)atomicAdd(&kprimeSh, 1) : NIL;
            cntS[i] = id;
        }
    }
    __syncthreads();
    for (int i = tid; i < NPIX; i += 256)
        pixLab[i] = bgS[i] ? (unsigned short)cntS[labS[i]] : (unsigned short)NIL;
    __syncthreads();
    const int K = kprimeSh;

    unsigned long long* keys = big;
    for (int k = tid; k < SORTN; k += 256) {
        unsigned long long key = 0ULL;
        if (k < NEDGE) {
            int a, b; edge_ab(k, a, b);
            float cost = pT[a] + pT[b];
            int nfg = (int)(!bgS[a]) + (int)(!bgS[b]);
            if (sgn == 0) { if (nfg == 2) cost = 20.0f; }
            else          { if (nfg == 0) cost = 0.0f;  }
            key = ((unsigned long long)__float_as_uint(cost) << 16)
                | (unsigned long long)(0xFFFFu - (unsigned)k);
        }
        keys[k] = key;
    }
    __syncthreads();
    for (int kk = 2; kk <= SORTN; kk <<= 1) {
        for (int jj = kk >> 1; jj > 0; jj >>= 1) {
            for (int i = tid; i < SORTN; i += 256) {
                int ixj = i ^ jj;
                if (ixj > i) {
                    unsigned long long A = keys[i], Bv = keys[ixj];
                    bool descBlk = ((i & kk) == 0);
                    if ((A < Bv) == descBlk) { keys[i] = Bv; keys[ixj] = A; }
                }
            }
            __syncthreads();
        }
    }
    for (int k = tid; k < NEDGE; k += 256)
        orderS[k] = (unsigned short)(0xFFFFu - (unsigned)(keys[k] & 0xFFFFULL));
    for (int i = tid; i < NPIX; i += 256) {
        parentS[i] = (unsigned short)i;
        nodeS[i] = ((unsigned long long)i << 48) | ((unsigned long long)i << 32)
                 | (1ULL << 16) | (unsigned long long)bgS[i];
        nextS[i] = (unsigned short)NIL;
    }
    __syncthreads();

    if (tid < 64) {
        const int lane = tid;
        int m = 0;
        for (int kb = 0; kb < NEDGE; kb += 64) {
            int e = orderS[kb + lane];
            int a, b; edge_ab(e, a, b);
            unsigned ra = (unsigned)a, rb = (unsigned)b;
            while (true) {
                unsigned pa = parentS[ra];
                unsigned pb = parentS[rb];
                if (pa == ra && pb == rb) break;
                if (pa != ra) { unsigned ga = parentS[pa]; parentS[ra] = (unsigned short)ga; ra = ga; }
                if (pb != rb) { unsigned gb = parentS[pb]; parentS[rb] = (unsigned short)gb; rb = gb; }
            }
            unsigned specAB = (ra << 16) | rb;
            unsigned long long na = nodeS[ra];
            unsigned long long nb = nodeS[rb];
            unsigned long long candm = __ballot(ra != rb);

            unsigned logRa = 0xFFFFFFFFu, logRb = 0xFFFFFFFFu;
            unsigned long long logNode = 0;
            int logCount = 0;
            while (candm != 0ULL) {
                int j = __ffsll((long long)candm) - 1;
                candm &= candm - 1ULL;
                unsigned sAB = __shfl(specAB, j);
                unsigned cra = sAB >> 16;
                unsigned crb = sAB & 0xFFFFu;
                while (true) {
                    unsigned long long hit = __ballot(logRa == cra);
                    if (hit == 0ULL) break;
                    cra = __shfl(logRb, __ffsll((long long)hit) - 1);
                }
                while (true) {
                    unsigned long long hit = __ballot(logRa == crb);
                    if (hit == 0ULL) break;
                    crb = __shfl(logRb, __ffsll((long long)hit) - 1);
                }
                if (cra == crb) continue;
                unsigned ce = (unsigned)__shfl(e, j);
                unsigned long long cna, cnb;
                {
                    unsigned long long hb = __ballot(logRb == cra);
                    cna = hb ? __shfl(logNode, 63 - __clzll((long long)hb)) : __shfl(na, j);
                    unsigned long long hb2 = __ballot(logRb == crb);
                    cnb = hb2 ? __shfl(logNode, 63 - __clzll((long long)hb2)) : __shfl(nb, j);
                }
                unsigned headA = (unsigned)(cna >> 48);
                unsigned tailA = (unsigned)(cna >> 32) & 0xFFFFu;
                unsigned szA   = (unsigned)(cna >> 16) & 0xFFFFu;
                unsigned slA   = (unsigned)cna & 0xFFFFu;
                unsigned headB = (unsigned)(cnb >> 48);
                unsigned tailB = (unsigned)(cnb >> 32) & 0xFFFFu;
                unsigned szB   = (unsigned)(cnb >> 16) & 0xFFFFu;
                unsigned slB   = (unsigned)cnb & 0xFFFFu;
                unsigned long long merged =
                      ((unsigned long long)headA << 48)
                    | ((unsigned long long)tailB << 32)
                    | ((unsigned long long)(szA + szB) << 16)
                    | (unsigned long long)(slA + slB);
                if (lane == logCount) {
                    logRa = cra; logRb = crb; logNode = merged;
                    parentS[cra] = (unsigned short)crb;
                    nodeS[crb]   = merged;
                    nextS[tailA] = (unsigned short)headB;
                    mRecA[m] = (headA << 16) | headB;
                    mRecB[m] = (szA << 16) | szB;
                    mSaSb[m] = slA * slB;
                    mEd[m]   = (unsigned short)ce;
                }
                logCount++;
                m++;
            }
        }
        if (lane == 0) mCountSh = m;
    }
    __syncthreads();
    const int M = mCountSh;
    for (int j = tid; j < M; j += 256) commonW[j] = 0;

    unsigned short* n0 = (unsigned short*)big;
    unsigned short* n1 = n0 + 1024;
    unsigned short* d0 = n0 + 2048;
    unsigned short* d1 = n0 + 3072;
    for (int i = tid; i < NPIX; i += 256) { n0[i] = nextS[i]; d0[i] = 1; }
    __syncthreads();
    for (int s = 0; s < 10; s++) {
        unsigned short* sn = (s & 1) ? n1 : n0;
        unsigned short* sd = (s & 1) ? d1 : d0;
        unsigned short* dn = (s & 1) ? n0 : n1;
        unsigned short* dd = (s & 1) ? d0 : d1;
        for (int i = tid; i < NPIX; i += 256) {
            unsigned nx = sn[i];
            unsigned dv = sd[i];
            if (nx != NIL) { dv += sd[nx]; nx = sn[nx]; }
            dn[i] = (unsigned short)nx;
            dd[i] = (unsigned short)dv;
        }
        __syncthreads();
    }
    for (int i = tid; i < NPIX; i += 256)
        posS[i] = (unsigned short)(NPIX - (int)d0[i]);
    __syncthreads();

    unsigned*       P32 = (unsigned*)big;
    uint4*          P4  = (uint4*)big;
    unsigned*       scr = P32 + 4100;
    uint4*          S4  = (uint4*)scr;
    unsigned short* P16 = (unsigned short*)big;
    for (int base = 0; base < K; base += CHUNK) {
        for (int idx = tid; idx < 4100; idx += 256) P32[idx] = 0;
        __syncthreads();
        for (int i = tid; i < NPIX; i += 256) {
            unsigned l = pixLab[i];
            if (l != NIL && l >= (unsigned)base && l < (unsigned)(base + CHUNK))
                P16[(posS[i] + 1) * 8 + (l - base)] = 1;
        }
        __syncthreads();
        {
            int r0 = tid * 4 + 1;
            uint4 acc = P4[r0];
            for (int rr = r0 + 1; rr <= r0 + 3; rr++) { acc = add4(acc, P4[rr]); P4[rr] = acc; }
            S4[tid] = acc;
            __syncthreads();
            if (tid < 64) {
                uint4 s0 = S4[tid * 4], s1 = S4[tid * 4 + 1], s2 = S4[tid * 4 + 2], s3 = S4[tid * 4 + 3];
                uint4 t1 = add4(s0, s1), t2 = add4(t1, s2), t3 = add4(t2, s3);
                uint4 run = t3;
                #pragma unroll
                for (int d = 1; d < 64; d <<= 1) {
                    uint4 o;
                    o.x = __shfl_up(run.x, d, 64);
                    o.y = __shfl_up(run.y, d, 64);
                    o.z = __shfl_up(run.z, d, 64);
                    o.w = __shfl_up(run.w, d, 64);
                    if (tid >= d) run = add4(run, o);
                }
                uint4 off = sub4(run, t3);
                S4[tid * 4]     = add4(s0, off);
                S4[tid * 4 + 1] = add4(t1, off);
                S4[tid * 4 + 2] = add4(t2, off);
                S4[tid * 4 + 3] = add4(t3, off);
            }
            __syncthreads();
            if (tid > 0) {
                uint4 off = S4[tid - 1];
                for (int rr = r0; rr <= r0 + 3; rr++) P4[rr] = add4(P4[rr], off);
            }
        }
        __syncthreads();
        for (int j = tid; j < M; j += 256) {
            unsigned recA = mRecA[j], recB = mRecB[j];
            unsigned aS = posS[recA >> 16];
            unsigned bS = posS[recA & 0xFFFFu];
            uint4 da = sub4(P4[aS + (recB >> 16)], P4[aS]);
            uint4 db = sub4(P4[bS + (recB & 0xFFFFu)], P4[bS]);
            unsigned acc;
            acc  = (da.x & 0xFFFFu) * (db.x & 0xFFFFu) + (da.x >> 16) * (db.x >> 16);
            acc += (da.y & 0xFFFFu) * (db.y & 0xFFFFu) + (da.y >> 16) * (db.y >> 16);
            acc += (da.z & 0xFFFFu) * (db.z & 0xFFFFu) + (da.z >> 16) * (db.z >> 16);
            acc += (da.w & 0xFFFFu) * (db.w & 0xFFFFu) + (da.w >> 16) * (db.w >> 16);
            commonW[j] += acc;
        }
        __syncthreads();
    }

    if (tid == 0) { wsumSh = 0; lossSh = 0.0f; }
    __syncthreads();
    unsigned wloc = 0;
    for (int j = tid; j < M; j += 256)
        wloc += (sgn == 0) ? (mSaSb[j] - commonW[j]) : commonW[j];
    if (wloc) atomicAdd(&wsumSh, wloc);
    __syncthreads();
    const unsigned wsum = wsumSh;
    if (wsum > 0) {
        const double inv = 1.0 / (double)wsum;
        float lloc = 0.0f;
        for (int j = tid; j < M; j += 256) {
            unsigned w = (sgn == 0) ? (mSaSb[j] - commonW[j]) : commonW[j];
            if (!w) continue;
            int e = mEd[j];
            int a, b; edge_ab(e, a, b);
            int nfg = (int)(!bgS[a]) + (int)(!bgS[b]);
            bool keep = (sgn == 0) ? (nfg == 0) : (nfg >= 1);
            if (!keep) continue;
            float wn = (float)((double)w * inv);
            float fa, fb;
            if (sgn == 0) { fa = pT[a] * pT[a];            fb = pT[b] * pT[b]; }
            else { float da = 20.0f - pT[a], db = 20.0f - pT[b]; fa = da * da; fb = db * db; }
            lloc += wn * (fa + fb);
        }
        if (lloc != 0.0f) atomicAdd(&lossSh, lloc);
        __syncthreads();
        if (tid == 0 && lossSh != 0.0f) atomicAdd(out, lossSh);
    }
}

extern "C" void kernel_launch(void* const* d_in, const int* in_sizes, int n_in,
                              void* d_out, int out_size, void* d_ws, size_t ws_size,
                              hipStream_t stream) {
    const float* y_true = (const float*)d_in[0];
    const float* y_pred = (const float*)d_in[1];
    float* out = (float*)d_out;
    const int B  = in_sizes[0] / (256 * 256);
    const int nT = B * 64;
    const int nW = nT * 2;

    const size_t offK   = (size_t)nT * 2048;
    const size_t offOrd = offK + (((size_t)nT * 4 + 255) & ~(size_t)255);
    const size_t offMrg = offOrd + (size_t)nW * 4096;
    const size_t need   = offMrg + (size_t)nW * MRG_STRIDE;

    hipMemsetAsync(d_out, 0, (size_t)out_size * sizeof(float), stream);

    if (ws_size >= need) {
        char* ws = (char*)d_ws;
        unsigned short* pixLab_g = (unsigned short*)ws;
        int*            Kg       = (int*)(ws + offK);
        unsigned short* ord_g    = (unsigned short*)(ws + offOrd);
        char*           mrg      = ws + offMrg;
        hipLaunchKernelGGL(k1_ccl,     dim3(nT), dim3(256), 0, stream, y_true, pixLab_g, Kg);
        hipLaunchKernelGGL(k2_sort,    dim3(nW), dim3(256), 0, stream, y_true, y_pred, ord_g);
        hipLaunchKernelGGL(k3_kruskal, dim3(nW), dim3(64),  0, stream, y_true, ord_g, mrg);
        hipLaunchKernelGGL(k4_weights, dim3(nW), dim3(256), 0, stream, y_true, y_pred,
                           pixLab_g, Kg, mrg, out);
    } else {
        hipLaunchKernelGGL(malis_mono, dim3(nW), dim3(256), 0, stream, y_true, y_pred, out);
    }
}

// Round 7
// 495.793 us; speedup vs baseline: 1.4411x; 1.4143x over previous
//
#include <hip/hip_runtime.h>

#define NPIX   1024   // 32*32
#define NEH    992    // horizontal edges 32*31
#define NEDGE  1984   // + vertical 31*32
#define SORTN  2048
#define CHUNK  8      // labels per phase-2 pass
#define NMERGE 1023
#define NIL    0xFFFFu

// per-(tile,sgn) merge-record block in ws (20480 B stride)
#define MRG_STRIDE 20480
#define MRG_M      0
#define MRG_RA     256
#define MRG_RB     4608
#define MRG_SS     8960
#define MRG_ED     13312
#define MRG_NXT    15616

__device__ __forceinline__ void edge_ab(int e, int& a, int& b) {
    if (e < NEH) { int y = e / 31; int x = e - y * 31; a = y * 32 + x; b = a + 1; }
    else         { int ev = e - NEH; a = ev; b = ev + 32; }
}

__device__ __forceinline__ uint4 add4(uint4 x, uint4 y) {
    return make_uint4(x.x + y.x, x.y + y.y, x.z + y.z, x.w + y.w);
}
__device__ __forceinline__ uint4 sub4(uint4 x, uint4 y) {
    return make_uint4(x.x - y.x, x.y - y.y, x.z - y.z, x.w - y.w);
}

// ============================ fused K1/K2 bodies ============================
__device__ void ccl_body(char* smem, int* kprimeSh,
                         const float* __restrict__ t_glob,
                         unsigned short* __restrict__ pixLab_g,
                         int* __restrict__ Kg, int tileId) {
    const int tid = threadIdx.x;
    const int bat = tileId >> 6;
    const int tile = tileId & 63;
    const int tr = tile >> 3, tc = tile & 7;

    unsigned short* labS = (unsigned short*)smem;                 // [0,2048)
    unsigned int*   cntS = (unsigned int*)(smem + 2048);          // [2048,6144)
    unsigned char*  bgS  = (unsigned char*)(smem + 20480);        // [20480,21504)

    for (int i = tid; i < NPIX; i += 256) {
        int y = i >> 5, x = i & 31;
        int gidx = bat * 65536 + (tr * 32 + y) * 256 + (tc * 32 + x);
        bgS[i] = (t_glob[gidx] == 0.0f) ? 1 : 0;
    }
    __syncthreads();

    if (tid < 64) {
        const int lane = tid;
        if (lane < 32) {
            #pragma unroll
            for (int x = 0; x < 32; x++) {
                int i = lane * 32 + x;
                labS[i] = bgS[i] ? (unsigned short)i : (unsigned short)NIL;
            }
        }
        while (true) {
            bool changed = false;
            if (lane < 32) {
                const int base = lane * 32;
                unsigned short v[32];
                #pragma unroll
                for (int x = 0; x < 32; x++) v[x] = labS[base + x];
                unsigned run = NIL;
                #pragma unroll
                for (int x = 0; x < 32; x++) {
                    unsigned val = v[x];
                    if (val == NIL) { run = NIL; }
                    else { unsigned nv = min(run, val); changed |= (nv != val); v[x] = (unsigned short)nv; run = nv; }
                }
                run = NIL;
                #pragma unroll
                for (int x = 31; x >= 0; x--) {
                    unsigned val = v[x];
                    if (val == NIL) { run = NIL; }
                    else { unsigned nv = min(run, val); changed |= (nv != val); v[x] = (unsigned short)nv; run = nv; }
                }
                #pragma unroll
                for (int x = 0; x < 32; x++) labS[base + x] = v[x];
            }
            if (lane < 32) {
                unsigned short c[32];
                #pragma unroll
                for (int k = 0; k < 32; k++) c[k] = labS[k * 32 + lane];
                unsigned run = NIL;
                #pragma unroll
                for (int k = 0; k < 32; k++) {
                    unsigned val = c[k];
                    if (val == NIL) { run = NIL; }
                    else { unsigned nv = min(run, val); changed |= (nv != val); c[k] = (unsigned short)nv; run = nv; }
                }
                run = NIL;
                #pragma unroll
                for (int k = 31; k >= 0; k--) {
                    unsigned val = c[k];
                    if (val == NIL) { run = NIL; }
                    else { unsigned nv = min(run, val); changed |= (nv != val); c[k] = (unsigned short)nv; run = nv; }
                }
                #pragma unroll
                for (int k = 0; k < 32; k++) labS[k * 32 + lane] = c[k];
            }
            if (!__any(changed)) break;
        }
    }
    __syncthreads();

    for (int i = tid; i < NPIX; i += 256) cntS[i] = 0;
    if (tid == 0) *kprimeSh = 0;
    __syncthreads();
    for (int i = tid; i < NPIX; i += 256)
        if (bgS[i]) atomicAdd(&cntS[labS[i]], 1u);
    __syncthreads();
    for (int i = tid; i < NPIX; i += 256) {
        if (bgS[i] && (int)labS[i] == i) {
            unsigned id = (cntS[i] >= 2) ? (unsigned)atomicAdd(kprimeSh, 1) : NIL;
            cntS[i] = id;
        }
    }
    __syncthreads();
    for (int i = tid; i < NPIX; i += 256)
        pixLab_g[tileId * NPIX + i] = bgS[i] ? (unsigned short)cntS[labS[i]] : (unsigned short)NIL;
    if (tid == 0) Kg[tileId] = *kprimeSh;
}

__device__ void sort_body(char* smem,
                          const float* __restrict__ t_glob,
                          const float* __restrict__ p_glob,
                          unsigned short* __restrict__ ord_g, int wg) {
    const int tid = threadIdx.x;
    const int sgn = wg & 1;
    const int tileId = wg >> 1;
    const int bat = tileId >> 6;
    const int tile = tileId & 63;
    const int tr = tile >> 3, tc = tile & 7;

    float*              pT   = (float*)smem;                      // [0,4096)
    unsigned long long* keys = (unsigned long long*)(smem + 4096);// [4096,20480)
    unsigned char*      bgS  = (unsigned char*)(smem + 20480);    // [20480,21504)

    for (int i = tid; i < NPIX; i += 256) {
        int y = i >> 5, x = i & 31;
        int gidx = bat * 65536 + (tr * 32 + y) * 256 + (tc * 32 + x);
        pT[i] = p_glob[gidx];
        bgS[i] = (t_glob[gidx] == 0.0f) ? 1 : 0;
    }
    __syncthreads();

    for (int k = tid; k < SORTN; k += 256) {
        unsigned long long key = 0ULL;
        if (k < NEDGE) {
            int a, b; edge_ab(k, a, b);
            float cost = pT[a] + pT[b];
            int nfg = (int)(!bgS[a]) + (int)(!bgS[b]);
            if (sgn == 0) { if (nfg == 2) cost = 20.0f; }
            else          { if (nfg == 0) cost = 0.0f;  }
            key = ((unsigned long long)__float_as_uint(cost) << 16)
                | (unsigned long long)(0xFFFFu - (unsigned)k);
        }
        keys[k] = key;
    }
    __syncthreads();
    for (int kk = 2; kk <= SORTN; kk <<= 1) {
        for (int jj = kk >> 1; jj > 0; jj >>= 1) {
            for (int i = tid; i < SORTN; i += 256) {
                int ixj = i ^ jj;
                if (ixj > i) {
                    unsigned long long A = keys[i], Bv = keys[ixj];
                    bool descBlk = ((i & kk) == 0);
                    if ((A < Bv) == descBlk) { keys[i] = Bv; keys[ixj] = A; }
                }
            }
            __syncthreads();
        }
    }
    for (int k = tid; k < NEDGE; k += 256)
        ord_g[(size_t)wg * SORTN + k] = (unsigned short)(0xFFFFu - (unsigned)(keys[k] & 0xFFFFULL));
}

__global__ __launch_bounds__(256, 2)
void k12_ccl_sort(const float* __restrict__ t_glob,
                  const float* __restrict__ p_glob,
                  unsigned short* __restrict__ pixLab_g,
                  int* __restrict__ Kg,
                  unsigned short* __restrict__ ord_g,
                  int nT) {
    __shared__ __align__(16) char smem[21504];
    __shared__ int kprimeSh;
    if ((int)blockIdx.x < nT)
        ccl_body(smem, &kprimeSh, t_glob, pixLab_g, Kg, blockIdx.x);
    else
        sort_body(smem, t_glob, p_glob, ord_g, blockIdx.x - nT);
}

// ============================ K3: Kruskal, O(1) register-log resolution ============================
__global__ __launch_bounds__(64)
void k3_kruskal(const float* __restrict__ t_glob,
                const unsigned short* __restrict__ ord_g,
                char* __restrict__ mrg_base) {
    const int lane = threadIdx.x;
    const int wg  = blockIdx.x;
    const int tileId = wg >> 1;
    const int bat = tileId >> 6;
    const int tile = tileId & 63;
    const int tr = tile >> 3, tc = tile & 7;

    __shared__ unsigned short parentS[NPIX];
    __shared__ unsigned long long nodeS[NPIX];
    __shared__ unsigned short nextS[NPIX];

    char* mg = mrg_base + (size_t)wg * MRG_STRIDE;
    unsigned int*   mrA = (unsigned int*)(mg + MRG_RA);
    unsigned int*   mrB = (unsigned int*)(mg + MRG_RB);
    unsigned int*   mSS = (unsigned int*)(mg + MRG_SS);
    unsigned short* mED = (unsigned short*)(mg + MRG_ED);
    unsigned short* mNX = (unsigned short*)(mg + MRG_NXT);
    const unsigned short* ord = ord_g + (size_t)wg * SORTN;

    for (int i = lane; i < NPIX; i += 64) {
        int y = i >> 5, x = i & 31;
        int gidx = bat * 65536 + (tr * 32 + y) * 256 + (tc * 32 + x);
        unsigned bg = (t_glob[gidx] == 0.0f) ? 1u : 0u;
        parentS[i] = (unsigned short)i;
        nodeS[i] = ((unsigned long long)i << 48) | ((unsigned long long)i << 32)
                 | (1ULL << 16) | (unsigned long long)bg;
        nextS[i] = (unsigned short)NIL;
    }
    __syncthreads();

    int m = 0;
    for (int kb = 0; kb < NEDGE; kb += 64) {      // 31 exact batches
        // ---- spec phase: all 64 lanes find roots (concurrent path-halving) ----
        int e = ord[kb + lane];
        int a, b; edge_ab(e, a, b);
        unsigned ra = (unsigned)a, rb = (unsigned)b;
        while (true) {
            unsigned pa = parentS[ra];
            unsigned pb = parentS[rb];
            if (pa == ra && pb == rb) break;
            if (pa != ra) { unsigned ga = parentS[pa]; parentS[ra] = (unsigned short)ga; ra = ga; }
            if (pb != rb) { unsigned gb = parentS[pb]; parentS[rb] = (unsigned short)gb; rb = gb; }
        }
        unsigned specAB = (ra << 16) | rb;                 // roots as of batch start
        unsigned long long na = nodeS[ra];                 // node values as of batch start
        unsigned long long nb = nodeS[rb];
        unsigned long long candm = __ballot(ra != rb);     // spec-equal => definitely connected

        // ---- serial log phase (wave-uniform). Per-lane registers hold the log.
        //   logRa   : root consumed by this lane's entry (distinct across entries)
        //   logRbO  : surviving root AT MERGE TIME (for node-value queries)
        //   curRoot : CURRENT root of this entry's component (path-compressed
        //             every merge by one uniform VALU op -> O(1) resolution)
        unsigned logRa  = 0xFFFFFFFFu;
        unsigned logRbO = 0xFFFFFFFFu;
        unsigned curRoot = 0xFFFFFFFFu;
        unsigned long long logNode = 0;
        int logCount = 0;
        while (candm != 0ULL) {
            int j = __ffsll((long long)candm) - 1;
            candm &= candm - 1ULL;
            unsigned sAB = __shfl(specAB, j);
            unsigned cra = sAB >> 16;
            unsigned crb = sAB & 0xFFFFu;
            // O(1) resolve: consumed roots have exactly one log entry; its curRoot is current
            unsigned long long hitA = __ballot(logRa == cra);
            unsigned long long hitB = __ballot(logRa == crb);
            if (hitA) cra = __shfl(curRoot, __ffsll((long long)hitA) - 1);
            if (hitB) crb = __shfl(curRoot, __ffsll((long long)hitB) - 1);
            if (cra == crb) continue;                      // became connected within batch
            unsigned ce = (unsigned)__shfl(e, j);
            // node values: latest entry that merged INTO this (current) root, else batch-start
            unsigned long long hbA = __ballot(logRbO == cra);
            unsigned long long hbB = __ballot(logRbO == crb);
            unsigned long long cna = hbA ? __shfl(logNode, 63 - __clzll((long long)hbA)) : __shfl(na, j);
            unsigned long long cnb = hbB ? __shfl(logNode, 63 - __clzll((long long)hbB)) : __shfl(nb, j);
            unsigned headA = (unsigned)(cna >> 48);
            unsigned tailA = (unsigned)(cna >> 32) & 0xFFFFu;
            unsigned szA   = (unsigned)(cna >> 16) & 0xFFFFu;
            unsigned slA   = (unsigned)cna & 0xFFFFu;
            unsigned headB = (unsigned)(cnb >> 48);
            unsigned tailB = (unsigned)(cnb >> 32) & 0xFFFFu;
            unsigned szB   = (unsigned)(cnb >> 16) & 0xFFFFu;
            unsigned slB   = (unsigned)cnb & 0xFFFFu;
            unsigned long long merged =
                  ((unsigned long long)headA << 48)
                | ((unsigned long long)tailB << 32)
                | ((unsigned long long)(szA + szB) << 16)
                | (unsigned long long)(slA + slB);
            if (curRoot == cra) curRoot = crb;             // path compression (all lanes, uniform)
            if (lane == logCount) {
                logRa = cra; logRbO = crb; curRoot = crb; logNode = merged;
                parentS[cra] = (unsigned short)crb;        // fire-and-forget commits:
                nodeS[crb]   = merged;                     //  nothing in this batch reads them
                nextS[tailA] = (unsigned short)headB;
                mrA[m] = (headA << 16) | headB;
                mrB[m] = (szA << 16) | szB;
                mSS[m] = slA * slB;
                mED[m] = (unsigned short)ce;
            }
            logCount++;
            m++;
        }
    }
    if (lane == 0) *(int*)(mg + MRG_M) = m;
    for (int i = lane; i < NPIX; i += 64) mNX[i] = nextS[i];
}

// ============================ K4: list-rank + chunked prefix dots + loss ============================
__global__ __launch_bounds__(256, 2)
void k4_weights(const float* __restrict__ t_glob,
                const float* __restrict__ p_glob,
                const unsigned short* __restrict__ pixLab_g,
                const int* __restrict__ Kg,
                const char* __restrict__ mrg_base,
                float* __restrict__ out) {
    const int tid = threadIdx.x;
    const int wg  = blockIdx.x;
    const int sgn = wg & 1;
    const int tileId = wg >> 1;
    const int bat = tileId >> 6;
    const int tile = tileId & 63;
    const int tr = tile >> 3, tc = tile & 7;

    __shared__ float          pT[NPIX];
    __shared__ unsigned char  bgS[NPIX];
    __shared__ unsigned short pixLab[NPIX];
    __shared__ unsigned short posS[NPIX];
    __shared__ unsigned int   mRecA[NMERGE];
    __shared__ unsigned int   mRecB[NMERGE];
    __shared__ unsigned int   mSaSb[NMERGE];
    __shared__ unsigned int   commonW[NMERGE];
    __shared__ unsigned short mEd[NMERGE];
    __shared__ __align__(16) unsigned long long big[2564];
    __shared__ unsigned wsumSh;
    __shared__ float lossSh;

    const char* mg = mrg_base + (size_t)wg * MRG_STRIDE;
    const int M = *(const int*)(mg + MRG_M);
    const int K = Kg[tileId];
    const unsigned int*   mrA = (const unsigned int*)(mg + MRG_RA);
    const unsigned int*   mrB = (const unsigned int*)(mg + MRG_RB);
    const unsigned int*   mSS = (const unsigned int*)(mg + MRG_SS);
    const unsigned short* mED = (const unsigned short*)(mg + MRG_ED);
    const unsigned short* mNX = (const unsigned short*)(mg + MRG_NXT);

    for (int i = tid; i < NPIX; i += 256) {
        int y = i >> 5, x = i & 31;
        int gidx = bat * 65536 + (tr * 32 + y) * 256 + (tc * 32 + x);
        pT[i] = p_glob[gidx];
        bgS[i] = (t_glob[gidx] == 0.0f) ? 1 : 0;
        pixLab[i] = pixLab_g[tileId * NPIX + i];
    }
    for (int j = tid; j < M; j += 256) {
        mRecA[j] = mrA[j];
        mRecB[j] = mrB[j];
        mSaSb[j] = mSS[j];
        mEd[j]   = mED[j];
        commonW[j] = 0;
    }

    // ---- Wyllie list ranking -> posS ----
    unsigned short* n0 = (unsigned short*)big;
    unsigned short* n1 = n0 + 1024;
    unsigned short* d0 = n0 + 2048;
    unsigned short* d1 = n0 + 3072;
    for (int i = tid; i < NPIX; i += 256) { n0[i] = mNX[i]; d0[i] = 1; }
    __syncthreads();
    for (int s = 0; s < 10; s++) {
        unsigned short* sn = (s & 1) ? n1 : n0;
        unsigned short* sd = (s & 1) ? d1 : d0;
        unsigned short* dn = (s & 1) ? n0 : n1;
        unsigned short* dd = (s & 1) ? d0 : d1;
        for (int i = tid; i < NPIX; i += 256) {
            unsigned nx = sn[i];
            unsigned dv = sd[i];
            if (nx != NIL) { dv += sd[nx]; nx = sn[nx]; }
            dn[i] = (unsigned short)nx;
            dd[i] = (unsigned short)dv;
        }
        __syncthreads();
    }
    for (int i = tid; i < NPIX; i += 256)
        posS[i] = (unsigned short)(NPIX - (int)d0[i]);
    __syncthreads();

    // ---- chunked label prefix sums + per-merge dots ----
    unsigned*       P32 = (unsigned*)big;
    uint4*          P4  = (uint4*)big;
    unsigned*       scr = P32 + 4100;
    uint4*          S4  = (uint4*)scr;
    unsigned short* P16 = (unsigned short*)big;
    for (int base = 0; base < K; base += CHUNK) {
        for (int idx = tid; idx < 4100; idx += 256) P32[idx] = 0;
        __syncthreads();
        for (int i = tid; i < NPIX; i += 256) {
            unsigned l = pixLab[i];
            if (l != NIL && l >= (unsigned)base && l < (unsigned)(base + CHUNK))
                P16[(posS[i] + 1) * 8 + (l - base)] = 1;
        }
        __syncthreads();
        {
            int r0 = tid * 4 + 1;
            uint4 acc = P4[r0];
            for (int rr = r0 + 1; rr <= r0 + 3; rr++) { acc = add4(acc, P4[rr]); P4[rr] = acc; }
            S4[tid] = acc;
            __syncthreads();
            if (tid < 64) {
                uint4 s0 = S4[tid * 4], s1 = S4[tid * 4 + 1], s2 = S4[tid * 4 + 2], s3 = S4[tid * 4 + 3];
                uint4 t1 = add4(s0, s1), t2 = add4(t1, s2), t3 = add4(t2, s3);
                uint4 run = t3;
                #pragma unroll
                for (int d = 1; d < 64; d <<= 1) {
                    uint4 o;
                    o.x = __shfl_up(run.x, d, 64);
                    o.y = __shfl_up(run.y, d, 64);
                    o.z = __shfl_up(run.z, d, 64);
                    o.w = __shfl_up(run.w, d, 64);
                    if (tid >= d) run = add4(run, o);
                }
                uint4 off = sub4(run, t3);
                S4[tid * 4]     = add4(s0, off);
                S4[tid * 4 + 1] = add4(t1, off);
                S4[tid * 4 + 2] = add4(t2, off);
                S4[tid * 4 + 3] = add4(t3, off);
            }
            __syncthreads();
            if (tid > 0) {
                uint4 off = S4[tid - 1];
                for (int rr = r0; rr <= r0 + 3; rr++) P4[rr] = add4(P4[rr], off);
            }
        }
        __syncthreads();
        for (int j = tid; j < M; j += 256) {
            unsigned recA = mRecA[j], recB = mRecB[j];
            unsigned aS = posS[recA >> 16];
            unsigned bS = posS[recA & 0xFFFFu];
            uint4 da = sub4(P4[aS + (recB >> 16)], P4[aS]);
            uint4 db = sub4(P4[bS + (recB & 0xFFFFu)], P4[bS]);
            unsigned acc;
            acc  = (da.x & 0xFFFFu) * (db.x & 0xFFFFu) + (da.x >> 16) * (db.x >> 16);
            acc += (da.y & 0xFFFFu) * (db.y & 0xFFFFu) + (da.y >> 16) * (db.y >> 16);
            acc += (da.z & 0xFFFFu) * (db.z & 0xFFFFu) + (da.z >> 16) * (db.z >> 16);
            acc += (da.w & 0xFFFFu) * (db.w & 0xFFFFu) + (da.w >> 16) * (db.w >> 16);
            commonW[j] += acc;
        }
        __syncthreads();
    }

    // ---- normalize + mask + loss ----
    if (tid == 0) { wsumSh = 0; lossSh = 0.0f; }
    __syncthreads();
    unsigned wloc = 0;
    for (int j = tid; j < M; j += 256)
        wloc += (sgn == 0) ? (mSaSb[j] - commonW[j]) : commonW[j];
    if (wloc) atomicAdd(&wsumSh, wloc);
    __syncthreads();
    const unsigned wsum = wsumSh;
    if (wsum > 0) {
        const double inv = 1.0 / (double)wsum;
        float lloc = 0.0f;
        for (int j = tid; j < M; j += 256) {
            unsigned w = (sgn == 0) ? (mSaSb[j] - commonW[j]) : commonW[j];
            if (!w) continue;
            int e = mEd[j];
            int a, b; edge_ab(e, a, b);
            int nfg = (int)(!bgS[a]) + (int)(!bgS[b]);
            bool keep = (sgn == 0) ? (nfg == 0) : (nfg >= 1);
            if (!keep) continue;
            float wn = (float)((double)w * inv);
            float fa, fb;
            if (sgn == 0) { fa = pT[a] * pT[a];            fb = pT[b] * pT[b]; }
            else { float da = 20.0f - pT[a], db = 20.0f - pT[b]; fa = da * da; fb = db * db; }
            lloc += wn * (fa + fb);
        }
        if (lloc != 0.0f) atomicAdd(&lossSh, lloc);
        __syncthreads();
        if (tid == 0 && lossSh != 0.0f) atomicAdd(out, lossSh);
    }
}

// ============================ fallback: monolith (used if ws too small) ============================
__global__ __launch_bounds__(256, 2)
void malis_mono(const float* __restrict__ t_glob,
                const float* __restrict__ p_glob,
                float* __restrict__ out) {
    const int tid  = threadIdx.x;
    const int wg   = blockIdx.x;
    const int sgn  = wg & 1;
    const int tileId = wg >> 1;
    const int bat  = tileId >> 6;
    const int tile = tileId & 63;
    const int tr = tile >> 3, tc = tile & 7;

    __shared__ float          pT[NPIX];
    __shared__ unsigned char  bgS[NPIX];
    __shared__ unsigned short pixLab[NPIX];
    __shared__ unsigned short parentS[NPIX];
    __shared__ unsigned short nextS[NPIX];
    __shared__ unsigned long long nodeS[NPIX];
    __shared__ unsigned short posS[NPIX];
    __shared__ unsigned short orderS[NEDGE];
    __shared__ unsigned int   mRecA[NMERGE];
    __shared__ unsigned int   mRecB[NMERGE];
    __shared__ unsigned short mEd[NMERGE];
    __shared__ unsigned int   mSaSb[NMERGE];
    __shared__ unsigned int   commonW[NMERGE];
    __shared__ __align__(16) unsigned long long big[2564];
    __shared__ int   kprimeSh, mCountSh;
    __shared__ unsigned wsumSh;
    __shared__ float lossSh;

    for (int i = tid; i < NPIX; i += 256) {
        int y = i >> 5, x = i & 31;
        int gidx = bat * 65536 + (tr * 32 + y) * 256 + (tc * 32 + x);
        pT[i] = p_glob[gidx];
        bgS[i] = (t_glob[gidx] == 0.0f) ? 1 : 0;
    }
    __syncthreads();

    unsigned short* labS = (unsigned short*)big;
    unsigned int*   cntS = (unsigned int*)(((char*)big) + 2048);
    if (tid < 64) {
        const int lane = tid;
        if (lane < 32) {
            #pragma unroll
            for (int x = 0; x < 32; x++) {
                int i = lane * 32 + x;
                labS[i] = bgS[i] ? (unsigned short)i : (unsigned short)NIL;
            }
        }
        while (true) {
            bool changed = false;
            if (lane < 32) {
                const int base = lane * 32;
                unsigned short v[32];
                #pragma unroll
                for (int x = 0; x < 32; x++) v[x] = labS[base + x];
                unsigned run = NIL;
                #pragma unroll
                for (int x = 0; x < 32; x++) {
                    unsigned val = v[x];
                    if (val == NIL) { run = NIL; }
                    else { unsigned nv = min(run, val); changed |= (nv != val); v[x] = (unsigned short)nv; run = nv; }
                }
                run = NIL;
                #pragma unroll
                for (int x = 31; x >= 0; x--) {
                    unsigned val = v[x];
                    if (val == NIL) { run = NIL; }
                    else { unsigned nv = min(run, val); changed |= (nv != val); v[x] = (unsigned short)nv; run = nv; }
                }
                #pragma unroll
                for (int x = 0; x < 32; x++) labS[base + x] = v[x];
            }
            if (lane < 32) {
                unsigned short c[32];
                #pragma unroll
                for (int k = 0; k < 32; k++) c[k] = labS[k * 32 + lane];
                unsigned run = NIL;
                #pragma unroll
                for (int k = 0; k < 32; k++) {
                    unsigned val = c[k];
                    if (val == NIL) { run = NIL; }
                    else { unsigned nv = min(run, val); changed |= (nv != val); c[k] = (unsigned short)nv; run = nv; }
                }
                run = NIL;
                #pragma unroll
                for (int k = 31; k >= 0; k--) {
                    unsigned val = c[k];
                    if (val == NIL) { run = NIL; }
                    else { unsigned nv = min(run, val); changed |= (nv != val); c[k] = (unsigned short)nv; run = nv; }
                }
                #pragma unroll
                for (int k = 0; k < 32; k++) labS[k * 32 + lane] = c[k];
            }
            if (!__any(changed)) break;
        }
    }
    __syncthreads();

    for (int i = tid; i < NPIX; i += 256) cntS[i] = 0;
    if (tid == 0) kprimeSh = 0;
    __syncthreads();
    for (int i = tid; i < NPIX; i += 256)
        if (bgS[i]) atomicAdd(&cntS[labS[i]], 1u);
    __syncthreads();
    for (int i = tid; i < NPIX; i += 256) {
        if (bgS[i] && (int)labS[i] == i) {
            unsigned id = (cntS[i] >= 2) ? (unsigned)atomicAdd(&kprimeSh, 1) : NIL;
            cntS[i] = id;
        }
    }
    __syncthreads();
    for (int i = tid; i < NPIX; i += 256)
        pixLab[i] = bgS[i] ? (unsigned short)cntS[labS[i]] : (unsigned short)NIL;
    __syncthreads();
    const int K = kprimeSh;

    unsigned long long* keys = big;
    for (int k = tid; k < SORTN; k += 256) {
        unsigned long long key = 0ULL;
        if (k < NEDGE) {
            int a, b; edge_ab(k, a, b);
            float cost = pT[a] + pT[b];
            int nfg = (int)(!bgS[a]) + (int)(!bgS[b]);
            if (sgn == 0) { if (nfg == 2) cost = 20.0f; }
            else          { if (nfg == 0) cost = 0.0f;  }
            key = ((unsigned long long)__float_as_uint(cost) << 16)
                | (unsigned long long)(0xFFFFu - (unsigned)k);
        }
        keys[k] = key;
    }
    __syncthreads();
    for (int kk = 2; kk <= SORTN; kk <<= 1) {
        for (int jj = kk >> 1; jj > 0; jj >>= 1) {
            for (int i = tid; i < SORTN; i += 256) {
                int ixj = i ^ jj;
                if (ixj > i) {
                    unsigned long long A = keys[i], Bv = keys[ixj];
                    bool descBlk = ((i & kk) == 0);
                    if ((A < Bv) == descBlk) { keys[i] = Bv; keys[ixj] = A; }
                }
            }
            __syncthreads();
        }
    }
    for (int k = tid; k < NEDGE; k += 256)
        orderS[k] = (unsigned short)(0xFFFFu - (unsigned)(keys[k] & 0xFFFFULL));
    for (int i = tid; i < NPIX; i += 256) {
        parentS[i] = (unsigned short)i;
        nodeS[i] = ((unsigned long long)i << 48) | ((unsigned long long)i << 32)
                 | (1ULL << 16) | (unsigned long long)bgS[i];
        nextS[i] = (unsigned short)NIL;
    }
    __syncthreads();

    if (tid < 64) {
        const int lane = tid;
        int m = 0;
        for (int kb = 0; kb < NEDGE; kb += 64) {
            int e = orderS[kb + lane];
            int a, b; edge_ab(e, a, b);
            unsigned ra = (unsigned)a, rb = (unsigned)b;
            while (true) {
                unsigned pa = parentS[ra];
                unsigned pb = parentS[rb];
                if (pa == ra && pb == rb) break;
                if (pa != ra) { unsigned ga = parentS[pa]; parentS[ra] = (unsigned short)ga; ra = ga; }
                if (pb != rb) { unsigned gb = parentS[pb]; parentS[rb] = (unsigned short)gb; rb = gb; }
            }
            unsigned specAB = (ra << 16) | rb;
            unsigned long long na = nodeS[ra];
            unsigned long long nb = nodeS[rb];
            unsigned long long candm = __ballot(ra != rb);

            unsigned logRa = 0xFFFFFFFFu, logRbO = 0xFFFFFFFFu, curRoot = 0xFFFFFFFFu;
            unsigned long long logNode = 0;
            int logCount = 0;
            while (candm != 0ULL) {
                int j = __ffsll((long long)candm) - 1;
                candm &= candm - 1ULL;
                unsigned sAB = __shfl(specAB, j);
                unsigned cra = sAB >> 16;
                unsigned crb = sAB & 0xFFFFu;
                unsigned long long hitA = __ballot(logRa == cra);
                unsigned long long hitB = __ballot(logRa == crb);
                if (hitA) cra = __shfl(curRoot, __ffsll((long long)hitA) - 1);
                if (hitB) crb = __shfl(curRoot, __ffsll((long long)hitB) - 1);
                if (cra == crb) continue;
                unsigned ce = (unsigned)__shfl(e, j);
                unsigned long long hbA = __ballot(logRbO == cra);
                unsigned long long hbB = __ballot(logRbO == crb);
                unsigned long long cna = hbA ? __shfl(logNode, 63 - __clzll((long long)hbA)) : __shfl(na, j);
                unsigned long long cnb = hbB ? __shfl(logNode, 63 - __clzll((long long)hbB)) : __shfl(nb, j);
                unsigned headA = (unsigned)(cna >> 48);
                unsigned tailA = (unsigned)(cna >> 32) & 0xFFFFu;
                unsigned szA   = (unsigned)(cna >> 16) & 0xFFFFu;
                unsigned slA   = (unsigned)cna & 0xFFFFu;
                unsigned headB = (unsigned)(cnb >> 48);
                unsigned tailB = (unsigned)(cnb >> 32) & 0xFFFFu;
                unsigned szB   = (unsigned)(cnb >> 16) & 0xFFFFu;
                unsigned slB   = (unsigned)cnb & 0xFFFFu;
                unsigned long long merged =
                      ((unsigned long long)headA << 48)
                    | ((unsigned long long)tailB << 32)
                    | ((unsigned long long)(szA + szB) << 16)
                    | (unsigned long long)(slA + slB);
                if (curRoot == cra) curRoot = crb;
                if (lane == logCount) {
                    logRa = cra; logRbO = crb; curRoot = crb; logNode = merged;
                    parentS[cra] = (unsigned short)crb;
                    nodeS[crb]   = merged;
                    nextS[tailA] = (unsigned short)headB;
                    mRecA[m] = (headA << 16) | headB;
                    mRecB[m] = (szA << 16) | szB;
                    mSaSb[m] = slA * slB;
                    mEd[m]   = (unsigned short)ce;
                }
                logCount++;
                m++;
            }
        }
        if (lane == 0) mCountSh = m;
    }
    __syncthreads();
    const int M = mCountSh;
    for (int j = tid; j < M; j += 256) commonW[j] = 0;

    unsigned short* n0 = (unsigned short*)big;
    unsigned short* n1 = n0 + 1024;
    unsigned short* d0 = n0 + 2048;
    unsigned short* d1 = n0 + 3072;
    for (int i = tid; i < NPIX; i += 256) { n0[i] = nextS[i]; d0[i] = 1; }
    __syncthreads();
    for (int s = 0; s < 10; s++) {
        unsigned short* sn = (s & 1) ? n1 : n0;
        unsigned short* sd = (s & 1) ? d1 : d0;
        unsigned short* dn = (s & 1) ? n0 : n1;
        unsigned short* dd = (s & 1) ? d0 : d1;
        for (int i = tid; i < NPIX; i += 256) {
            unsigned nx = sn[i];
            unsigned dv = sd[i];
            if (nx != NIL) { dv += sd[nx]; nx = sn[nx]; }
            dn[i] = (unsigned short)nx;
            dd[i] = (unsigned short)dv;
        }
        __syncthreads();
    }
    for (int i = tid; i < NPIX; i += 256)
        posS[i] = (unsigned short)(NPIX - (int)d0[i]);
    __syncthreads();

    unsigned*       P32 = (unsigned*)big;
    uint4*          P4  = (uint4*)big;
    unsigned*       scr = P32 + 4100;
    uint4*          S4  = (uint4*)scr;
    unsigned short* P16 = (unsigned short*)big;
    for (int base = 0; base < K; base += CHUNK) {
        for (int idx = tid; idx < 4100; idx += 256) P32[idx] = 0;
        __syncthreads();
        for (int i = tid; i < NPIX; i += 256) {
            unsigned l = pixLab[i];
            if (l != NIL && l >= (unsigned)base && l < (unsigned)(base + CHUNK))
                P16[(posS[i] + 1) * 8 + (l - base)] = 1;
        }
        __syncthreads();
        {
            int r0 = tid * 4 + 1;
            uint4 acc = P4[r0];
            for (int rr = r0 + 1; rr <= r0 + 3; rr++) { acc = add4(acc, P4[rr]); P4[rr] = acc; }
            S4[tid] = acc;
            __syncthreads();
            if (tid < 64) {
                uint4 s0 = S4[tid * 4], s1 = S4[tid * 4 + 1], s2 = S4[tid * 4 + 2], s3 = S4[tid * 4 + 3];
                uint4 t1 = add4(s0, s1), t2 = add4(t1, s2), t3 = add4(t2, s3);
                uint4 run = t3;
                #pragma unroll
                for (int d = 1; d < 64; d <<= 1) {
                    uint4 o;
                    o.x = __shfl_up(run.x, d, 64);
                    o.y = __shfl_up(run.y, d, 64);
                    o.z = __shfl_up(run.z, d, 64);
                    o.w = __shfl_up(run.w, d, 64);
                    if (tid >= d) run = add4(run, o);
                }
                uint4 off = sub4(run, t3);
                S4[tid * 4]     = add4(s0, off);
                S4[tid * 4 + 1] = add4(t1, off);
                S4[tid * 4 + 2] = add4(t2, off);
                S4[tid * 4 + 3] = add4(t3, off);
            }
            __syncthreads();
            if (tid > 0) {
                uint4 off = S4[tid - 1];
                for (int rr = r0; rr <= r0 + 3; rr++) P4[rr] = add4(P4[rr], off);
            }
        }
        __syncthreads();
        for (int j = tid; j < M; j += 256) {
            unsigned recA = mRecA[j], recB = mRecB[j];
            unsigned aS = posS[recA >> 16];
            unsigned bS = posS[recA & 0xFFFFu];
            uint4 da = sub4(P4[aS + (recB >> 16)], P4[aS]);
            uint4 db = sub4(P4[bS + (recB & 0xFFFFu)], P4[bS]);
            unsigned acc;
            acc  = (da.x & 0xFFFFu) * (db.x & 0xFFFFu) + (da.x >> 16) * (db.x >> 16);
            acc += (da.y & 0xFFFFu) * (db.y & 0xFFFFu) + (da.y >> 16) * (db.y >> 16);
            acc += (da.z & 0xFFFFu) * (db.z & 0xFFFFu) + (da.z >> 16) * (db.z >> 16);
            acc += (da.w & 0xFFFFu) * (db.w & 0xFFFFu) + (da.w >> 16) * (db.w >> 16);
            commonW[j] += acc;
        }
        __syncthreads();
    }

    if (tid == 0) { wsumSh = 0; lossSh = 0.0f; }
    __syncthreads();
    unsigned wloc = 0;
    for (int j = tid; j < M; j += 256)
        wloc += (sgn == 0) ? (mSaSb[j] - commonW[j]) : commonW[j];
    if (wloc) atomicAdd(&wsumSh, wloc);
    __syncthreads();
    const unsigned wsum = wsumSh;
    if (wsum > 0) {
        const double inv = 1.0 / (double)wsum;
        float lloc = 0.0f;
        for (int j = tid; j < M; j += 256) {
            unsigned w = (sgn == 0) ? (mSaSb[j] - commonW[j]) : commonW[j];
            if (!w) continue;
            int e = mEd[j];
            int a, b; edge_ab(e, a, b);
            int nfg = (int)(!bgS[a]) + (int)(!bgS[b]);
            bool keep = (sgn == 0) ? (nfg == 0) : (nfg >= 1);
            if (!keep) continue;
            float wn = (float)((double)w * inv);
            float fa, fb;
            if (sgn == 0) { fa = pT[a] * pT[a];            fb = pT[b] * pT[b]; }
            else { float da = 20.0f - pT[a], db = 20.0f - pT[b]; fa = da * da; fb = db * db; }
            lloc += wn * (fa + fb);
        }
        if (lloc != 0.0f) atomicAdd(&lossSh, lloc);
        __syncthreads();
        if (tid == 0 && lossSh != 0.0f) atomicAdd(out, lossSh);
    }
}

extern "C" void kernel_launch(void* const* d_in, const int* in_sizes, int n_in,
                              void* d_out, int out_size, void* d_ws, size_t ws_size,
                              hipStream_t stream) {
    const float* y_true = (const float*)d_in[0];
    const float* y_pred = (const float*)d_in[1];
    float* out = (float*)d_out;
    const int B  = in_sizes[0] / (256 * 256);
    const int nT = B * 64;
    const int nW = nT * 2;

    const size_t offK   = (size_t)nT * 2048;
    const size_t offOrd = offK + (((size_t)nT * 4 + 255) & ~(size_t)255);
    const size_t offMrg = offOrd + (size_t)nW * 4096;
    const size_t need   = offMrg + (size_t)nW * MRG_STRIDE;

    hipMemsetAsync(d_out, 0, (size_t)out_size * sizeof(float), stream);

    if (ws_size >= need) {
        char* ws = (char*)d_ws;
        unsigned short* pixLab_g = (unsigned short*)ws;
        int*            Kg       = (int*)(ws + offK);
        unsigned short* ord_g    = (unsigned short*)(ws + offOrd);
        char*           mrg      = ws + offMrg;
        hipLaunchKernelGGL(k12_ccl_sort, dim3(nT + nW), dim3(256), 0, stream,
                           y_true, y_pred, pixLab_g, Kg, ord_g, nT);
        hipLaunchKernelGGL(k3_kruskal,   dim3(nW), dim3(64),  0, stream, y_true, ord_g, mrg);
        hipLaunchKernelGGL(k4_weights,   dim3(nW), dim3(256), 0, stream, y_true, y_pred,
                           pixLab_g, Kg, mrg, out);
    } else {
        hipLaunchKernelGGL(malis_mono, dim3(nW), dim3(256), 0, stream, y_true, y_pred, out);
    }
}

// Round 8
// 486.177 us; speedup vs baseline: 1.4696x; 1.0198x over previous
//
#include <hip/hip_runtime.h>

#define NPIX   1024   // 32*32
#define NEH    992    // horizontal edges 32*31
#define NEDGE  1984   // + vertical 31*32
#define SORTN  2048
#define CHUNK  8      // labels per phase-2 pass
#define NMERGE 1023
#define NIL    0xFFFFu

// per-(tile,sgn) merge-record block in ws (20480 B stride)
#define MRG_STRIDE 20480
#define MRG_M      0
#define MRG_RA     256
#define MRG_RB     4608
#define MRG_SS     8960
#define MRG_ED     13312
#define MRG_NXT    15616

__device__ __forceinline__ void edge_ab(int e, int& a, int& b) {
    if (e < NEH) { int y = e / 31; int x = e - y * 31; a = y * 32 + x; b = a + 1; }
    else         { int ev = e - NEH; a = ev; b = ev + 32; }
}

__device__ __forceinline__ uint4 add4(uint4 x, uint4 y) {
    return make_uint4(x.x + y.x, x.y + y.y, x.z + y.z, x.w + y.w);
}
__device__ __forceinline__ uint4 sub4(uint4 x, uint4 y) {
    return make_uint4(x.x - y.x, x.y - y.y, x.z - y.z, x.w - y.w);
}

// wave-uniform broadcast via v_readlane (VALU/SALU class, ~8cy; no LDS round-trip)
__device__ __forceinline__ unsigned rdl32(unsigned v, int lane) {
    return (unsigned)__builtin_amdgcn_readlane((int)v, lane);
}
__device__ __forceinline__ unsigned long long rdl64(unsigned long long v, int lane) {
    unsigned lo = (unsigned)__builtin_amdgcn_readlane((int)(unsigned)v, lane);
    unsigned hi = (unsigned)__builtin_amdgcn_readlane((int)(unsigned)(v >> 32), lane);
    return ((unsigned long long)hi << 32) | lo;
}

// ============================ fused K1/K2 bodies ============================
__device__ void ccl_body(char* smem, int* kprimeSh,
                         const float* __restrict__ t_glob,
                         unsigned short* __restrict__ pixLab_g,
                         int* __restrict__ Kg, int tileId) {
    const int tid = threadIdx.x;
    const int bat = tileId >> 6;
    const int tile = tileId & 63;
    const int tr = tile >> 3, tc = tile & 7;

    unsigned short* labS = (unsigned short*)smem;                 // [0,2048)
    unsigned int*   cntS = (unsigned int*)(smem + 2048);          // [2048,6144)
    unsigned char*  bgS  = (unsigned char*)(smem + 20480);        // [20480,21504)

    for (int i = tid; i < NPIX; i += 256) {
        int y = i >> 5, x = i & 31;
        int gidx = bat * 65536 + (tr * 32 + y) * 256 + (tc * 32 + x);
        bgS[i] = (t_glob[gidx] == 0.0f) ? 1 : 0;
    }
    __syncthreads();

    if (tid < 64) {
        const int lane = tid;
        if (lane < 32) {
            #pragma unroll
            for (int x = 0; x < 32; x++) {
                int i = lane * 32 + x;
                labS[i] = bgS[i] ? (unsigned short)i : (unsigned short)NIL;
            }
        }
        while (true) {
            bool changed = false;
            if (lane < 32) {
                const int base = lane * 32;
                unsigned short v[32];
                #pragma unroll
                for (int x = 0; x < 32; x++) v[x] = labS[base + x];
                unsigned run = NIL;
                #pragma unroll
                for (int x = 0; x < 32; x++) {
                    unsigned val = v[x];
                    if (val == NIL) { run = NIL; }
                    else { unsigned nv = min(run, val); changed |= (nv != val); v[x] = (unsigned short)nv; run = nv; }
                }
                run = NIL;
                #pragma unroll
                for (int x = 31; x >= 0; x--) {
                    unsigned val = v[x];
                    if (val == NIL) { run = NIL; }
                    else { unsigned nv = min(run, val); changed |= (nv != val); v[x] = (unsigned short)nv; run = nv; }
                }
                #pragma unroll
                for (int x = 0; x < 32; x++) labS[base + x] = v[x];
            }
            if (lane < 32) {
                unsigned short c[32];
                #pragma unroll
                for (int k = 0; k < 32; k++) c[k] = labS[k * 32 + lane];
                unsigned run = NIL;
                #pragma unroll
                for (int k = 0; k < 32; k++) {
                    unsigned val = c[k];
                    if (val == NIL) { run = NIL; }
                    else { unsigned nv = min(run, val); changed |= (nv != val); c[k] = (unsigned short)nv; run = nv; }
                }
                run = NIL;
                #pragma unroll
                for (int k = 31; k >= 0; k--) {
                    unsigned val = c[k];
                    if (val == NIL) { run = NIL; }
                    else { unsigned nv = min(run, val); changed |= (nv != val); c[k] = (unsigned short)nv; run = nv; }
                }
                #pragma unroll
                for (int k = 0; k < 32; k++) labS[k * 32 + lane] = c[k];
            }
            if (!__any(changed)) break;
        }
    }
    __syncthreads();

    for (int i = tid; i < NPIX; i += 256) cntS[i] = 0;
    if (tid == 0) *kprimeSh = 0;
    __syncthreads();
    for (int i = tid; i < NPIX; i += 256)
        if (bgS[i]) atomicAdd(&cntS[labS[i]], 1u);
    __syncthreads();
    for (int i = tid; i < NPIX; i += 256) {
        if (bgS[i] && (int)labS[i] == i) {
            unsigned id = (cntS[i] >= 2) ? (unsigned)atomicAdd(kprimeSh, 1) : NIL;
            cntS[i] = id;
        }
    }
    __syncthreads();
    for (int i = tid; i < NPIX; i += 256)
        pixLab_g[tileId * NPIX + i] = bgS[i] ? (unsigned short)cntS[labS[i]] : (unsigned short)NIL;
    if (tid == 0) Kg[tileId] = *kprimeSh;
}

__device__ void sort_body(char* smem,
                          const float* __restrict__ t_glob,
                          const float* __restrict__ p_glob,
                          unsigned short* __restrict__ ord_g, int wg) {
    const int tid = threadIdx.x;
    const int sgn = wg & 1;
    const int tileId = wg >> 1;
    const int bat = tileId >> 6;
    const int tile = tileId & 63;
    const int tr = tile >> 3, tc = tile & 7;

    float*              pT   = (float*)smem;                      // [0,4096)
    unsigned long long* keys = (unsigned long long*)(smem + 4096);// [4096,20480)
    unsigned char*      bgS  = (unsigned char*)(smem + 20480);    // [20480,21504)

    for (int i = tid; i < NPIX; i += 256) {
        int y = i >> 5, x = i & 31;
        int gidx = bat * 65536 + (tr * 32 + y) * 256 + (tc * 32 + x);
        pT[i] = p_glob[gidx];
        bgS[i] = (t_glob[gidx] == 0.0f) ? 1 : 0;
    }
    __syncthreads();

    for (int k = tid; k < SORTN; k += 256) {
        unsigned long long key = 0ULL;
        if (k < NEDGE) {
            int a, b; edge_ab(k, a, b);
            float cost = pT[a] + pT[b];
            int nfg = (int)(!bgS[a]) + (int)(!bgS[b]);
            if (sgn == 0) { if (nfg == 2) cost = 20.0f; }
            else          { if (nfg == 0) cost = 0.0f;  }
            key = ((unsigned long long)__float_as_uint(cost) << 16)
                | (unsigned long long)(0xFFFFu - (unsigned)k);
        }
        keys[k] = key;
    }
    __syncthreads();
    for (int kk = 2; kk <= SORTN; kk <<= 1) {
        for (int jj = kk >> 1; jj > 0; jj >>= 1) {
            for (int i = tid; i < SORTN; i += 256) {
                int ixj = i ^ jj;
                if (ixj > i) {
                    unsigned long long A = keys[i], Bv = keys[ixj];
                    bool descBlk = ((i & kk) == 0);
                    if ((A < Bv) == descBlk) { keys[i] = Bv; keys[ixj] = A; }
                }
            }
            __syncthreads();
        }
    }
    for (int k = tid; k < NEDGE; k += 256)
        ord_g[(size_t)wg * SORTN + k] = (unsigned short)(0xFFFFu - (unsigned)(keys[k] & 0xFFFFULL));
}

__global__ __launch_bounds__(256, 2)
void k12_ccl_sort(const float* __restrict__ t_glob,
                  const float* __restrict__ p_glob,
                  unsigned short* __restrict__ pixLab_g,
                  int* __restrict__ Kg,
                  unsigned short* __restrict__ ord_g,
                  int nT) {
    __shared__ __align__(16) char smem[21504];
    __shared__ int kprimeSh;
    if ((int)blockIdx.x < nT)
        ccl_body(smem, &kprimeSh, t_glob, pixLab_g, Kg, blockIdx.x);
    else
        sort_body(smem, t_glob, p_glob, ord_g, blockIdx.x - nT);
}

// ============================ K3: Kruskal, readlane-chain serial phase ============================
__global__ __launch_bounds__(64)
void k3_kruskal(const float* __restrict__ t_glob,
                const unsigned short* __restrict__ ord_g,
                char* __restrict__ mrg_base) {
    const int lane = threadIdx.x;
    const int wg  = blockIdx.x;
    const int tileId = wg >> 1;
    const int bat = tileId >> 6;
    const int tile = tileId & 63;
    const int tr = tile >> 3, tc = tile & 7;

    __shared__ unsigned short parentS[NPIX];
    __shared__ unsigned long long nodeS[NPIX];
    __shared__ unsigned short nextS[NPIX];

    char* mg = mrg_base + (size_t)wg * MRG_STRIDE;
    unsigned int*   mrA = (unsigned int*)(mg + MRG_RA);
    unsigned int*   mrB = (unsigned int*)(mg + MRG_RB);
    unsigned int*   mSS = (unsigned int*)(mg + MRG_SS);
    unsigned short* mED = (unsigned short*)(mg + MRG_ED);
    unsigned short* mNX = (unsigned short*)(mg + MRG_NXT);
    const unsigned short* ord = ord_g + (size_t)wg * SORTN;

    for (int i = lane; i < NPIX; i += 64) {
        int y = i >> 5, x = i & 31;
        int gidx = bat * 65536 + (tr * 32 + y) * 256 + (tc * 32 + x);
        unsigned bg = (t_glob[gidx] == 0.0f) ? 1u : 0u;
        parentS[i] = (unsigned short)i;
        nodeS[i] = ((unsigned long long)i << 48) | ((unsigned long long)i << 32)
                 | (1ULL << 16) | (unsigned long long)bg;
        nextS[i] = (unsigned short)NIL;
    }
    __syncthreads();

    int m = 0;
    for (int kb = 0; kb < NEDGE; kb += 64) {      // 31 exact batches
        // ---- spec phase: all 64 lanes find roots (concurrent path-halving) ----
        int e = ord[kb + lane];
        int a, b; edge_ab(e, a, b);
        unsigned ra = (unsigned)a, rb = (unsigned)b;
        while (true) {
            unsigned pa = parentS[ra];
            unsigned pb = parentS[rb];
            if (pa == ra && pb == rb) break;
            if (pa != ra) { unsigned ga = parentS[pa]; parentS[ra] = (unsigned short)ga; ra = ga; }
            if (pb != rb) { unsigned gb = parentS[pb]; parentS[rb] = (unsigned short)gb; rb = gb; }
        }
        unsigned specAB = (ra << 16) | rb;                 // roots as of batch start
        unsigned long long na = nodeS[ra];                 // node values as of batch start
        unsigned long long nb = nodeS[rb];
        unsigned long long candm = __ballot(ra != rb);     // spec-equal => definitely connected

        // ---- serial log phase (wave-uniform). Cross-lane traffic = readlane only.
        unsigned logRa  = 0xFFFFFFFFu;   // root consumed by this lane's entry
        unsigned logRbO = 0xFFFFFFFFu;   // surviving root AT MERGE TIME (node-value queries)
        unsigned curRoot = 0xFFFFFFFFu;  // current root of this entry's component
        unsigned long long logNode = 0;
        int logCount = 0;
        while (candm != 0ULL) {
            int j = __ffsll((long long)candm) - 1;         // uniform
            candm &= candm - 1ULL;
            unsigned sAB = rdl32(specAB, j);
            unsigned cra = sAB >> 16;
            unsigned crb = sAB & 0xFFFFu;
            // O(1) resolve: consumed roots have one log entry; its curRoot is current
            unsigned long long hitA = __ballot(logRa == cra);
            unsigned long long hitB = __ballot(logRa == crb);
            if (hitA) cra = rdl32(curRoot, __ffsll((long long)hitA) - 1);
            if (hitB) crb = rdl32(curRoot, __ffsll((long long)hitB) - 1);
            if (cra == crb) continue;                      // became connected within batch
            unsigned ce = rdl32((unsigned)e, j);
            // node values: latest entry that merged INTO this (current) root, else batch-start
            unsigned long long hbA = __ballot(logRbO == cra);
            unsigned long long hbB = __ballot(logRbO == crb);
            unsigned long long cna = hbA ? rdl64(logNode, 63 - __clzll((long long)hbA)) : rdl64(na, j);
            unsigned long long cnb = hbB ? rdl64(logNode, 63 - __clzll((long long)hbB)) : rdl64(nb, j);
            unsigned headA = (unsigned)(cna >> 48);
            unsigned tailA = (unsigned)(cna >> 32) & 0xFFFFu;
            unsigned szA   = (unsigned)(cna >> 16) & 0xFFFFu;
            unsigned slA   = (unsigned)cna & 0xFFFFu;
            unsigned headB = (unsigned)(cnb >> 48);
            unsigned tailB = (unsigned)(cnb >> 32) & 0xFFFFu;
            unsigned szB   = (unsigned)(cnb >> 16) & 0xFFFFu;
            unsigned slB   = (unsigned)cnb & 0xFFFFu;
            unsigned long long merged =
                  ((unsigned long long)headA << 48)
                | ((unsigned long long)tailB << 32)
                | ((unsigned long long)(szA + szB) << 16)
                | (unsigned long long)(slA + slB);
            if (curRoot == cra) curRoot = crb;             // path compression (uniform VALU)
            if (lane == logCount) {
                logRa = cra; logRbO = crb; curRoot = crb; logNode = merged;
                parentS[cra] = (unsigned short)crb;        // fire-and-forget commits
                nodeS[crb]   = merged;
                nextS[tailA] = (unsigned short)headB;
                mrA[m] = (headA << 16) | headB;
                mrB[m] = (szA << 16) | szB;
                mSS[m] = slA * slB;
                mED[m] = (unsigned short)ce;
            }
            logCount++;
            m++;
        }
    }
    if (lane == 0) *(int*)(mg + MRG_M) = m;
    for (int i = lane; i < NPIX; i += 64) mNX[i] = nextS[i];
}

// ============================ K4: list-rank + chunked prefix dots + loss ============================
__global__ __launch_bounds__(256, 2)
void k4_weights(const float* __restrict__ t_glob,
                const float* __restrict__ p_glob,
                const unsigned short* __restrict__ pixLab_g,
                const int* __restrict__ Kg,
                const char* __restrict__ mrg_base,
                float* __restrict__ out) {
    const int tid = threadIdx.x;
    const int wg  = blockIdx.x;
    const int sgn = wg & 1;
    const int tileId = wg >> 1;
    const int bat = tileId >> 6;
    const int tile = tileId & 63;
    const int tr = tile >> 3, tc = tile & 7;

    __shared__ float          pT[NPIX];
    __shared__ unsigned char  bgS[NPIX];
    __shared__ unsigned short pixLab[NPIX];
    __shared__ unsigned short posS[NPIX];
    __shared__ unsigned int   mRecA[NMERGE];
    __shared__ unsigned int   mRecB[NMERGE];
    __shared__ unsigned int   mSaSb[NMERGE];
    __shared__ unsigned int   commonW[NMERGE];
    __shared__ unsigned short mEd[NMERGE];
    __shared__ __align__(16) unsigned long long big[2564];
    __shared__ unsigned wsumSh;
    __shared__ float lossSh;

    const char* mg = mrg_base + (size_t)wg * MRG_STRIDE;
    const int M = *(const int*)(mg + MRG_M);
    const int K = Kg[tileId];
    const unsigned int*   mrA = (const unsigned int*)(mg + MRG_RA);
    const unsigned int*   mrB = (const unsigned int*)(mg + MRG_RB);
    const unsigned int*   mSS = (const unsigned int*)(mg + MRG_SS);
    const unsigned short* mED = (const unsigned short*)(mg + MRG_ED);
    const unsigned short* mNX = (const unsigned short*)(mg + MRG_NXT);

    for (int i = tid; i < NPIX; i += 256) {
        int y = i >> 5, x = i & 31;
        int gidx = bat * 65536 + (tr * 32 + y) * 256 + (tc * 32 + x);
        pT[i] = p_glob[gidx];
        bgS[i] = (t_glob[gidx] == 0.0f) ? 1 : 0;
        pixLab[i] = pixLab_g[tileId * NPIX + i];
    }
    for (int j = tid; j < M; j += 256) {
        mRecA[j] = mrA[j];
        mRecB[j] = mrB[j];
        mSaSb[j] = mSS[j];
        mEd[j]   = mED[j];
        commonW[j] = 0;
    }

    // ---- Wyllie list ranking -> posS ----
    unsigned short* n0 = (unsigned short*)big;
    unsigned short* n1 = n0 + 1024;
    unsigned short* d0 = n0 + 2048;
    unsigned short* d1 = n0 + 3072;
    for (int i = tid; i < NPIX; i += 256) { n0[i] = mNX[i]; d0[i] = 1; }
    __syncthreads();
    for (int s = 0; s < 10; s++) {
        unsigned short* sn = (s & 1) ? n1 : n0;
        unsigned short* sd = (s & 1) ? d1 : d0;
        unsigned short* dn = (s & 1) ? n0 : n1;
        unsigned short* dd = (s & 1) ? d0 : d1;
        for (int i = tid; i < NPIX; i += 256) {
            unsigned nx = sn[i];
            unsigned dv = sd[i];
            if (nx != NIL) { dv += sd[nx]; nx = sn[nx]; }
            dn[i] = (unsigned short)nx;
            dd[i] = (unsigned short)dv;
        }
        __syncthreads();
    }
    for (int i = tid; i < NPIX; i += 256)
        posS[i] = (unsigned short)(NPIX - (int)d0[i]);
    __syncthreads();

    // ---- chunked label prefix sums + per-merge dots ----
    unsigned*       P32 = (unsigned*)big;
    uint4*          P4  = (uint4*)big;
    unsigned*       scr = P32 + 4100;
    uint4*          S4  = (uint4*)scr;
    unsigned short* P16 = (unsigned short*)big;
    for (int base = 0; base < K; base += CHUNK) {
        for (int idx = tid; idx < 4100; idx += 256) P32[idx] = 0;
        __syncthreads();
        for (int i = tid; i < NPIX; i += 256) {
            unsigned l = pixLab[i];
            if (l != NIL && l >= (unsigned)base && l < (unsigned)(base + CHUNK))
                P16[(posS[i] + 1) * 8 + (l - base)] = 1;
        }
        __syncthreads();
        {
            int r0 = tid * 4 + 1;
            uint4 acc = P4[r0];
            for (int rr = r0 + 1; rr <= r0 + 3; rr++) { acc = add4(acc, P4[rr]); P4[rr] = acc; }
            S4[tid] = acc;
            __syncthreads();
            if (tid < 64) {
                uint4 s0 = S4[tid * 4], s1 = S4[tid * 4 + 1], s2 = S4[tid * 4 + 2], s3 = S4[tid * 4 + 3];
                uint4 t1 = add4(s0, s1), t2 = add4(t1, s2), t3 = add4(t2, s3);
                uint4 run = t3;
                #pragma unroll
                for (int d = 1; d < 64; d <<= 1) {
                    uint4 o;
                    o.x = __shfl_up(run.x, d, 64);
                    o.y = __shfl_up(run.y, d, 64);
                    o.z = __shfl_up(run.z, d, 64);
                    o.w = __shfl_up(run.w, d, 64);
                    if (tid >= d) run = add4(run, o);
                }
                uint4 off = sub4(run, t3);
                S4[tid * 4]     = add4(s0, off);
                S4[tid * 4 + 1] = add4(t1, off);
                S4[tid * 4 + 2] = add4(t2, off);
                S4[tid * 4 + 3] = add4(t3, off);
            }
            __syncthreads();
            if (tid > 0) {
                uint4 off = S4[tid - 1];
                for (int rr = r0; rr <= r0 + 3; rr++) P4[rr] = add4(P4[rr], off);
            }
        }
        __syncthreads();
        for (int j = tid; j < M; j += 256) {
            unsigned recA = mRecA[j], recB = mRecB[j];
            unsigned aS = posS[recA >> 16];
            unsigned bS = posS[recA & 0xFFFFu];
            uint4 da = sub4(P4[aS + (recB >> 16)], P4[aS]);
            uint4 db = sub4(P4[bS + (recB & 0xFFFFu)], P4[bS]);
            unsigned acc;
            acc  = (da.x & 0xFFFFu) * (db.x & 0xFFFFu) + (da.x >> 16) * (db.x >> 16);
            acc += (da.y & 0xFFFFu) * (db.y & 0xFFFFu) + (da.y >> 16) * (db.y >> 16);
            acc += (da.z & 0xFFFFu) * (db.z & 0xFFFFu) + (da.z >> 16) * (db.z >> 16);
            acc += (da.w & 0xFFFFu) * (db.w & 0xFFFFu) + (da.w >> 16) * (db.w >> 16);
            commonW[j] += acc;
        }
        __syncthreads();
    }

    // ---- normalize + mask + loss ----
    if (tid == 0) { wsumSh = 0; lossSh = 0.0f; }
    __syncthreads();
    unsigned wloc = 0;
    for (int j = tid; j < M; j += 256)
        wloc += (sgn == 0) ? (mSaSb[j] - commonW[j]) : commonW[j];
    if (wloc) atomicAdd(&wsumSh, wloc);
    __syncthreads();
    const unsigned wsum = wsumSh;
    if (wsum > 0) {
        const double inv = 1.0 / (double)wsum;
        float lloc = 0.0f;
        for (int j = tid; j < M; j += 256) {
            unsigned w = (sgn == 0) ? (mSaSb[j] - commonW[j]) : commonW[j];
            if (!w) continue;
            int e = mEd[j];
            int a, b; edge_ab(e, a, b);
            int nfg = (int)(!bgS[a]) + (int)(!bgS[b]);
            bool keep = (sgn == 0) ? (nfg == 0) : (nfg >= 1);
            if (!keep) continue;
            float wn = (float)((double)w * inv);
            float fa, fb;
            if (sgn == 0) { fa = pT[a] * pT[a];            fb = pT[b] * pT[b]; }
            else { float da = 20.0f - pT[a], db = 20.0f - pT[b]; fa = da * da; fb = db * db; }
            lloc += wn * (fa + fb);
        }
        if (lloc != 0.0f) atomicAdd(&lossSh, lloc);
        __syncthreads();
        if (tid == 0 && lossSh != 0.0f) atomicAdd(out, lossSh);
    }
}

// ============================ fallback: monolith (used if ws too small) ============================
__global__ __launch_bounds__(256, 2)
void malis_mono(const float* __restrict__ t_glob,
                const float* __restrict__ p_glob,
                float* __restrict__ out) {
    const int tid  = threadIdx.x;
    const int wg   = blockIdx.x;
    const int sgn  = wg & 1;
    const int tileId = wg >> 1;
    const int bat  = tileId >> 6;
    const int tile = tileId & 63;
    const int tr = tile >> 3, tc = tile & 7;

    __shared__ float          pT[NPIX];
    __shared__ unsigned char  bgS[NPIX];
    __shared__ unsigned short pixLab[NPIX];
    __shared__ unsigned short parentS[NPIX];
    __shared__ unsigned short nextS[NPIX];
    __shared__ unsigned long long nodeS[NPIX];
    __shared__ unsigned short posS[NPIX];
    __shared__ unsigned short orderS[NEDGE];
    __shared__ unsigned int   mRecA[NMERGE];
    __shared__ unsigned int   mRecB[NMERGE];
    __shared__ unsigned short mEd[NMERGE];
    __shared__ unsigned int   mSaSb[NMERGE];
    __shared__ unsigned int   commonW[NMERGE];
    __shared__ __align__(16) unsigned long long big[2564];
    __shared__ int   kprimeSh, mCountSh;
    __shared__ unsigned wsumSh;
    __shared__ float lossSh;

    for (int i = tid; i < NPIX; i += 256) {
        int y = i >> 5, x = i & 31;
        int gidx = bat * 65536 + (tr * 32 + y) * 256 + (tc * 32 + x);
        pT[i] = p_glob[gidx];
        bgS[i] = (t_glob[gidx] == 0.0f) ? 1 : 0;
    }
    __syncthreads();

    unsigned short* labS = (unsigned short*)big;
    unsigned int*   cntS = (unsigned int*)(((char*)big) + 2048);
    if (tid < 64) {
        const int lane = tid;
        if (lane < 32) {
            #pragma unroll
            for (int x = 0; x < 32; x++) {
                int i = lane * 32 + x;
                labS[i] = bgS[i] ? (unsigned short)i : (unsigned short)NIL;
            }
        }
        while (true) {
            bool changed = false;
            if (lane < 32) {
                const int base = lane * 32;
                unsigned short v[32];
                #pragma unroll
                for (int x = 0; x < 32; x++) v[x] = labS[base + x];
                unsigned run = NIL;
                #pragma unroll
                for (int x = 0; x < 32; x++) {
                    unsigned val = v[x];
                    if (val == NIL) { run = NIL; }
                    else { unsigned nv = min(run, val); changed |= (nv != val); v[x] = (unsigned short)nv; run = nv; }
                }
                run = NIL;
                #pragma unroll
                for (int x = 31; x >= 0; x--) {
                    unsigned val = v[x];
                    if (val == NIL) { run = NIL; }
                    else { unsigned nv = min(run, val); changed |= (nv != val); v[x] = (unsigned short)nv; run = nv; }
                }
                #pragma unroll
                for (int x = 0; x < 32; x++) labS[base + x] = v[x];
            }
            if (lane < 32) {
                unsigned short c[32];
                #pragma unroll
                for (int k = 0; k < 32; k++) c[k] = labS[k * 32 + lane];
                unsigned run = NIL;
                #pragma unroll
                for (int k = 0; k < 32; k++) {
                    unsigned val = c[k];
                    if (val == NIL) { run = NIL; }
                    else { unsigned nv = min(run, val); changed |= (nv != val); c[k] = (unsigned short)nv; run = nv; }
                }
                run = NIL;
                #pragma unroll
                for (int k = 31; k >= 0; k--) {
                    unsigned val = c[k];
                    if (val == NIL) { run = NIL; }
                    else { unsigned nv = min(run, val); changed |= (nv != val); c[k] = (unsigned short)nv; run = nv; }
                }
                #pragma unroll
                for (int k = 0; k < 32; k++) labS[k * 32 + lane] = c[k];
            }
            if (!__any(changed)) break;
        }
    }
    __syncthreads();

    for (int i = tid; i < NPIX; i += 256) cntS[i] = 0;
    if (tid == 0) kprimeSh = 0;
    __syncthreads();
    for (int i = tid; i < NPIX; i += 256)
        if (bgS[i]) atomicAdd(&cntS[labS[i]], 1u);
    __syncthreads();
    for (int i = tid; i < NPIX; i += 256) {
        if (bgS[i] && (int)labS[i] == i) {
            unsigned id = (cntS[i] >= 2) ? (unsigned)atomicAdd(&kprimeSh, 1) : NIL;
            cntS[i] = id;
        }
    }
    __syncthreads();
    for (int i = tid; i < NPIX; i += 256)
        pixLab[i] = bgS[i] ? (unsigned short)cntS[labS[i]] : (unsigned short)NIL;
    __syncthreads();
    const int K = kprimeSh;

    unsigned long long* keys = big;
    for (int k = tid; k < SORTN; k += 256) {
        unsigned long long key = 0ULL;
        if (k < NEDGE) {
            int a, b; edge_ab(k, a, b);
            float cost = pT[a] + pT[b];
            int nfg = (int)(!bgS[a]) + (int)(!bgS[b]);
            if (sgn == 0) { if (nfg == 2) cost = 20.0f; }
            else          { if (nfg == 0) cost = 0.0f;  }
            key = ((unsigned long long)__float_as_uint(cost) << 16)
                | (unsigned long long)(0xFFFFu - (unsigned)k);
        }
        keys[k] = key;
    }
    __syncthreads();
    for (int kk = 2; kk <= SORTN; kk <<= 1) {
        for (int jj = kk >> 1; jj > 0; jj >>= 1) {
            for (int i = tid; i < SORTN; i += 256) {
                int ixj = i ^ jj;
                if (ixj > i) {
                    unsigned long long A = keys[i], Bv = keys[ixj];
                    bool descBlk = ((i & kk) == 0);
                    if ((A < Bv) == descBlk) { keys[i] = Bv; keys[ixj] = A; }
                }
            }
            __syncthreads();
        }
    }
    for (int k = tid; k < NEDGE; k += 256)
        orderS[k] = (unsigned short)(0xFFFFu - (unsigned)(keys[k] & 0xFFFFULL));
    for (int i = tid; i < NPIX; i += 256) {
        parentS[i] = (unsigned short)i;
        nodeS[i] = ((unsigned long long)i << 48) | ((unsigned long long)i << 32)
                 | (1ULL << 16) | (unsigned long long)bgS[i];
        nextS[i] = (unsigned short)NIL;
    }
    __syncthreads();

    if (tid < 64) {
        const int lane = tid;
        int m = 0;
        for (int kb = 0; kb < NEDGE; kb += 64) {
            int e = orderS[kb + lane];
            int a, b; edge_ab(e, a, b);
            unsigned ra = (unsigned)a, rb = (unsigned)b;
            while (true) {
                unsigned pa = parentS[ra];
                unsigned pb = parentS[rb];
                if (pa == ra && pb == rb) break;
                if (pa != ra) { unsigned ga = parentS[pa]; parentS[ra] = (unsigned short)ga; ra = ga; }
                if (pb != rb) { unsigned gb = parentS[pb]; parentS[rb] = (unsigned short)gb; rb = gb; }
            }
            unsigned specAB = (ra << 16) | rb;
            unsigned long long na = nodeS[ra];
            unsigned long long nb = nodeS[rb];
            unsigned long long candm = __ballot(ra != rb);

            unsigned logRa = 0xFFFFFFFFu, logRbO = 0xFFFFFFFFu, curRoot = 0xFFFFFFFFu;
            unsigned long long logNode = 0;
            int logCount = 0;
            while (candm != 0ULL) {
                int j = __ffsll((long long)candm) - 1;
                candm &= candm - 1ULL;
                unsigned sAB = rdl32(specAB, j);
                unsigned cra = sAB >> 16;
                unsigned crb = sAB & 0xFFFFu;
                unsigned long long hitA = __ballot(logRa == cra);
                unsigned long long hitB = __ballot(logRa == crb);
                if (hitA) cra = rdl32(curRoot, __ffsll((long long)hitA) - 1);
                if (hitB) crb = rdl32(curRoot, __ffsll((long long)hitB) - 1);
                if (cra == crb) continue;
                unsigned ce = rdl32((unsigned)e, j);
                unsigned long long hbA = __ballot(logRbO == cra);
                unsigned long long hbB = __ballot(logRbO == crb);
                unsigned long long cna = hbA ? rdl64(logNode, 63 - __clzll((long long)hbA)) : rdl64(na, j);
                unsigned long long cnb = hbB ? rdl64(logNode, 63 - __clzll((long long)hbB)) : rdl64(nb, j);
                unsigned headA = (unsigned)(cna >> 48);
                unsigned tailA = (unsigned)(cna >> 32) & 0xFFFFu;
                unsigned szA   = (unsigned)(cna >> 16) & 0xFFFFu;
                unsigned slA   = (unsigned)cna & 0xFFFFu;
                unsigned headB = (unsigned)(cnb >> 48);
                unsigned tailB = (unsigned)(cnb >> 32) & 0xFFFFu;
                unsigned szB   = (unsigned)(cnb >> 16) & 0xFFFFu;
                unsigned slB   = (unsigned)cnb & 0xFFFFu;
                unsigned long long merged =
                      ((unsigned long long)headA << 48)
                    | ((unsigned long long)tailB << 32)
                    | ((unsigned long long)(szA + szB) << 16)
                    | (unsigned long long)(slA + slB);
                if (curRoot == cra) curRoot = crb;
                if (lane == logCount) {
                    logRa = cra; logRbO = crb; curRoot = crb; logNode = merged;
                    parentS[cra] = (unsigned short)crb;
                    nodeS[crb]   = merged;
                    nextS[tailA] = (unsigned short)headB;
                    mRecA[m] = (headA << 16) | headB;
                    mRecB[m] = (szA << 16) | szB;
                    mSaSb[m] = slA * slB;
                    mEd[m]   = (unsigned short)ce;
                }
                logCount++;
                m++;
            }
        }
        if (lane == 0) mCountSh = m;
    }
    __syncthreads();
    const int M = mCountSh;
    for (int j = tid; j < M; j += 256) commonW[j] = 0;

    unsigned short* n0 = (unsigned short*)big;
    unsigned short* n1 = n0 + 1024;
    unsigned short* d0 = n0 + 2048;
    unsigned short* d1 = n0 + 3072;
    for (int i = tid; i < NPIX; i += 256) { n0[i] = nextS[i]; d0[i] = 1; }
    __syncthreads();
    for (int s = 0; s < 10; s++) {
        unsigned short* sn = (s & 1) ? n1 : n0;
        unsigned short* sd = (s & 1) ? d1 : d0;
        unsigned short* dn = (s & 1) ? n0 : n1;
        unsigned short* dd = (s & 1) ? d0 : d1;
        for (int i = tid; i < NPIX; i += 256) {
            unsigned nx = sn[i];
            unsigned dv = sd[i];
            if (nx != NIL) { dv += sd[nx]; nx = sn[nx]; }
            dn[i] = (unsigned short)nx;
            dd[i] = (unsigned short)dv;
        }
        __syncthreads();
    }
    for (int i = tid; i < NPIX; i += 256)
        posS[i] = (unsigned short)(NPIX - (int)d0[i]);
    __syncthreads();

    unsigned*       P32 = (unsigned*)big;
    uint4*          P4  = (uint4*)big;
    unsigned*       scr = P32 + 4100;
    uint4*          S4  = (uint4*)scr;
    unsigned short* P16 = (unsigned short*)big;
    for (int base = 0; base < K; base += CHUNK) {
        for (int idx = tid; idx < 4100; idx += 256) P32[idx] = 0;
        __syncthreads();
        for (int i = tid; i < NPIX; i += 256) {
            unsigned l = pixLab[i];
            if (l != NIL && l >= (unsigned)base && l < (unsigned)(base + CHUNK))
                P16[(posS[i] + 1) * 8 + (l - base)] = 1;
        }
        __syncthreads();
        {
            int r0 = tid * 4 + 1;
            uint4 acc = P4[r0];
            for (int rr = r0 + 1; rr <= r0 + 3; rr++) { acc = add4(acc, P4[rr]); P4[rr] = acc; }
            S4[tid] = acc;
            __syncthreads();
            if (tid < 64) {
                uint4 s0 = S4[tid * 4], s1 = S4[tid * 4 + 1], s2 = S4[tid * 4 + 2], s3 = S4[tid * 4 + 3];
                uint4 t1 = add4(s0, s1), t2 = add4(t1, s2), t3 = add4(t2, s3);
                uint4 run = t3;
                #pragma unroll
                for (int d = 1; d < 64; d <<= 1) {
                    uint4 o;
                    o.x = __shfl_up(run.x, d, 64);
                    o.y = __shfl_up(run.y, d, 64);
                    o.z = __shfl_up(run.z, d, 64);
                    o.w = __shfl_up(run.w, d, 64);
                    if (tid >= d) run = add4(run, o);
                }
                uint4 off = sub4(run, t3);
                S4[tid * 4]     = add4(s0, off);
                S4[tid * 4 + 1] = add4(t1, off);
                S4[tid * 4 + 2] = add4(t2, off);
                S4[tid * 4 + 3] = add4(t3, off);
            }
            __syncthreads();
            if (tid > 0) {
                uint4 off = S4[tid - 1];
                for (int rr = r0; rr <= r0 + 3; rr++) P4[rr] = add4(P4[rr], off);
            }
        }
        __syncthreads();
        for (int j = tid; j < M; j += 256) {
            unsigned recA = mRecA[j], recB = mRecB[j];
            unsigned aS = posS[recA >> 16];
            unsigned bS = posS[recA & 0xFFFFu];
            uint4 da = sub4(P4[aS + (recB >> 16)], P4[aS]);
            uint4 db = sub4(P4[bS + (recB & 0xFFFFu)], P4[bS]);
            unsigned acc;
            acc  = (da.x & 0xFFFFu) * (db.x & 0xFFFFu) + (da.x >> 16) * (db.x >> 16);
            acc += (da.y & 0xFFFFu) * (db.y & 0xFFFFu) + (da.y >> 16) * (db.y >> 16);
            acc += (da.z & 0xFFFFu) * (db.z & 0xFFFFu) + (da.z >> 16) * (db.z >> 16);
            acc += (da.w & 0xFFFFu) * (db.w & 0xFFFFu) + (da.w >> 16) * (db.w >> 16);
            commonW[j] += acc;
        }
        __syncthreads();
    }

    if (tid == 0) { wsumSh = 0; lossSh = 0.0f; }
    __syncthreads();
    unsigned wloc = 0;
    for (int j = tid; j < M; j += 256)
        wloc += (sgn == 0) ? (mSaSb[j] - commonW[j]) : commonW[j];
    if (wloc) atomicAdd(&wsumSh, wloc);
    __syncthreads();
    const unsigned wsum = wsumSh;
    if (wsum > 0) {
        const double inv = 1.0 / (double)wsum;
        float lloc = 0.0f;
        for (int j = tid; j < M; j += 256) {
            unsigned w = (sgn == 0) ? (mSaSb[j] - commonW[j]) : commonW[j];
            if (!w) continue;
            int e = mEd[j];
            int a, b; edge_ab(e, a, b);
            int nfg = (int)(!bgS[a]) + (int)(!bgS[b]);
            bool keep = (sgn == 0) ? (nfg == 0) : (nfg >= 1);
            if (!keep) continue;
            float wn = (float)((double)w * inv);
            float fa, fb;
            if (sgn == 0) { fa = pT[a] * pT[a];            fb = pT[b] * pT[b]; }
            else { float da = 20.0f - pT[a], db = 20.0f - pT[b]; fa = da * da; fb = db * db; }
            lloc += wn * (fa + fb);
        }
        if (lloc != 0.0f) atomicAdd(&lossSh, lloc);
        __syncthreads();
        if (tid == 0 && lossSh != 0.0f) atomicAdd(out, lossSh);
    }
}

extern "C" void kernel_launch(void* const* d_in, const int* in_sizes, int n_in,
                              void* d_out, int out_size, void* d_ws, size_t ws_size,
                              hipStream_t stream) {
    const float* y_true = (const float*)d_in[0];
    const float* y_pred = (const float*)d_in[1];
    float* out = (float*)d_out;
    const int B  = in_sizes[0] / (256 * 256);
    const int nT = B * 64;
    const int nW = nT * 2;

    const size_t offK   = (size_t)nT * 2048;
    const size_t offOrd = offK + (((size_t)nT * 4 + 255) & ~(size_t)255);
    const size_t offMrg = offOrd + (size_t)nW * 4096;
    const size_t need   = offMrg + (size_t)nW * MRG_STRIDE;

    hipMemsetAsync(d_out, 0, (size_t)out_size * sizeof(float), stream);

    if (ws_size >= need) {
        char* ws = (char*)d_ws;
        unsigned short* pixLab_g = (unsigned short*)ws;
        int*            Kg       = (int*)(ws + offK);
        unsigned short* ord_g    = (unsigned short*)(ws + offOrd);
        char*           mrg      = ws + offMrg;
        hipLaunchKernelGGL(k12_ccl_sort, dim3(nT + nW), dim3(256), 0, stream,
                           y_true, y_pred, pixLab_g, Kg, ord_g, nT);
        hipLaunchKernelGGL(k3_kruskal,   dim3(nW), dim3(64),  0, stream, y_true, ord_g, mrg);
        hipLaunchKernelGGL(k4_weights,   dim3(nW), dim3(256), 0, stream, y_true, y_pred,
                           pixLab_g, Kg, mrg, out);
    } else {
        hipLaunchKernelGGL(malis_mono, dim3(nW), dim3(256), 0, stream, y_true, y_pred, out);
    }
}

// Round 9
// 311.265 us; speedup vs baseline: 2.2955x; 1.5619x over previous
//
#include <hip/hip_runtime.h>

#define NPIX   1024   // 32*32
#define NEH    992    // horizontal edges 32*31
#define NEDGE  1984   // + vertical 31*32
#define SORTN  2048
#define CHUNK  8      // labels per phase-2 pass
#define NMERGE 1023
#define NIL    0xFFFFu

// per-(tile,sgn) merge-record block in ws (20480 B stride)
#define MRG_STRIDE 20480
#define MRG_M      0
#define MRG_RA     256
#define MRG_RB     4608
#define MRG_SS     8960
#define MRG_ED     13312
#define MRG_NXT    15616

__device__ __forceinline__ void edge_ab(int e, int& a, int& b) {
    if (e < NEH) { int y = e / 31; int x = e - y * 31; a = y * 32 + x; b = a + 1; }
    else         { int ev = e - NEH; a = ev; b = ev + 32; }
}

__device__ __forceinline__ uint4 add4(uint4 x, uint4 y) {
    return make_uint4(x.x + y.x, x.y + y.y, x.z + y.z, x.w + y.w);
}
__device__ __forceinline__ uint4 sub4(uint4 x, uint4 y) {
    return make_uint4(x.x - y.x, x.y - y.y, x.z - y.z, x.w - y.w);
}

// ============================ fused K1/K2 bodies ============================
__device__ void ccl_body(char* smem, int* kprimeSh,
                         const float* __restrict__ t_glob,
                         unsigned short* __restrict__ pixLab_g,
                         int* __restrict__ Kg, int tileId) {
    const int tid = threadIdx.x;
    const int bat = tileId >> 6;
    const int tile = tileId & 63;
    const int tr = tile >> 3, tc = tile & 7;

    unsigned short* labS = (unsigned short*)smem;                 // [0,2048)
    unsigned int*   cntS = (unsigned int*)(smem + 2048);          // [2048,6144)
    unsigned char*  bgS  = (unsigned char*)(smem + 20480);        // [20480,21504)

    for (int i = tid; i < NPIX; i += 256) {
        int y = i >> 5, x = i & 31;
        int gidx = bat * 65536 + (tr * 32 + y) * 256 + (tc * 32 + x);
        bgS[i] = (t_glob[gidx] == 0.0f) ? 1 : 0;
    }
    __syncthreads();

    if (tid < 64) {
        const int lane = tid;
        if (lane < 32) {
            #pragma unroll
            for (int x = 0; x < 32; x++) {
                int i = lane * 32 + x;
                labS[i] = bgS[i] ? (unsigned short)i : (unsigned short)NIL;
            }
        }
        while (true) {
            bool changed = false;
            if (lane < 32) {
                const int base = lane * 32;
                unsigned short v[32];
                #pragma unroll
                for (int x = 0; x < 32; x++) v[x] = labS[base + x];
                unsigned run = NIL;
                #pragma unroll
                for (int x = 0; x < 32; x++) {
                    unsigned val = v[x];
                    if (val == NIL) { run = NIL; }
                    else { unsigned nv = min(run, val); changed |= (nv != val); v[x] = (unsigned short)nv; run = nv; }
                }
                run = NIL;
                #pragma unroll
                for (int x = 31; x >= 0; x--) {
                    unsigned val = v[x];
                    if (val == NIL) { run = NIL; }
                    else { unsigned nv = min(run, val); changed |= (nv != val); v[x] = (unsigned short)nv; run = nv; }
                }
                #pragma unroll
                for (int x = 0; x < 32; x++) labS[base + x] = v[x];
            }
            if (lane < 32) {
                unsigned short c[32];
                #pragma unroll
                for (int k = 0; k < 32; k++) c[k] = labS[k * 32 + lane];
                unsigned run = NIL;
                #pragma unroll
                for (int k = 0; k < 32; k++) {
                    unsigned val = c[k];
                    if (val == NIL) { run = NIL; }
                    else { unsigned nv = min(run, val); changed |= (nv != val); c[k] = (unsigned short)nv; run = nv; }
                }
                run = NIL;
                #pragma unroll
                for (int k = 31; k >= 0; k--) {
                    unsigned val = c[k];
                    if (val == NIL) { run = NIL; }
                    else { unsigned nv = min(run, val); changed |= (nv != val); c[k] = (unsigned short)nv; run = nv; }
                }
                #pragma unroll
                for (int k = 0; k < 32; k++) labS[k * 32 + lane] = c[k];
            }
            if (!__any(changed)) break;
        }
    }
    __syncthreads();

    for (int i = tid; i < NPIX; i += 256) cntS[i] = 0;
    if (tid == 0) *kprimeSh = 0;
    __syncthreads();
    for (int i = tid; i < NPIX; i += 256)
        if (bgS[i]) atomicAdd(&cntS[labS[i]], 1u);
    __syncthreads();
    for (int i = tid; i < NPIX; i += 256) {
        if (bgS[i] && (int)labS[i] == i) {
            unsigned id = (cntS[i] >= 2) ? (unsigned)atomicAdd(kprimeSh, 1) : NIL;
            cntS[i] = id;
        }
    }
    __syncthreads();
    for (int i = tid; i < NPIX; i += 256)
        pixLab_g[tileId * NPIX + i] = bgS[i] ? (unsigned short)cntS[labS[i]] : (unsigned short)NIL;
    if (tid == 0) Kg[tileId] = *kprimeSh;
}

__device__ void sort_body(char* smem,
                          const float* __restrict__ t_glob,
                          const float* __restrict__ p_glob,
                          unsigned short* __restrict__ ord_g, int wg) {
    const int tid = threadIdx.x;
    const int sgn = wg & 1;
    const int tileId = wg >> 1;
    const int bat = tileId >> 6;
    const int tile = tileId & 63;
    const int tr = tile >> 3, tc = tile & 7;

    float*              pT   = (float*)smem;                      // [0,4096)
    unsigned long long* keys = (unsigned long long*)(smem + 4096);// [4096,20480)
    unsigned char*      bgS  = (unsigned char*)(smem + 20480);    // [20480,21504)

    for (int i = tid; i < NPIX; i += 256) {
        int y = i >> 5, x = i & 31;
        int gidx = bat * 65536 + (tr * 32 + y) * 256 + (tc * 32 + x);
        pT[i] = p_glob[gidx];
        bgS[i] = (t_glob[gidx] == 0.0f) ? 1 : 0;
    }
    __syncthreads();

    for (int k = tid; k < SORTN; k += 256) {
        unsigned long long key = 0ULL;
        if (k < NEDGE) {
            int a, b; edge_ab(k, a, b);
            float cost = pT[a] + pT[b];
            int nfg = (int)(!bgS[a]) + (int)(!bgS[b]);
            if (sgn == 0) { if (nfg == 2) cost = 20.0f; }
            else          { if (nfg == 0) cost = 0.0f;  }
            key = ((unsigned long long)__float_as_uint(cost) << 16)
                | (unsigned long long)(0xFFFFu - (unsigned)k);
        }
        keys[k] = key;
    }
    __syncthreads();
    for (int kk = 2; kk <= SORTN; kk <<= 1) {
        for (int jj = kk >> 1; jj > 0; jj >>= 1) {
            for (int i = tid; i < SORTN; i += 256) {
                int ixj = i ^ jj;
                if (ixj > i) {
                    unsigned long long A = keys[i], Bv = keys[ixj];
                    bool descBlk = ((i & kk) == 0);
                    if ((A < Bv) == descBlk) { keys[i] = Bv; keys[ixj] = A; }
                }
            }
            __syncthreads();
        }
    }
    for (int k = tid; k < NEDGE; k += 256)
        ord_g[(size_t)wg * SORTN + k] = (unsigned short)(0xFFFFu - (unsigned)(keys[k] & 0xFFFFULL));
}

__global__ __launch_bounds__(256, 2)
void k12_ccl_sort(const float* __restrict__ t_glob,
                  const float* __restrict__ p_glob,
                  unsigned short* __restrict__ pixLab_g,
                  int* __restrict__ Kg,
                  unsigned short* __restrict__ ord_g,
                  int nT) {
    __shared__ __align__(16) char smem[21504];
    __shared__ int kprimeSh;
    if ((int)blockIdx.x < nT)
        ccl_body(smem, &kprimeSh, t_glob, pixLab_g, Kg, blockIdx.x);
    else
        sort_body(smem, t_glob, p_glob, ord_g, blockIdx.x - nT);
}

// ============================ K3: Kruskal via priority-claim parallel rounds ============================
// Within a 64-edge batch (lane = its own edge, priority = lane index = serial edge
// order): each round, pending lanes re-find roots, atomicMin-claim both roots, and
// the winners of BOTH claims commit IN PARALLEL (winners own disjoint roots, so all
// LDS updates are race-free). A pending earlier edge that could affect lane i must
// directly touch one of i's current roots, so i never commits early -> exact serial
// semantics. Records rank into exact serial slots via ballot+popcount after batch.
__global__ __launch_bounds__(64)
void k3_kruskal(const float* __restrict__ t_glob,
                const unsigned short* __restrict__ ord_g,
                char* __restrict__ mrg_base) {
    const int lane = threadIdx.x;
    const int wg  = blockIdx.x;
    const int tileId = wg >> 1;
    const int bat = tileId >> 6;
    const int tile = tileId & 63;
    const int tr = tile >> 3, tc = tile & 7;

    __shared__ unsigned short parentS[NPIX];
    __shared__ unsigned long long nodeS[NPIX];
    __shared__ unsigned short nextS[NPIX];
    __shared__ unsigned int   claimS[NPIX];

    char* mg = mrg_base + (size_t)wg * MRG_STRIDE;
    unsigned int*   mrA = (unsigned int*)(mg + MRG_RA);
    unsigned int*   mrB = (unsigned int*)(mg + MRG_RB);
    unsigned int*   mSS = (unsigned int*)(mg + MRG_SS);
    unsigned short* mED = (unsigned short*)(mg + MRG_ED);
    unsigned short* mNX = (unsigned short*)(mg + MRG_NXT);
    const unsigned short* ord = ord_g + (size_t)wg * SORTN;

    for (int i = lane; i < NPIX; i += 64) {
        int y = i >> 5, x = i & 31;
        int gidx = bat * 65536 + (tr * 32 + y) * 256 + (tc * 32 + x);
        unsigned bg = (t_glob[gidx] == 0.0f) ? 1u : 0u;
        parentS[i] = (unsigned short)i;
        nodeS[i] = ((unsigned long long)i << 48) | ((unsigned long long)i << 32)
                 | (1ULL << 16) | (unsigned long long)bg;
        nextS[i] = (unsigned short)NIL;
    }
    __syncthreads();

    int m = 0;
    for (int kb = 0; kb < NEDGE; kb += 64) {      // 31 exact batches
        int e = ord[kb + lane];
        int a, b; edge_ab(e, a, b);
        unsigned ra = (unsigned)a, rb = (unsigned)b;
        bool pending = true;
        bool committed = false;
        unsigned recA = 0, recB = 0, recSS = 0;

        while (__any(pending)) {
            // re-find current roots (concurrent path-halving, safe)
            if (pending) {
                while (true) {
                    unsigned pa = parentS[ra];
                    unsigned pb = parentS[rb];
                    if (pa == ra && pb == rb) break;
                    if (pa != ra) { unsigned ga = parentS[pa]; parentS[ra] = (unsigned short)ga; ra = ga; }
                    if (pb != rb) { unsigned gb = parentS[pb]; parentS[rb] = (unsigned short)gb; rb = gb; }
                }
                if (ra == rb) pending = false;       // cycle: drop
            }
            // claim both roots with edge-order priority (same-wave DS ops are in-order:
            // clears complete before atomics, atomics before reads)
            if (pending) {
                claimS[ra] = 0xFFFFFFFFu;
                claimS[rb] = 0xFFFFFFFFu;
            }
            if (pending) {
                atomicMin(&claimS[ra], (unsigned)lane);
                atomicMin(&claimS[rb], (unsigned)lane);
            }
            bool win = pending && (claimS[ra] == (unsigned)lane) && (claimS[rb] == (unsigned)lane);
            if (win) {
                unsigned long long nA = nodeS[ra], nB = nodeS[rb];
                unsigned cons = ra, surv = rb;
                unsigned szAu = (unsigned)(nA >> 16) & 0xFFFFu;
                unsigned szBu = (unsigned)(nB >> 16) & 0xFFFFu;
                if (szAu > szBu) {                    // union by size (direction is
                    unsigned t = cons; cons = surv; surv = t;   //  weight-irrelevant)
                    unsigned long long tn = nA; nA = nB; nB = tn;
                }
                unsigned headA = (unsigned)(nA >> 48);
                unsigned tailA = (unsigned)(nA >> 32) & 0xFFFFu;
                unsigned szA   = (unsigned)(nA >> 16) & 0xFFFFu;
                unsigned slA   = (unsigned)nA & 0xFFFFu;
                unsigned headB = (unsigned)(nB >> 48);
                unsigned tailB = (unsigned)(nB >> 32) & 0xFFFFu;
                unsigned szB   = (unsigned)(nB >> 16) & 0xFFFFu;
                unsigned slB   = (unsigned)nB & 0xFFFFu;
                unsigned long long merged =
                      ((unsigned long long)headA << 48)
                    | ((unsigned long long)tailB << 32)
                    | ((unsigned long long)(szA + szB) << 16)
                    | (unsigned long long)(slA + slB);
                parentS[cons] = (unsigned short)surv; // disjoint roots across winners:
                nodeS[surv]   = merged;               //  all parallel writes race-free
                nextS[tailA]  = (unsigned short)headB;
                recA = (headA << 16) | headB;
                recB = (szA << 16) | szB;
                recSS = slA * slB;
                committed = true;
                pending = false;
            }
        }
        unsigned long long cm = __ballot(committed);
        if (committed) {                              // exact serial record index
            int idx = m + (int)__popcll(cm & ((1ULL << lane) - 1ULL));
            mrA[idx] = recA;
            mrB[idx] = recB;
            mSS[idx] = recSS;
            mED[idx] = (unsigned short)e;
        }
        m += (int)__popcll(cm);
    }
    if (lane == 0) *(int*)(mg + MRG_M) = m;
    for (int i = lane; i < NPIX; i += 64) mNX[i] = nextS[i];
}

// ============================ K4: list-rank + chunked prefix dots + loss ============================
__global__ __launch_bounds__(256, 2)
void k4_weights(const float* __restrict__ t_glob,
                const float* __restrict__ p_glob,
                const unsigned short* __restrict__ pixLab_g,
                const int* __restrict__ Kg,
                const char* __restrict__ mrg_base,
                float* __restrict__ out) {
    const int tid = threadIdx.x;
    const int wg  = blockIdx.x;
    const int sgn = wg & 1;
    const int tileId = wg >> 1;
    const int bat = tileId >> 6;
    const int tile = tileId & 63;
    const int tr = tile >> 3, tc = tile & 7;

    __shared__ float          pT[NPIX];
    __shared__ unsigned char  bgS[NPIX];
    __shared__ unsigned short pixLab[NPIX];
    __shared__ unsigned short posS[NPIX];
    __shared__ unsigned int   mRecA[NMERGE];
    __shared__ unsigned int   mRecB[NMERGE];
    __shared__ unsigned int   mSaSb[NMERGE];
    __shared__ unsigned int   commonW[NMERGE];
    __shared__ unsigned short mEd[NMERGE];
    __shared__ __align__(16) unsigned long long big[2564];
    __shared__ unsigned wsumSh;
    __shared__ float lossSh;

    const char* mg = mrg_base + (size_t)wg * MRG_STRIDE;
    const int M = *(const int*)(mg + MRG_M);
    const int K = Kg[tileId];
    const unsigned int*   mrA = (const unsigned int*)(mg + MRG_RA);
    const unsigned int*   mrB = (const unsigned int*)(mg + MRG_RB);
    const unsigned int*   mSS = (const unsigned int*)(mg + MRG_SS);
    const unsigned short* mED = (const unsigned short*)(mg + MRG_ED);
    const unsigned short* mNX = (const unsigned short*)(mg + MRG_NXT);

    for (int i = tid; i < NPIX; i += 256) {
        int y = i >> 5, x = i & 31;
        int gidx = bat * 65536 + (tr * 32 + y) * 256 + (tc * 32 + x);
        pT[i] = p_glob[gidx];
        bgS[i] = (t_glob[gidx] == 0.0f) ? 1 : 0;
        pixLab[i] = pixLab_g[tileId * NPIX + i];
    }
    for (int j = tid; j < M; j += 256) {
        mRecA[j] = mrA[j];
        mRecB[j] = mrB[j];
        mSaSb[j] = mSS[j];
        mEd[j]   = mED[j];
        commonW[j] = 0;
    }

    // ---- Wyllie list ranking -> posS ----
    unsigned short* n0 = (unsigned short*)big;
    unsigned short* n1 = n0 + 1024;
    unsigned short* d0 = n0 + 2048;
    unsigned short* d1 = n0 + 3072;
    for (int i = tid; i < NPIX; i += 256) { n0[i] = mNX[i]; d0[i] = 1; }
    __syncthreads();
    for (int s = 0; s < 10; s++) {
        unsigned short* sn = (s & 1) ? n1 : n0;
        unsigned short* sd = (s & 1) ? d1 : d0;
        unsigned short* dn = (s & 1) ? n0 : n1;
        unsigned short* dd = (s & 1) ? d0 : d1;
        for (int i = tid; i < NPIX; i += 256) {
            unsigned nx = sn[i];
            unsigned dv = sd[i];
            if (nx != NIL) { dv += sd[nx]; nx = sn[nx]; }
            dn[i] = (unsigned short)nx;
            dd[i] = (unsigned short)dv;
        }
        __syncthreads();
    }
    for (int i = tid; i < NPIX; i += 256)
        posS[i] = (unsigned short)(NPIX - (int)d0[i]);
    __syncthreads();

    // ---- chunked label prefix sums + per-merge dots ----
    unsigned*       P32 = (unsigned*)big;
    uint4*          P4  = (uint4*)big;
    unsigned*       scr = P32 + 4100;
    uint4*          S4  = (uint4*)scr;
    unsigned short* P16 = (unsigned short*)big;
    for (int base = 0; base < K; base += CHUNK) {
        for (int idx = tid; idx < 4100; idx += 256) P32[idx] = 0;
        __syncthreads();
        for (int i = tid; i < NPIX; i += 256) {
            unsigned l = pixLab[i];
            if (l != NIL && l >= (unsigned)base && l < (unsigned)(base + CHUNK))
                P16[(posS[i] + 1) * 8 + (l - base)] = 1;
        }
        __syncthreads();
        {
            int r0 = tid * 4 + 1;
            uint4 acc = P4[r0];
            for (int rr = r0 + 1; rr <= r0 + 3; rr++) { acc = add4(acc, P4[rr]); P4[rr] = acc; }
            S4[tid] = acc;
            __syncthreads();
            if (tid < 64) {
                uint4 s0 = S4[tid * 4], s1 = S4[tid * 4 + 1], s2 = S4[tid * 4 + 2], s3 = S4[tid * 4 + 3];
                uint4 t1 = add4(s0, s1), t2 = add4(t1, s2), t3 = add4(t2, s3);
                uint4 run = t3;
                #pragma unroll
                for (int d = 1; d < 64; d <<= 1) {
                    uint4 o;
                    o.x = __shfl_up(run.x, d, 64);
                    o.y = __shfl_up(run.y, d, 64);
                    o.z = __shfl_up(run.z, d, 64);
                    o.w = __shfl_up(run.w, d, 64);
                    if (tid >= d) run = add4(run, o);
                }
                uint4 off = sub4(run, t3);
                S4[tid * 4]     = add4(s0, off);
                S4[tid * 4 + 1] = add4(t1, off);
                S4[tid * 4 + 2] = add4(t2, off);
                S4[tid * 4 + 3] = add4(t3, off);
            }
            __syncthreads();
            if (tid > 0) {
                uint4 off = S4[tid - 1];
                for (int rr = r0; rr <= r0 + 3; rr++) P4[rr] = add4(P4[rr], off);
            }
        }
        __syncthreads();
        for (int j = tid; j < M; j += 256) {
            unsigned recA = mRecA[j], recB = mRecB[j];
            unsigned aS = posS[recA >> 16];
            unsigned bS = posS[recA & 0xFFFFu];
            uint4 da = sub4(P4[aS + (recB >> 16)], P4[aS]);
            uint4 db = sub4(P4[bS + (recB & 0xFFFFu)], P4[bS]);
            unsigned acc;
            acc  = (da.x & 0xFFFFu) * (db.x & 0xFFFFu) + (da.x >> 16) * (db.x >> 16);
            acc += (da.y & 0xFFFFu) * (db.y & 0xFFFFu) + (da.y >> 16) * (db.y >> 16);
            acc += (da.z & 0xFFFFu) * (db.z & 0xFFFFu) + (da.z >> 16) * (db.z >> 16);
            acc += (da.w & 0xFFFFu) * (db.w & 0xFFFFu) + (da.w >> 16) * (db.w >> 16);
            commonW[j] += acc;
        }
        __syncthreads();
    }

    // ---- normalize + mask + loss ----
    if (tid == 0) { wsumSh = 0; lossSh = 0.0f; }
    __syncthreads();
    unsigned wloc = 0;
    for (int j = tid; j < M; j += 256)
        wloc += (sgn == 0) ? (mSaSb[j] - commonW[j]) : commonW[j];
    if (wloc) atomicAdd(&wsumSh, wloc);
    __syncthreads();
    const unsigned wsum = wsumSh;
    if (wsum > 0) {
        const double inv = 1.0 / (double)wsum;
        float lloc = 0.0f;
        for (int j = tid; j < M; j += 256) {
            unsigned w = (sgn == 0) ? (mSaSb[j] - commonW[j]) : commonW[j];
            if (!w) continue;
            int e = mEd[j];
            int a, b; edge_ab(e, a, b);
            int nfg = (int)(!bgS[a]) + (int)(!bgS[b]);
            bool keep = (sgn == 0) ? (nfg == 0) : (nfg >= 1);
            if (!keep) continue;
            float wn = (float)((double)w * inv);
            float fa, fb;
            if (sgn == 0) { fa = pT[a] * pT[a];            fb = pT[b] * pT[b]; }
            else { float da = 20.0f - pT[a], db = 20.0f - pT[b]; fa = da * da; fb = db * db; }
            lloc += wn * (fa + fb);
        }
        if (lloc != 0.0f) atomicAdd(&lossSh, lloc);
        __syncthreads();
        if (tid == 0 && lossSh != 0.0f) atomicAdd(out, lossSh);
    }
}

// ============================ fallback: monolith (used if ws too small) ============================
__global__ __launch_bounds__(256, 2)
void malis_mono(const float* __restrict__ t_glob,
                const float* __restrict__ p_glob,
                float* __restrict__ out) {
    const int tid  = threadIdx.x;
    const int wg   = blockIdx.x;
    const int sgn  = wg & 1;
    const int tileId = wg >> 1;
    const int bat  = tileId >> 6;
    const int tile = tileId & 63;
    const int tr = tile >> 3, tc = tile & 7;

    __shared__ float          pT[NPIX];
    __shared__ unsigned char  bgS[NPIX];
    __shared__ unsigned short pixLab[NPIX];
    __shared__ unsigned short parentS[NPIX];
    __shared__ unsigned short nextS[NPIX];
    __shared__ unsigned long long nodeS[NPIX];
    __shared__ unsigned int   claimS[NPIX];
    __shared__ unsigned short posS[NPIX];
    __shared__ unsigned short orderS[NEDGE];
    __shared__ unsigned int   mRecA[NMERGE];
    __shared__ unsigned int   mRecB[NMERGE];
    __shared__ unsigned short mEd[NMERGE];
    __shared__ unsigned int   mSaSb[NMERGE];
    __shared__ unsigned int   commonW[NMERGE];
    __shared__ __align__(16) unsigned long long big[2564];
    __shared__ int   kprimeSh, mCountSh;
    __shared__ unsigned wsumSh;
    __shared__ float lossSh;

    for (int i = tid; i < NPIX; i += 256) {
        int y = i >> 5, x = i & 31;
        int gidx = bat * 65536 + (tr * 32 + y) * 256 + (tc * 32 + x);
        pT[i] = p_glob[gidx];
        bgS[i] = (t_glob[gidx] == 0.0f) ? 1 : 0;
    }
    __syncthreads();

    unsigned short* labS = (unsigned short*)big;
    unsigned int*   cntS = (unsigned int*)(((char*)big) + 2048);
    if (tid < 64) {
        const int lane = tid;
        if (lane < 32) {
            #pragma unroll
            for (int x = 0; x < 32; x++) {
                int i = lane * 32 + x;
                labS[i] = bgS[i] ? (unsigned short)i : (unsigned short)NIL;
            }
        }
        while (true) {
            bool changed = false;
            if (lane < 32) {
                const int base = lane * 32;
                unsigned short v[32];
                #pragma unroll
                for (int x = 0; x < 32; x++) v[x] = labS[base + x];
                unsigned run = NIL;
                #pragma unroll
                for (int x = 0; x < 32; x++) {
                    unsigned val = v[x];
                    if (val == NIL) { run = NIL; }
                    else { unsigned nv = min(run, val); changed |= (nv != val); v[x] = (unsigned short)nv; run = nv; }
                }
                run = NIL;
                #pragma unroll
                for (int x = 31; x >= 0; x--) {
                    unsigned val = v[x];
                    if (val == NIL) { run = NIL; }
                    else { unsigned nv = min(run, val); changed |= (nv != val); v[x] = (unsigned short)nv; run = nv; }
                }
                #pragma unroll
                for (int x = 0; x < 32; x++) labS[base + x] = v[x];
            }
            if (lane < 32) {
                unsigned short c[32];
                #pragma unroll
                for (int k = 0; k < 32; k++) c[k] = labS[k * 32 + lane];
                unsigned run = NIL;
                #pragma unroll
                for (int k = 0; k < 32; k++) {
                    unsigned val = c[k];
                    if (val == NIL) { run = NIL; }
                    else { unsigned nv = min(run, val); changed |= (nv != val); c[k] = (unsigned short)nv; run = nv; }
                }
                run = NIL;
                #pragma unroll
                for (int k = 31; k >= 0; k--) {
                    unsigned val = c[k];
                    if (val == NIL) { run = NIL; }
                    else { unsigned nv = min(run, val); changed |= (nv != val); c[k] = (unsigned short)nv; run = nv; }
                }
                #pragma unroll
                for (int k = 0; k < 32; k++) labS[k * 32 + lane] = c[k];
            }
            if (!__any(changed)) break;
        }
    }
    __syncthreads();

    for (int i = tid; i < NPIX; i += 256) cntS[i] = 0;
    if (tid == 0) kprimeSh = 0;
    __syncthreads();
    for (int i = tid; i < NPIX; i += 256)
        if (bgS[i]) atomicAdd(&cntS[labS[i]], 1u);
    __syncthreads();
    for (int i = tid; i < NPIX; i += 256) {
        if (bgS[i] && (int)labS[i] == i) {
            unsigned id = (cntS[i] >= 2) ? (unsigned)atomicAdd(&kprimeSh, 1) : NIL;
            cntS[i] = id;
        }
    }
    __syncthreads();
    for (int i = tid; i < NPIX; i += 256)
        pixLab[i] = bgS[i] ? (unsigned short)cntS[labS[i]] : (unsigned short)NIL;
    __syncthreads();
    const int K = kprimeSh;

    unsigned long long* keys = big;
    for (int k = tid; k < SORTN; k += 256) {
        unsigned long long key = 0ULL;
        if (k < NEDGE) {
            int a, b; edge_ab(k, a, b);
            float cost = pT[a] + pT[b];
            int nfg = (int)(!bgS[a]) + (int)(!bgS[b]);
            if (sgn == 0) { if (nfg == 2) cost = 20.0f; }
            else          { if (nfg == 0) cost = 0.0f;  }
            key = ((unsigned long long)__float_as_uint(cost) << 16)
                | (unsigned long long)(0xFFFFu - (unsigned)k);
        }
        keys[k] = key;
    }
    __syncthreads();
    for (int kk = 2; kk <= SORTN; kk <<= 1) {
        for (int jj = kk >> 1; jj > 0; jj >>= 1) {
            for (int i = tid; i < SORTN; i += 256) {
                int ixj = i ^ jj;
                if (ixj > i) {
                    unsigned long long A = keys[i], Bv = keys[ixj];
                    bool descBlk = ((i & kk) == 0);
                    if ((A < Bv) == descBlk) { keys[i] = Bv; keys[ixj] = A; }
                }
            }
            __syncthreads();
        }
    }
    for (int k = tid; k < NEDGE; k += 256)
        orderS[k] = (unsigned short)(0xFFFFu - (unsigned)(keys[k] & 0xFFFFULL));
    for (int i = tid; i < NPIX; i += 256) {
        parentS[i] = (unsigned short)i;
        nodeS[i] = ((unsigned long long)i << 48) | ((unsigned long long)i << 32)
                 | (1ULL << 16) | (unsigned long long)bgS[i];
        nextS[i] = (unsigned short)NIL;
    }
    __syncthreads();

    if (tid < 64) {
        const int lane = tid;
        int m = 0;
        for (int kb = 0; kb < NEDGE; kb += 64) {
            int e = orderS[kb + lane];
            int a, b; edge_ab(e, a, b);
            unsigned ra = (unsigned)a, rb = (unsigned)b;
            bool pending = true;
            bool committed = false;
            unsigned recA = 0, recB = 0, recSS = 0;
            while (__any(pending)) {
                if (pending) {
                    while (true) {
                        unsigned pa = parentS[ra];
                        unsigned pb = parentS[rb];
                        if (pa == ra && pb == rb) break;
                        if (pa != ra) { unsigned ga = parentS[pa]; parentS[ra] = (unsigned short)ga; ra = ga; }
                        if (pb != rb) { unsigned gb = parentS[pb]; parentS[rb] = (unsigned short)gb; rb = gb; }
                    }
                    if (ra == rb) pending = false;
                }
                if (pending) {
                    claimS[ra] = 0xFFFFFFFFu;
                    claimS[rb] = 0xFFFFFFFFu;
                }
                if (pending) {
                    atomicMin(&claimS[ra], (unsigned)lane);
                    atomicMin(&claimS[rb], (unsigned)lane);
                }
                bool win = pending && (claimS[ra] == (unsigned)lane) && (claimS[rb] == (unsigned)lane);
                if (win) {
                    unsigned long long nA = nodeS[ra], nB = nodeS[rb];
                    unsigned cons = ra, surv = rb;
                    unsigned szAu = (unsigned)(nA >> 16) & 0xFFFFu;
                    unsigned szBu = (unsigned)(nB >> 16) & 0xFFFFu;
                    if (szAu > szBu) {
                        unsigned t = cons; cons = surv; surv = t;
                        unsigned long long tn = nA; nA = nB; nB = tn;
                    }
                    unsigned headA = (unsigned)(nA >> 48);
                    unsigned tailA = (unsigned)(nA >> 32) & 0xFFFFu;
                    unsigned szA   = (unsigned)(nA >> 16) & 0xFFFFu;
                    unsigned slA   = (unsigned)nA & 0xFFFFu;
                    unsigned headB = (unsigned)(nB >> 48);
                    unsigned tailB = (unsigned)(nB >> 32) & 0xFFFFu;
                    unsigned szB   = (unsigned)(nB >> 16) & 0xFFFFu;
                    unsigned slB   = (unsigned)nB & 0xFFFFu;
                    unsigned long long merged =
                          ((unsigned long long)headA << 48)
                        | ((unsigned long long)tailB << 32)
                        | ((unsigned long long)(szA + szB) << 16)
                        | (unsigned long long)(slA + slB);
                    parentS[cons] = (unsigned short)surv;
                    nodeS[surv]   = merged;
                    nextS[tailA]  = (unsigned short)headB;
                    recA = (headA << 16) | headB;
                    recB = (szA << 16) | szB;
                    recSS = slA * slB;
                    committed = true;
                    pending = false;
                }
            }
            unsigned long long cm = __ballot(committed);
            if (committed) {
                int idx = m + (int)__popcll(cm & ((1ULL << lane) - 1ULL));
                mRecA[idx] = recA;
                mRecB[idx] = recB;
                mSaSb[idx] = recSS;
                mEd[idx]   = (unsigned short)e;
            }
            m += (int)__popcll(cm);
        }
        if (lane == 0) mCountSh = m;
    }
    __syncthreads();
    const int M = mCountSh;
    for (int j = tid; j < M; j += 256) commonW[j] = 0;

    unsigned short* n0 = (unsigned short*)big;
    unsigned short* n1 = n0 + 1024;
    unsigned short* d0 = n0 + 2048;
    unsigned short* d1 = n0 + 3072;
    for (int i = tid; i < NPIX; i += 256) { n0[i] = nextS[i]; d0[i] = 1; }
    __syncthreads();
    for (int s = 0; s < 10; s++) {
        unsigned short* sn = (s & 1) ? n1 : n0;
        unsigned short* sd = (s & 1) ? d1 : d0;
        unsigned short* dn = (s & 1) ? n0 : n1;
        unsigned short* dd = (s & 1) ? d0 : d1;
        for (int i = tid; i < NPIX; i += 256) {
            unsigned nx = sn[i];
            unsigned dv = sd[i];
            if (nx != NIL) { dv += sd[nx]; nx = sn[nx]; }
            dn[i] = (unsigned short)nx;
            dd[i] = (unsigned short)dv;
        }
        __syncthreads();
    }
    for (int i = tid; i < NPIX; i += 256)
        posS[i] = (unsigned short)(NPIX - (int)d0[i]);
    __syncthreads();

    unsigned*       P32 = (unsigned*)big;
    uint4*          P4  = (uint4*)big;
    unsigned*       scr = P32 + 4100;
    uint4*          S4  = (uint4*)scr;
    unsigned short* P16 = (unsigned short*)big;
    for (int base = 0; base < K; base += CHUNK) {
        for (int idx = tid; idx < 4100; idx += 256) P32[idx] = 0;
        __syncthreads();
        for (int i = tid; i < NPIX; i += 256) {
            unsigned l = pixLab[i];
            if (l != NIL && l >= (unsigned)base && l < (unsigned)(base + CHUNK))
                P16[(posS[i] + 1) * 8 + (l - base)] = 1;
        }
        __syncthreads();
        {
            int r0 = tid * 4 + 1;
            uint4 acc = P4[r0];
            for (int rr = r0 + 1; rr <= r0 + 3; rr++) { acc = add4(acc, P4[rr]); P4[rr] = acc; }
            S4[tid] = acc;
            __syncthreads();
            if (tid < 64) {
                uint4 s0 = S4[tid * 4], s1 = S4[tid * 4 + 1], s2 = S4[tid * 4 + 2], s3 = S4[tid * 4 + 3];
                uint4 t1 = add4(s0, s1), t2 = add4(t1, s2), t3 = add4(t2, s3);
                uint4 run = t3;
                #pragma unroll
                for (int d = 1; d < 64; d <<= 1) {
                    uint4 o;
                    o.x = __shfl_up(run.x, d, 64);
                    o.y = __shfl_up(run.y, d, 64);
                    o.z = __shfl_up(run.z, d, 64);
                    o.w = __shfl_up(run.w, d, 64);
                    if (tid >= d) run = add4(run, o);
                }
                uint4 off = sub4(run, t3);
                S4[tid * 4]     = add4(s0, off);
                S4[tid * 4 + 1] = add4(t1, off);
                S4[tid * 4 + 2] = add4(t2, off);
                S4[tid * 4 + 3] = add4(t3, off);
            }
            __syncthreads();
            if (tid > 0) {
                uint4 off = S4[tid - 1];
                for (int rr = r0; rr <= r0 + 3; rr++) P4[rr] = add4(P4[rr], off);
            }
        }
        __syncthreads();
        for (int j = tid; j < M; j += 256) {
            unsigned recA = mRecA[j], recB = mRecB[j];
            unsigned aS = posS[recA >> 16];
            unsigned bS = posS[recA & 0xFFFFu];
            uint4 da = sub4(P4[aS + (recB >> 16)], P4[aS]);
            uint4 db = sub4(P4[bS + (recB & 0xFFFFu)], P4[bS]);
            unsigned acc;
            acc  = (da.x & 0xFFFFu) * (db.x & 0xFFFFu) + (da.x >> 16) * (db.x >> 16);
            acc += (da.y & 0xFFFFu) * (db.y & 0xFFFFu) + (da.y >> 16) * (db.y >> 16);
            acc += (da.z & 0xFFFFu) * (db.z & 0xFFFFu) + (da.z >> 16) * (db.z >> 16);
            acc += (da.w & 0xFFFFu) * (db.w & 0xFFFFu) + (da.w >> 16) * (db.w >> 16);
            commonW[j] += acc;
        }
        __syncthreads();
    }

    if (tid == 0) { wsumSh = 0; lossSh = 0.0f; }
    __syncthreads();
    unsigned wloc = 0;
    for (int j = tid; j < M; j += 256)
        wloc += (sgn == 0) ? (mSaSb[j] - commonW[j]) : commonW[j];
    if (wloc) atomicAdd(&wsumSh, wloc);
    __syncthreads();
    const unsigned wsum = wsumSh;
    if (wsum > 0) {
        const double inv = 1.0 / (double)wsum;
        float lloc = 0.0f;
        for (int j = tid; j < M; j += 256) {
            unsigned w = (sgn == 0) ? (mSaSb[j] - commonW[j]) : commonW[j];
            if (!w) continue;
            int e = mEd[j];
            int a, b; edge_ab(e, a, b);
            int nfg = (int)(!bgS[a]) + (int)(!bgS[b]);
            bool keep = (sgn == 0) ? (nfg == 0) : (nfg >= 1);
            if (!keep) continue;
            float wn = (float)((double)w * inv);
            float fa, fb;
            if (sgn == 0) { fa = pT[a] * pT[a];            fb = pT[b] * pT[b]; }
            else { float da = 20.0f - pT[a], db = 20.0f - pT[b]; fa = da * da; fb = db * db; }
            lloc += wn * (fa + fb);
        }
        if (lloc != 0.0f) atomicAdd(&lossSh, lloc);
        __syncthreads();
        if (tid == 0 && lossSh != 0.0f) atomicAdd(out, lossSh);
    }
}

extern "C" void kernel_launch(void* const* d_in, const int* in_sizes, int n_in,
                              void* d_out, int out_size, void* d_ws, size_t ws_size,
                              hipStream_t stream) {
    const float* y_true = (const float*)d_in[0];
    const float* y_pred = (const float*)d_in[1];
    float* out = (float*)d_out;
    const int B  = in_sizes[0] / (256 * 256);
    const int nT = B * 64;
    const int nW = nT * 2;

    const size_t offK   = (size_t)nT * 2048;
    const size_t offOrd = offK + (((size_t)nT * 4 + 255) & ~(size_t)255);
    const size_t offMrg = offOrd + (size_t)nW * 4096;
    const size_t need   = offMrg + (size_t)nW * MRG_STRIDE;

    hipMemsetAsync(d_out, 0, (size_t)out_size * sizeof(float), stream);

    if (ws_size >= need) {
        char* ws = (char*)d_ws;
        unsigned short* pixLab_g = (unsigned short*)ws;
        int*            Kg       = (int*)(ws + offK);
        unsigned short* ord_g    = (unsigned short*)(ws + offOrd);
        char*           mrg      = ws + offMrg;
        hipLaunchKernelGGL(k12_ccl_sort, dim3(nT + nW), dim3(256), 0, stream,
                           y_true, y_pred, pixLab_g, Kg, ord_g, nT);
        hipLaunchKernelGGL(k3_kruskal,   dim3(nW), dim3(64),  0, stream, y_true, ord_g, mrg);
        hipLaunchKernelGGL(k4_weights,   dim3(nW), dim3(256), 0, stream, y_true, y_pred,
                           pixLab_g, Kg, mrg, out);
    } else {
        hipLaunchKernelGGL(malis_mono, dim3(nW), dim3(256), 0, stream, y_true, y_pred, out);
    }
}

// Round 10
// 297.621 us; speedup vs baseline: 2.4007x; 1.0458x over previous
//
#include <hip/hip_runtime.h>

#define NPIX   1024   // 32*32
#define NEH    992    // horizontal edges 32*31
#define NEDGE  1984   // + vertical 31*32
#define SORTN  2048
#define CHUNK  8      // labels per phase-2 pass
#define NMERGE 1023
#define NIL    0xFFFFu

// per-(tile,sgn) merge-record block in ws (20480 B stride)
#define MRG_STRIDE 20480
#define MRG_M      0
#define MRG_RA     256
#define MRG_RB     4608
#define MRG_SS     8960
#define MRG_ED     13312
#define MRG_NXT    15616

__device__ __forceinline__ void edge_ab(int e, int& a, int& b) {
    if (e < NEH) { int y = e / 31; int x = e - y * 31; a = y * 32 + x; b = a + 1; }
    else         { int ev = e - NEH; a = ev; b = ev + 32; }
}

__device__ __forceinline__ uint4 add4(uint4 x, uint4 y) {
    return make_uint4(x.x + y.x, x.y + y.y, x.z + y.z, x.w + y.w);
}
__device__ __forceinline__ uint4 sub4(uint4 x, uint4 y) {
    return make_uint4(x.x - y.x, x.y - y.y, x.z - y.z, x.w - y.w);
}

// wave-uniform broadcast via v_readlane (VALU/SALU class, ~8cy; no LDS round-trip)
__device__ __forceinline__ unsigned rdl32(unsigned v, int lane) {
    return (unsigned)__builtin_amdgcn_readlane((int)v, lane);
}
__device__ __forceinline__ unsigned long long rdl64(unsigned long long v, int lane) {
    unsigned lo = (unsigned)__builtin_amdgcn_readlane((int)(unsigned)v, lane);
    unsigned hi = (unsigned)__builtin_amdgcn_readlane((int)(unsigned)(v >> 32), lane);
    return ((unsigned long long)hi << 32) | lo;
}

// ============================ fused K1/K2 bodies ============================
__device__ void ccl_body(char* smem, int* kprimeSh,
                         const float* __restrict__ t_glob,
                         unsigned short* __restrict__ pixLab_g,
                         int* __restrict__ Kg, int tileId) {
    const int tid = threadIdx.x;
    const int bat = tileId >> 6;
    const int tile = tileId & 63;
    const int tr = tile >> 3, tc = tile & 7;

    unsigned short* labS = (unsigned short*)smem;                 // [0,2048)
    unsigned int*   cntS = (unsigned int*)(smem + 2048);          // [2048,6144)
    unsigned char*  bgS  = (unsigned char*)(smem + 20480);        // [20480,21504)

    for (int i = tid; i < NPIX; i += 256) {
        int y = i >> 5, x = i & 31;
        int gidx = bat * 65536 + (tr * 32 + y) * 256 + (tc * 32 + x);
        bgS[i] = (t_glob[gidx] == 0.0f) ? 1 : 0;
    }
    __syncthreads();

    if (tid < 64) {
        const int lane = tid;
        if (lane < 32) {
            #pragma unroll
            for (int x = 0; x < 32; x++) {
                int i = lane * 32 + x;
                labS[i] = bgS[i] ? (unsigned short)i : (unsigned short)NIL;
            }
        }
        while (true) {
            bool changed = false;
            if (lane < 32) {
                const int base = lane * 32;
                unsigned short v[32];
                #pragma unroll
                for (int x = 0; x < 32; x++) v[x] = labS[base + x];
                unsigned run = NIL;
                #pragma unroll
                for (int x = 0; x < 32; x++) {
                    unsigned val = v[x];
                    if (val == NIL) { run = NIL; }
                    else { unsigned nv = min(run, val); changed |= (nv != val); v[x] = (unsigned short)nv; run = nv; }
                }
                run = NIL;
                #pragma unroll
                for (int x = 31; x >= 0; x--) {
                    unsigned val = v[x];
                    if (val == NIL) { run = NIL; }
                    else { unsigned nv = min(run, val); changed |= (nv != val); v[x] = (unsigned short)nv; run = nv; }
                }
                #pragma unroll
                for (int x = 0; x < 32; x++) labS[base + x] = v[x];
            }
            if (lane < 32) {
                unsigned short c[32];
                #pragma unroll
                for (int k = 0; k < 32; k++) c[k] = labS[k * 32 + lane];
                unsigned run = NIL;
                #pragma unroll
                for (int k = 0; k < 32; k++) {
                    unsigned val = c[k];
                    if (val == NIL) { run = NIL; }
                    else { unsigned nv = min(run, val); changed |= (nv != val); c[k] = (unsigned short)nv; run = nv; }
                }
                run = NIL;
                #pragma unroll
                for (int k = 31; k >= 0; k--) {
                    unsigned val = c[k];
                    if (val == NIL) { run = NIL; }
                    else { unsigned nv = min(run, val); changed |= (nv != val); c[k] = (unsigned short)nv; run = nv; }
                }
                #pragma unroll
                for (int k = 0; k < 32; k++) labS[k * 32 + lane] = c[k];
            }
            if (!__any(changed)) break;
        }
    }
    __syncthreads();

    for (int i = tid; i < NPIX; i += 256) cntS[i] = 0;
    if (tid == 0) *kprimeSh = 0;
    __syncthreads();
    for (int i = tid; i < NPIX; i += 256)
        if (bgS[i]) atomicAdd(&cntS[labS[i]], 1u);
    __syncthreads();
    for (int i = tid; i < NPIX; i += 256) {
        if (bgS[i] && (int)labS[i] == i) {
            unsigned id = (cntS[i] >= 2) ? (unsigned)atomicAdd(kprimeSh, 1) : NIL;
            cntS[i] = id;
        }
    }
    __syncthreads();
    for (int i = tid; i < NPIX; i += 256)
        pixLab_g[tileId * NPIX + i] = bgS[i] ? (unsigned short)cntS[labS[i]] : (unsigned short)NIL;
    if (tid == 0) Kg[tileId] = *kprimeSh;
}

__device__ void sort_body(char* smem,
                          const float* __restrict__ t_glob,
                          const float* __restrict__ p_glob,
                          unsigned short* __restrict__ ord_g, int wg) {
    const int tid = threadIdx.x;
    const int sgn = wg & 1;
    const int tileId = wg >> 1;
    const int bat = tileId >> 6;
    const int tile = tileId & 63;
    const int tr = tile >> 3, tc = tile & 7;

    float*              pT   = (float*)smem;                      // [0,4096)
    unsigned long long* keys = (unsigned long long*)(smem + 4096);// [4096,20480)
    unsigned char*      bgS  = (unsigned char*)(smem + 20480);    // [20480,21504)

    for (int i = tid; i < NPIX; i += 256) {
        int y = i >> 5, x = i & 31;
        int gidx = bat * 65536 + (tr * 32 + y) * 256 + (tc * 32 + x);
        pT[i] = p_glob[gidx];
        bgS[i] = (t_glob[gidx] == 0.0f) ? 1 : 0;
    }
    __syncthreads();

    for (int k = tid; k < SORTN; k += 256) {
        unsigned long long key = 0ULL;
        if (k < NEDGE) {
            int a, b; edge_ab(k, a, b);
            float cost = pT[a] + pT[b];
            int nfg = (int)(!bgS[a]) + (int)(!bgS[b]);
            if (sgn == 0) { if (nfg == 2) cost = 20.0f; }
            else          { if (nfg == 0) cost = 0.0f;  }
            key = ((unsigned long long)__float_as_uint(cost) << 16)
                | (unsigned long long)(0xFFFFu - (unsigned)k);
        }
        keys[k] = key;
    }
    __syncthreads();
    for (int kk = 2; kk <= SORTN; kk <<= 1) {
        for (int jj = kk >> 1; jj > 0; jj >>= 1) {
            for (int i = tid; i < SORTN; i += 256) {
                int ixj = i ^ jj;
                if (ixj > i) {
                    unsigned long long A = keys[i], Bv = keys[ixj];
                    bool descBlk = ((i & kk) == 0);
                    if ((A < Bv) == descBlk) { keys[i] = Bv; keys[ixj] = A; }
                }
            }
            __syncthreads();
        }
    }
    for (int k = tid; k < NEDGE; k += 256)
        ord_g[(size_t)wg * SORTN + k] = (unsigned short)(0xFFFFu - (unsigned)(keys[k] & 0xFFFFULL));
}

__global__ __launch_bounds__(256, 2)
void k12_ccl_sort(const float* __restrict__ t_glob,
                  const float* __restrict__ p_glob,
                  unsigned short* __restrict__ pixLab_g,
                  int* __restrict__ Kg,
                  unsigned short* __restrict__ ord_g,
                  int nT) {
    __shared__ __align__(16) char smem[21504];
    __shared__ int kprimeSh;
    if ((int)blockIdx.x < nT)
        ccl_body(smem, &kprimeSh, t_glob, pixLab_g, Kg, blockIdx.x);
    else
        sort_body(smem, t_glob, p_glob, ord_g, blockIdx.x - nT);
}

// ============================ K3: hybrid Kruskal ============================
// Bulk: priority-claim parallel rounds (commit all edge-order-min winners at once)
// while a round yields >= 6 winners. Tail: the remaining (chained) candidates go
// through the register-log serial loop (readlane/ballot only; commits are
// fire-and-forget LDS writes read only by the next batch). Record order within a
// batch is irrelevant (weights/dendrogram ranges are order-independent).
__global__ __launch_bounds__(64)
void k3_kruskal(const float* __restrict__ t_glob,
                const unsigned short* __restrict__ ord_g,
                char* __restrict__ mrg_base) {
    const int lane = threadIdx.x;
    const int wg  = blockIdx.x;
    const int tileId = wg >> 1;
    const int bat = tileId >> 6;
    const int tile = tileId & 63;
    const int tr = tile >> 3, tc = tile & 7;

    __shared__ unsigned short parentS[NPIX];
    __shared__ unsigned long long nodeS[NPIX];
    __shared__ unsigned short nextS[NPIX];
    __shared__ unsigned int   claimS[NPIX];

    char* mg = mrg_base + (size_t)wg * MRG_STRIDE;
    unsigned int*   mrA = (unsigned int*)(mg + MRG_RA);
    unsigned int*   mrB = (unsigned int*)(mg + MRG_RB);
    unsigned int*   mSS = (unsigned int*)(mg + MRG_SS);
    unsigned short* mED = (unsigned short*)(mg + MRG_ED);
    unsigned short* mNX = (unsigned short*)(mg + MRG_NXT);
    const unsigned short* ord = ord_g + (size_t)wg * SORTN;

    for (int i = lane; i < NPIX; i += 64) {
        int y = i >> 5, x = i & 31;
        int gidx = bat * 65536 + (tr * 32 + y) * 256 + (tc * 32 + x);
        unsigned bg = (t_glob[gidx] == 0.0f) ? 1u : 0u;
        parentS[i] = (unsigned short)i;
        nodeS[i] = ((unsigned long long)i << 48) | ((unsigned long long)i << 32)
                 | (1ULL << 16) | (unsigned long long)bg;
        nextS[i] = (unsigned short)NIL;
    }
    __syncthreads();

    int m = 0;
    for (int kb = 0; kb < NEDGE; kb += 64) {      // 31 exact batches
        int e = ord[kb + lane];
        int a, b; edge_ab(e, a, b);
        unsigned ra = (unsigned)a, rb = (unsigned)b;
        // initial find (concurrent path-halving)
        while (true) {
            unsigned pa = parentS[ra];
            unsigned pb = parentS[rb];
            if (pa == ra && pb == rb) break;
            if (pa != ra) { unsigned ga = parentS[pa]; parentS[ra] = (unsigned short)ga; ra = ga; }
            if (pb != rb) { unsigned gb = parentS[pb]; parentS[rb] = (unsigned short)gb; rb = gb; }
        }
        bool pending = (ra != rb);
        bool committed = false;
        unsigned recA = 0, recB = 0, recSS = 0;

        // ---- bulk claim rounds (stop when parallelism collapses) ----
        int winners = 64;
        while (__any(pending) && winners >= 6) {
            if (pending) {
                claimS[ra] = 0xFFFFFFFFu;
                claimS[rb] = 0xFFFFFFFFu;
            }
            if (pending) {
                atomicMin(&claimS[ra], (unsigned)lane);
                atomicMin(&claimS[rb], (unsigned)lane);
            }
            bool win = pending && (claimS[ra] == (unsigned)lane) && (claimS[rb] == (unsigned)lane);
            if (win) {
                unsigned long long nA = nodeS[ra], nB = nodeS[rb];
                unsigned cons = ra, surv = rb;
                unsigned szAu = (unsigned)(nA >> 16) & 0xFFFFu;
                unsigned szBu = (unsigned)(nB >> 16) & 0xFFFFu;
                if (szAu > szBu) {
                    unsigned t = cons; cons = surv; surv = t;
                    unsigned long long tn = nA; nA = nB; nB = tn;
                }
                unsigned headA = (unsigned)(nA >> 48);
                unsigned tailA = (unsigned)(nA >> 32) & 0xFFFFu;
                unsigned szA   = (unsigned)(nA >> 16) & 0xFFFFu;
                unsigned slA   = (unsigned)nA & 0xFFFFu;
                unsigned headB = (unsigned)(nB >> 48);
                unsigned tailB = (unsigned)(nB >> 32) & 0xFFFFu;
                unsigned szB   = (unsigned)(nB >> 16) & 0xFFFFu;
                unsigned slB   = (unsigned)nB & 0xFFFFu;
                unsigned long long merged =
                      ((unsigned long long)headA << 48)
                    | ((unsigned long long)tailB << 32)
                    | ((unsigned long long)(szA + szB) << 16)
                    | (unsigned long long)(slA + slB);
                parentS[cons] = (unsigned short)surv;   // winners own disjoint roots
                nodeS[surv]   = merged;
                nextS[tailA]  = (unsigned short)headB;
                recA = (headA << 16) | headB;
                recB = (szA << 16) | szB;
                recSS = slA * slB;
                committed = true;
                pending = false;
            }
            winners = (int)__popcll(__ballot(win));
            if (pending) {                               // re-find for next round/tail
                while (true) {
                    unsigned pa = parentS[ra];
                    unsigned pb = parentS[rb];
                    if (pa == ra && pb == rb) break;
                    if (pa != ra) { unsigned ga = parentS[pa]; parentS[ra] = (unsigned short)ga; ra = ga; }
                    if (pb != rb) { unsigned gb = parentS[pb]; parentS[rb] = (unsigned short)gb; rb = gb; }
                }
                if (ra == rb) pending = false;
            }
        }

        // bulk record write (rank via ballot; order within batch irrelevant)
        unsigned long long cmB = __ballot(committed);
        if (committed) {
            int idx = m + (int)__popcll(cmB & ((1ULL << lane) - 1ULL));
            mrA[idx] = recA;
            mrB[idx] = recB;
            mSS[idx] = recSS;
            mED[idx] = (unsigned short)e;
        }
        int bulkCount = (int)__popcll(cmB);

        // ---- serial register-log tail (chained candidates) ----
        int logCount = 0;
        if (__any(pending)) {
            unsigned long long na = 0, nb = 0;
            if (pending) { na = nodeS[ra]; nb = nodeS[rb]; }   // fresh post-bulk
            unsigned specAB = (ra << 16) | rb;                  // current roots
            unsigned long long candm = __ballot(pending);
            unsigned logRa  = 0xFFFFFFFFu;   // root consumed by this lane's entry
            unsigned logRbO = 0xFFFFFFFFu;   // surviving root at merge time
            unsigned curRoot = 0xFFFFFFFFu;  // current root of entry's component
            unsigned long long logNode = 0;
            while (candm != 0ULL) {
                int j = __ffsll((long long)candm) - 1;          // uniform
                candm &= candm - 1ULL;
                unsigned sAB = rdl32(specAB, j);
                unsigned cra = sAB >> 16;
                unsigned crb = sAB & 0xFFFFu;
                unsigned long long hitA = __ballot(logRa == cra);
                unsigned long long hitB = __ballot(logRa == crb);
                if (hitA) cra = rdl32(curRoot, __ffsll((long long)hitA) - 1);
                if (hitB) crb = rdl32(curRoot, __ffsll((long long)hitB) - 1);
                if (cra == crb) continue;
                unsigned ce = rdl32((unsigned)e, j);
                unsigned long long hbA = __ballot(logRbO == cra);
                unsigned long long hbB = __ballot(logRbO == crb);
                unsigned long long cna = hbA ? rdl64(logNode, 63 - __clzll((long long)hbA)) : rdl64(na, j);
                unsigned long long cnb = hbB ? rdl64(logNode, 63 - __clzll((long long)hbB)) : rdl64(nb, j);
                unsigned cons = cra, surv = crb;
                unsigned szAq = (unsigned)(cna >> 16) & 0xFFFFu;
                unsigned szBq = (unsigned)(cnb >> 16) & 0xFFFFu;
                if (szAq > szBq) {
                    unsigned t = cons; cons = surv; surv = t;
                    unsigned long long tn = cna; cna = cnb; cnb = tn;
                }
                unsigned headA = (unsigned)(cna >> 48);
                unsigned tailA = (unsigned)(cna >> 32) & 0xFFFFu;
                unsigned szA   = (unsigned)(cna >> 16) & 0xFFFFu;
                unsigned slA   = (unsigned)cna & 0xFFFFu;
                unsigned headB = (unsigned)(cnb >> 48);
                unsigned tailB = (unsigned)(cnb >> 32) & 0xFFFFu;
                unsigned szB   = (unsigned)(cnb >> 16) & 0xFFFFu;
                unsigned slB   = (unsigned)cnb & 0xFFFFu;
                unsigned long long merged =
                      ((unsigned long long)headA << 48)
                    | ((unsigned long long)tailB << 32)
                    | ((unsigned long long)(szA + szB) << 16)
                    | (unsigned long long)(slA + slB);
                if (curRoot == cons) curRoot = surv;            // uniform patch
                if (lane == logCount) {
                    logRa = cons; logRbO = surv; curRoot = surv; logNode = merged;
                    parentS[cons] = (unsigned short)surv;       // fire-and-forget:
                    nodeS[surv]   = merged;                     //  read next batch only
                    nextS[tailA]  = (unsigned short)headB;
                    int idx = m + bulkCount + logCount;
                    mrA[idx] = (headA << 16) | headB;
                    mrB[idx] = (szA << 16) | szB;
                    mSS[idx] = slA * slB;
                    mED[idx] = (unsigned short)ce;
                }
                logCount++;
            }
        }
        m += bulkCount + logCount;
    }
    if (lane == 0) *(int*)(mg + MRG_M) = m;
    for (int i = lane; i < NPIX; i += 64) mNX[i] = nextS[i];
}

// ============================ K4: list-rank + chunked prefix dots + loss ============================
__global__ __launch_bounds__(256, 2)
void k4_weights(const float* __restrict__ t_glob,
                const float* __restrict__ p_glob,
                const unsigned short* __restrict__ pixLab_g,
                const int* __restrict__ Kg,
                const char* __restrict__ mrg_base,
                float* __restrict__ out) {
    const int tid = threadIdx.x;
    const int wg  = blockIdx.x;
    const int sgn = wg & 1;
    const int tileId = wg >> 1;
    const int bat = tileId >> 6;
    const int tile = tileId & 63;
    const int tr = tile >> 3, tc = tile & 7;

    __shared__ float          pT[NPIX];
    __shared__ unsigned char  bgS[NPIX];
    __shared__ unsigned short pixLab[NPIX];
    __shared__ unsigned short posS[NPIX];
    __shared__ unsigned int   mRecA[NMERGE];
    __shared__ unsigned int   mRecB[NMERGE];
    __shared__ unsigned int   mSaSb[NMERGE];
    __shared__ unsigned int   commonW[NMERGE];
    __shared__ unsigned short mEd[NMERGE];
    __shared__ __align__(16) unsigned long long big[2564];
    __shared__ unsigned wsumSh;
    __shared__ float lossSh;

    const char* mg = mrg_base + (size_t)wg * MRG_STRIDE;
    const int M = *(const int*)(mg + MRG_M);
    const int K = Kg[tileId];
    const unsigned int*   mrA = (const unsigned int*)(mg + MRG_RA);
    const unsigned int*   mrB = (const unsigned int*)(mg + MRG_RB);
    const unsigned int*   mSS = (const unsigned int*)(mg + MRG_SS);
    const unsigned short* mED = (const unsigned short*)(mg + MRG_ED);
    const unsigned short* mNX = (const unsigned short*)(mg + MRG_NXT);

    for (int i = tid; i < NPIX; i += 256) {
        int y = i >> 5, x = i & 31;
        int gidx = bat * 65536 + (tr * 32 + y) * 256 + (tc * 32 + x);
        pT[i] = p_glob[gidx];
        bgS[i] = (t_glob[gidx] == 0.0f) ? 1 : 0;
        pixLab[i] = pixLab_g[tileId * NPIX + i];
    }
    for (int j = tid; j < M; j += 256) {
        mRecA[j] = mrA[j];
        mRecB[j] = mrB[j];
        mSaSb[j] = mSS[j];
        mEd[j]   = mED[j];
        commonW[j] = 0;
    }

    // ---- Wyllie list ranking -> posS ----
    unsigned short* n0 = (unsigned short*)big;
    unsigned short* n1 = n0 + 1024;
    unsigned short* d0 = n0 + 2048;
    unsigned short* d1 = n0 + 3072;
    for (int i = tid; i < NPIX; i += 256) { n0[i] = mNX[i]; d0[i] = 1; }
    __syncthreads();
    for (int s = 0; s < 10; s++) {
        unsigned short* sn = (s & 1) ? n1 : n0;
        unsigned short* sd = (s & 1) ? d1 : d0;
        unsigned short* dn = (s & 1) ? n0 : n1;
        unsigned short* dd = (s & 1) ? d0 : d1;
        for (int i = tid; i < NPIX; i += 256) {
            unsigned nx = sn[i];
            unsigned dv = sd[i];
            if (nx != NIL) { dv += sd[nx]; nx = sn[nx]; }
            dn[i] = (unsigned short)nx;
            dd[i] = (unsigned short)dv;
        }
        __syncthreads();
    }
    for (int i = tid; i < NPIX; i += 256)
        posS[i] = (unsigned short)(NPIX - (int)d0[i]);
    __syncthreads();

    // ---- chunked label prefix sums + per-merge dots ----
    unsigned*       P32 = (unsigned*)big;
    uint4*          P4  = (uint4*)big;
    unsigned*       scr = P32 + 4100;
    uint4*          S4  = (uint4*)scr;
    unsigned short* P16 = (unsigned short*)big;
    for (int base = 0; base < K; base += CHUNK) {
        for (int idx = tid; idx < 4100; idx += 256) P32[idx] = 0;
        __syncthreads();
        for (int i = tid; i < NPIX; i += 256) {
            unsigned l = pixLab[i];
            if (l != NIL && l >= (unsigned)base && l < (unsigned)(base + CHUNK))
                P16[(posS[i] + 1) * 8 + (l - base)] = 1;
        }
        __syncthreads();
        {
            int r0 = tid * 4 + 1;
            uint4 acc = P4[r0];
            for (int rr = r0 + 1; rr <= r0 + 3; rr++) { acc = add4(acc, P4[rr]); P4[rr] = acc; }
            S4[tid] = acc;
            __syncthreads();
            if (tid < 64) {
                uint4 s0 = S4[tid * 4], s1 = S4[tid * 4 + 1], s2 = S4[tid * 4 + 2], s3 = S4[tid * 4 + 3];
                uint4 t1 = add4(s0, s1), t2 = add4(t1, s2), t3 = add4(t2, s3);
                uint4 run = t3;
                #pragma unroll
                for (int d = 1; d < 64; d <<= 1) {
                    uint4 o;
                    o.x = __shfl_up(run.x, d, 64);
                    o.y = __shfl_up(run.y, d, 64);
                    o.z = __shfl_up(run.z, d, 64);
                    o.w = __shfl_up(run.w, d, 64);
                    if (tid >= d) run = add4(run, o);
                }
                uint4 off = sub4(run, t3);
                S4[tid * 4]     = add4(s0, off);
                S4[tid * 4 + 1] = add4(t1, off);
                S4[tid * 4 + 2] = add4(t2, off);
                S4[tid * 4 + 3] = add4(t3, off);
            }
            __syncthreads();
            if (tid > 0) {
                uint4 off = S4[tid - 1];
                for (int rr = r0; rr <= r0 + 3; rr++) P4[rr] = add4(P4[rr], off);
            }
        }
        __syncthreads();
        for (int j = tid; j < M; j += 256) {
            unsigned recA = mRecA[j], recB = mRecB[j];
            unsigned aS = posS[recA >> 16];
            unsigned bS = posS[recA & 0xFFFFu];
            uint4 da = sub4(P4[aS + (recB >> 16)], P4[aS]);
            uint4 db = sub4(P4[bS + (recB & 0xFFFFu)], P4[bS]);
            unsigned acc;
            acc  = (da.x & 0xFFFFu) * (db.x & 0xFFFFu) + (da.x >> 16) * (db.x >> 16);
            acc += (da.y & 0xFFFFu) * (db.y & 0xFFFFu) + (da.y >> 16) * (db.y >> 16);
            acc += (da.z & 0xFFFFu) * (db.z & 0xFFFFu) + (da.z >> 16) * (db.z >> 16);
            acc += (da.w & 0xFFFFu) * (db.w & 0xFFFFu) + (da.w >> 16) * (db.w >> 16);
            commonW[j] += acc;
        }
        __syncthreads();
    }

    // ---- normalize + mask + loss ----
    if (tid == 0) { wsumSh = 0; lossSh = 0.0f; }
    __syncthreads();
    unsigned wloc = 0;
    for (int j = tid; j < M; j += 256)
        wloc += (sgn == 0) ? (mSaSb[j] - commonW[j]) : commonW[j];
    if (wloc) atomicAdd(&wsumSh, wloc);
    __syncthreads();
    const unsigned wsum = wsumSh;
    if (wsum > 0) {
        const double inv = 1.0 / (double)wsum;
        float lloc = 0.0f;
        for (int j = tid; j < M; j += 256) {
            unsigned w = (sgn == 0) ? (mSaSb[j] - commonW[j]) : commonW[j];
            if (!w) continue;
            int e = mEd[j];
            int a, b; edge_ab(e, a, b);
            int nfg = (int)(!bgS[a]) + (int)(!bgS[b]);
            bool keep = (sgn == 0) ? (nfg == 0) : (nfg >= 1);
            if (!keep) continue;
            float wn = (float)((double)w * inv);
            float fa, fb;
            if (sgn == 0) { fa = pT[a] * pT[a];            fb = pT[b] * pT[b]; }
            else { float da = 20.0f - pT[a], db = 20.0f - pT[b]; fa = da * da; fb = db * db; }
            lloc += wn * (fa + fb);
        }
        if (lloc != 0.0f) atomicAdd(&lossSh, lloc);
        __syncthreads();
        if (tid == 0 && lossSh != 0.0f) atomicAdd(out, lossSh);
    }
}

// ============================ fallback: monolith (used if ws too small) ============================
__global__ __launch_bounds__(256, 2)
void malis_mono(const float* __restrict__ t_glob,
                const float* __restrict__ p_glob,
                float* __restrict__ out) {
    const int tid  = threadIdx.x;
    const int wg   = blockIdx.x;
    const int sgn  = wg & 1;
    const int tileId = wg >> 1;
    const int bat  = tileId >> 6;
    const int tile = tileId & 63;
    const int tr = tile >> 3, tc = tile & 7;

    __shared__ float          pT[NPIX];
    __shared__ unsigned char  bgS[NPIX];
    __shared__ unsigned short pixLab[NPIX];
    __shared__ unsigned short parentS[NPIX];
    __shared__ unsigned short nextS[NPIX];
    __shared__ unsigned long long nodeS[NPIX];
    __shared__ unsigned int   claimS[NPIX];
    __shared__ unsigned short posS[NPIX];
    __shared__ unsigned short orderS[NEDGE];
    __shared__ unsigned int   mRecA[NMERGE];
    __shared__ unsigned int   mRecB[NMERGE];
    __shared__ unsigned short mEd[NMERGE];
    __shared__ unsigned int   mSaSb[NMERGE];
    __shared__ unsigned int   commonW[NMERGE];
    __shared__ __align__(16) unsigned long long big[2564];
    __shared__ int   kprimeSh, mCountSh;
    __shared__ unsigned wsumSh;
    __shared__ float lossSh;

    for (int i = tid; i < NPIX; i += 256) {
        int y = i >> 5, x = i & 31;
        int gidx = bat * 65536 + (tr * 32 + y) * 256 + (tc * 32 + x);
        pT[i] = p_glob[gidx];
        bgS[i] = (t_glob[gidx] == 0.0f) ? 1 : 0;
    }
    __syncthreads();

    unsigned short* labS = (unsigned short*)big;
    unsigned int*   cntS = (unsigned int*)(((char*)big) + 2048);
    if (tid < 64) {
        const int lane = tid;
        if (lane < 32) {
            #pragma unroll
            for (int x = 0; x < 32; x++) {
                int i = lane * 32 + x;
                labS[i] = bgS[i] ? (unsigned short)i : (unsigned short)NIL;
            }
        }
        while (true) {
            bool changed = false;
            if (lane < 32) {
                const int base = lane * 32;
                unsigned short v[32];
                #pragma unroll
                for (int x = 0; x < 32; x++) v[x] = labS[base + x];
                unsigned run = NIL;
                #pragma unroll
                for (int x = 0; x < 32; x++) {
                    unsigned val = v[x];
                    if (val == NIL) { run = NIL; }
                    else { unsigned nv = min(run, val); changed |= (nv != val); v[x] = (unsigned short)nv; run = nv; }
                }
                run = NIL;
                #pragma unroll
                for (int x = 31; x >= 0; x--) {
                    unsigned val = v[x];
                    if (val == NIL) { run = NIL; }
                    else { unsigned nv = min(run, val); changed |= (nv != val); v[x] = (unsigned short)nv; run = nv; }
                }
                #pragma unroll
                for (int x = 0; x < 32; x++) labS[base + x] = v[x];
            }
            if (lane < 32) {
                unsigned short c[32];
                #pragma unroll
                for (int k = 0; k < 32; k++) c[k] = labS[k * 32 + lane];
                unsigned run = NIL;
                #pragma unroll
                for (int k = 0; k < 32; k++) {
                    unsigned val = c[k];
                    if (val == NIL) { run = NIL; }
                    else { unsigned nv = min(run, val); changed |= (nv != val); c[k] = (unsigned short)nv; run = nv; }
                }
                run = NIL;
                #pragma unroll
                for (int k = 31; k >= 0; k--) {
                    unsigned val = c[k];
                    if (val == NIL) { run = NIL; }
                    else { unsigned nv = min(run, val); changed |= (nv != val); c[k] = (unsigned short)nv; run = nv; }
                }
                #pragma unroll
                for (int k = 0; k < 32; k++) labS[k * 32 + lane] = c[k];
            }
            if (!__any(changed)) break;
        }
    }
    __syncthreads();

    for (int i = tid; i < NPIX; i += 256) cntS[i] = 0;
    if (tid == 0) kprimeSh = 0;
    __syncthreads();
    for (int i = tid; i < NPIX; i += 256)
        if (bgS[i]) atomicAdd(&cntS[labS[i]], 1u);
    __syncthreads();
    for (int i = tid; i < NPIX; i += 256) {
        if (bgS[i] && (int)labS[i] == i) {
            unsigned id = (cntS[i] >= 2) ? (unsigned)atomicAdd(&kprimeSh, 1) : NIL;
            cntS[i] = id;
        }
    }
    __syncthreads();
    for (int i = tid; i < NPIX; i += 256)
        pixLab[i] = bgS[i] ? (unsigned short)cntS[labS[i]] : (unsigned short)NIL;
    __syncthreads();
    const int K = kprimeSh;

    unsigned long long* keys = big;
    for (int k = tid; k < SORTN; k += 256) {
        unsigned long long key = 0ULL;
        if (k < NEDGE) {
            int a, b; edge_ab(k, a, b);
            float cost = pT[a] + pT[b];
            int nfg = (int)(!bgS[a]) + (int)(!bgS[b]);
            if (sgn == 0) { if (nfg == 2) cost = 20.0f; }
            else          { if (nfg == 0) cost = 0.0f;  }
            key = ((unsigned long long)__float_as_uint(cost) << 16)
                | (unsigned long long)(0xFFFFu - (unsigned)k);
        }
        keys[k] = key;
    }
    __syncthreads();
    for (int kk = 2; kk <= SORTN; kk <<= 1) {
        for (int jj = kk >> 1; jj > 0; jj >>= 1) {
            for (int i = tid; i < SORTN; i += 256) {
                int ixj = i ^ jj;
                if (ixj > i) {
                    unsigned long long A = keys[i], Bv = keys[ixj];
                    bool descBlk = ((i & kk) == 0);
                    if ((A < Bv) == descBlk) { keys[i] = Bv; keys[ixj] = A; }
                }
            }
            __syncthreads();
        }
    }
    for (int k = tid; k < NEDGE; k += 256)
        orderS[k] = (unsigned short)(0xFFFFu - (unsigned)(keys[k] & 0xFFFFULL));
    for (int i = tid; i < NPIX; i += 256) {
        parentS[i] = (unsigned short)i;
        nodeS[i] = ((unsigned long long)i << 48) | ((unsigned long long)i << 32)
                 | (1ULL << 16) | (unsigned long long)bgS[i];
        nextS[i] = (unsigned short)NIL;
    }
    __syncthreads();

    if (tid < 64) {
        const int lane = tid;
        int m = 0;
        for (int kb = 0; kb < NEDGE; kb += 64) {
            int e = orderS[kb + lane];
            int a, b; edge_ab(e, a, b);
            unsigned ra = (unsigned)a, rb = (unsigned)b;
            bool pending = true;
            bool committed = false;
            unsigned recA = 0, recB = 0, recSS = 0;
            while (__any(pending)) {
                if (pending) {
                    while (true) {
                        unsigned pa = parentS[ra];
                        unsigned pb = parentS[rb];
                        if (pa == ra && pb == rb) break;
                        if (pa != ra) { unsigned ga = parentS[pa]; parentS[ra] = (unsigned short)ga; ra = ga; }
                        if (pb != rb) { unsigned gb = parentS[pb]; parentS[rb] = (unsigned short)gb; rb = gb; }
                    }
                    if (ra == rb) pending = false;
                }
                if (pending) {
                    claimS[ra] = 0xFFFFFFFFu;
                    claimS[rb] = 0xFFFFFFFFu;
                }
                if (pending) {
                    atomicMin(&claimS[ra], (unsigned)lane);
                    atomicMin(&claimS[rb], (unsigned)lane);
                }
                bool win = pending && (claimS[ra] == (unsigned)lane) && (claimS[rb] == (unsigned)lane);
                if (win) {
                    unsigned long long nA = nodeS[ra], nB = nodeS[rb];
                    unsigned cons = ra, surv = rb;
                    unsigned szAu = (unsigned)(nA >> 16) & 0xFFFFu;
                    unsigned szBu = (unsigned)(nB >> 16) & 0xFFFFu;
                    if (szAu > szBu) {
                        unsigned t = cons; cons = surv; surv = t;
                        unsigned long long tn = nA; nA = nB; nB = tn;
                    }
                    unsigned headA = (unsigned)(nA >> 48);
                    unsigned tailA = (unsigned)(nA >> 32) & 0xFFFFu;
                    unsigned szA   = (unsigned)(nA >> 16) & 0xFFFFu;
                    unsigned slA   = (unsigned)nA & 0xFFFFu;
                    unsigned headB = (unsigned)(nB >> 48);
                    unsigned tailB = (unsigned)(nB >> 32) & 0xFFFFu;
                    unsigned szB   = (unsigned)(nB >> 16) & 0xFFFFu;
                    unsigned slB   = (unsigned)nB & 0xFFFFu;
                    unsigned long long merged =
                          ((unsigned long long)headA << 48)
                        | ((unsigned long long)tailB << 32)
                        | ((unsigned long long)(szA + szB) << 16)
                        | (unsigned long long)(slA + slB);
                    parentS[cons] = (unsigned short)surv;
                    nodeS[surv]   = merged;
                    nextS[tailA]  = (unsigned short)headB;
                    recA = (headA << 16) | headB;
                    recB = (szA << 16) | szB;
                    recSS = slA * slB;
                    committed = true;
                    pending = false;
                }
            }
            unsigned long long cm = __ballot(committed);
            if (committed) {
                int idx = m + (int)__popcll(cm & ((1ULL << lane) - 1ULL));
                mRecA[idx] = recA;
                mRecB[idx] = recB;
                mSaSb[idx] = recSS;
                mEd[idx]   = (unsigned short)e;
            }
            m += (int)__popcll(cm);
        }
        if (lane == 0) mCountSh = m;
    }
    __syncthreads();
    const int M = mCountSh;
    for (int j = tid; j < M; j += 256) commonW[j] = 0;

    unsigned short* n0 = (unsigned short*)big;
    unsigned short* n1 = n0 + 1024;
    unsigned short* d0 = n0 + 2048;
    unsigned short* d1 = n0 + 3072;
    for (int i = tid; i < NPIX; i += 256) { n0[i] = nextS[i]; d0[i] = 1; }
    __syncthreads();
    for (int s = 0; s < 10; s++) {
        unsigned short* sn = (s & 1) ? n1 : n0;
        unsigned short* sd = (s & 1) ? d1 : d0;
        unsigned short* dn = (s & 1) ? n0 : n1;
        unsigned short* dd = (s & 1) ? d0 : d1;
        for (int i = tid; i < NPIX; i += 256) {
            unsigned nx = sn[i];
            unsigned dv = sd[i];
            if (nx != NIL) { dv += sd[nx]; nx = sn[nx]; }
            dn[i] = (unsigned short)nx;
            dd[i] = (unsigned short)dv;
        }
        __syncthreads();
    }
    for (int i = tid; i < NPIX; i += 256)
        posS[i] = (unsigned short)(NPIX - (int)d0[i]);
    __syncthreads();

    unsigned*       P32 = (unsigned*)big;
    uint4*          P4  = (uint4*)big;
    unsigned*       scr = P32 + 4100;
    uint4*          S4  = (uint4*)scr;
    unsigned short* P16 = (unsigned short*)big;
    for (int base = 0; base < K; base += CHUNK) {
        for (int idx = tid; idx < 4100; idx += 256) P32[idx] = 0;
        __syncthreads();
        for (int i = tid; i < NPIX; i += 256) {
            unsigned l = pixLab[i];
            if (l != NIL && l >= (unsigned)base && l < (unsigned)(base + CHUNK))
                P16[(posS[i] + 1) * 8 + (l - base)] = 1;
        }
        __syncthreads();
        {
            int r0 = tid * 4 + 1;
            uint4 acc = P4[r0];
            for (int rr = r0 + 1; rr <= r0 + 3; rr++) { acc = add4(acc, P4[rr]); P4[rr] = acc; }
            S4[tid] = acc;
            __syncthreads();
            if (tid < 64) {
                uint4 s0 = S4[tid * 4], s1 = S4[tid * 4 + 1], s2 = S4[tid * 4 + 2], s3 = S4[tid * 4 + 3];
                uint4 t1 = add4(s0, s1), t2 = add4(t1, s2), t3 = add4(t2, s3);
                uint4 run = t3;
                #pragma unroll
                for (int d = 1; d < 64; d <<= 1) {
                    uint4 o;
                    o.x = __shfl_up(run.x, d, 64);
                    o.y = __shfl_up(run.y, d, 64);
                    o.z = __shfl_up(run.z, d, 64);
                    o.w = __shfl_up(run.w, d, 64);
                    if (tid >= d) run = add4(run, o);
                }
                uint4 off = sub4(run, t3);
                S4[tid * 4]     = add4(s0, off);
                S4[tid * 4 + 1] = add4(t1, off);
                S4[tid * 4 + 2] = add4(t2, off);
                S4[tid * 4 + 3] = add4(t3, off);
            }
            __syncthreads();
            if (tid > 0) {
                uint4 off = S4[tid - 1];
                for (int rr = r0; rr <= r0 + 3; rr++) P4[rr] = add4(P4[rr], off);
            }
        }
        __syncthreads();
        for (int j = tid; j < M; j += 256) {
            unsigned recA = mRecA[j], recB = mRecB[j];
            unsigned aS = posS[recA >> 16];
            unsigned bS = posS[recA & 0xFFFFu];
            uint4 da = sub4(P4[aS + (recB >> 16)], P4[aS]);
            uint4 db = sub4(P4[bS + (recB & 0xFFFFu)], P4[bS]);
            unsigned acc;
            acc  = (da.x & 0xFFFFu) * (db.x & 0xFFFFu) + (da.x >> 16) * (db.x >> 16);
            acc += (da.y & 0xFFFFu) * (db.y & 0xFFFFu) + (da.y >> 16) * (db.y >> 16);
            acc += (da.z & 0xFFFFu) * (db.z & 0xFFFFu) + (da.z >> 16) * (db.z >> 16);
            acc += (da.w & 0xFFFFu) * (db.w & 0xFFFFu) + (da.w >> 16) * (db.w >> 16);
            commonW[j] += acc;
        }
        __syncthreads();
    }

    if (tid == 0) { wsumSh = 0; lossSh = 0.0f; }
    __syncthreads();
    unsigned wloc = 0;
    for (int j = tid; j < M; j += 256)
        wloc += (sgn == 0) ? (mSaSb[j] - commonW[j]) : commonW[j];
    if (wloc) atomicAdd(&wsumSh, wloc);
    __syncthreads();
    const unsigned wsum = wsumSh;
    if (wsum > 0) {
        const double inv = 1.0 / (double)wsum;
        float lloc = 0.0f;
        for (int j = tid; j < M; j += 256) {
            unsigned w = (sgn == 0) ? (mSaSb[j] - commonW[j]) : commonW[j];
            if (!w) continue;
            int e = mEd[j];
            int a, b; edge_ab(e, a, b);
            int nfg = (int)(!bgS[a]) + (int)(!bgS[b]);
            bool keep = (sgn == 0) ? (nfg == 0) : (nfg >= 1);
            if (!keep) continue;
            float wn = (float)((double)w * inv);
            float fa, fb;
            if (sgn == 0) { fa = pT[a] * pT[a];            fb = pT[b] * pT[b]; }
            else { float da = 20.0f - pT[a], db = 20.0f - pT[b]; fa = da * da; fb = db * db; }
            lloc += wn * (fa + fb);
        }
        if (lloc != 0.0f) atomicAdd(&lossSh, lloc);
        __syncthreads();
        if (tid == 0 && lossSh != 0.0f) atomicAdd(out, lossSh);
    }
}

extern "C" void kernel_launch(void* const* d_in, const int* in_sizes, int n_in,
                              void* d_out, int out_size, void* d_ws, size_t ws_size,
                              hipStream_t stream) {
    const float* y_true = (const float*)d_in[0];
    const float* y_pred = (const float*)d_in[1];
    float* out = (float*)d_out;
    const int B  = in_sizes[0] / (256 * 256);
    const int nT = B * 64;
    const int nW = nT * 2;

    const size_t offK   = (size_t)nT * 2048;
    const size_t offOrd = offK + (((size_t)nT * 4 + 255) & ~(size_t)255);
    const size_t offMrg = offOrd + (size_t)nW * 4096;
    const size_t need   = offMrg + (size_t)nW * MRG_STRIDE;

    hipMemsetAsync(d_out, 0, (size_t)out_size * sizeof(float), stream);

    if (ws_size >= need) {
        char* ws = (char*)d_ws;
        unsigned short* pixLab_g = (unsigned short*)ws;
        int*            Kg       = (int*)(ws + offK);
        unsigned short* ord_g    = (unsigned short*)(ws + offOrd);
        char*           mrg      = ws + offMrg;
        hipLaunchKernelGGL(k12_ccl_sort, dim3(nT + nW), dim3(256), 0, stream,
                           y_true, y_pred, pixLab_g, Kg, ord_g, nT);
        hipLaunchKernelGGL(k3_kruskal,   dim3(nW), dim3(64),  0, stream, y_true, ord_g, mrg);
        hipLaunchKernelGGL(k4_weights,   dim3(nW), dim3(256), 0, stream, y_true, y_pred,
                           pixLab_g, Kg, mrg, out);
    } else {
        hipLaunchKernelGGL(malis_mono, dim3(nW), dim3(256), 0, stream, y_true, y_pred, out);
    }
}